// Round 3
// baseline (2457.062 us; speedup 1.0000x reference)
//
#include <hip/hip_runtime.h>
#include <math.h>

#define PPP 20000   // paths
#define TT  30      // max timesteps
#define SS  1000    // samples
#define VNT 10000   // non-terminal vocab
#define PB  64      // paths per LSTM block

// ---------------- length bucketing (counting sort by path length) -----------

__global__ void k_zero(int* bins) {
    if (threadIdx.x < 32) bins[threadIdx.x] = 0;
}

__global__ void k_hist(const int* __restrict__ len, int* __restrict__ bins) {
    int p = blockIdx.x * 256 + threadIdx.x;
    if (p < PPP) atomicAdd(&bins[len[p] - 1], 1);
}

// descending order: longest paths first (better tail scheduling)
__global__ void k_scan(const int* __restrict__ bins, int* __restrict__ cur) {
    if (threadIdx.x == 0 && blockIdx.x == 0) {
        int ofs = 0;
        for (int l = TT - 1; l >= 0; l--) { cur[l] = ofs; ofs += bins[l]; }
    }
}

__global__ void k_scatter(const int* __restrict__ len, int* __restrict__ cur,
                          int* __restrict__ order) {
    int p = blockIdx.x * 256 + threadIdx.x;
    if (p < PPP) {
        int pos = atomicAdd(&cur[len[p] - 1], 1);
        order[pos] = p;
    }
}

// ---------------- precompute Zx = emb @ W + b  (per direction) --------------

__global__ __launch_bounds__(256) void zx_kernel(
    const float* __restrict__ emb,
    const float* __restrict__ Wf, const float* __restrict__ bf,
    const float* __restrict__ Wb, const float* __restrict__ bb,
    float* __restrict__ Zall)
{
    const int dir = blockIdx.y;
    const float* W = dir ? Wb : Wf;
    const float* b = dir ? bb : bf;
    float* Z = Zall + (size_t)dir * VNT * 512;

    __shared__ float X[8][128];
    const int tid = threadIdx.x;
    const int tok0 = blockIdx.x * 8;

    {
        int tr = tid >> 5;
        int c4 = (tid & 31) * 4;
        *(float4*)&X[tr][c4] = *(const float4*)(emb + (size_t)(tok0 + tr) * 128 + c4);
    }
    __syncthreads();

    const int pp = tid >> 5;
    const int cg = tid & 31;
    const int c0 = cg * 16;

    float acc[16];
#pragma unroll
    for (int j = 0; j < 16; j++) acc[j] = 0.f;

    for (int k = 0; k < 128; k++) {
        float a = X[pp][k];
        const float* wr = W + (size_t)k * 512 + c0;
#pragma unroll
        for (int q = 0; q < 4; q++) {
            float4 w = *(const float4*)(wr + q * 4);
            acc[q * 4 + 0] = fmaf(a, w.x, acc[q * 4 + 0]);
            acc[q * 4 + 1] = fmaf(a, w.y, acc[q * 4 + 1]);
            acc[q * 4 + 2] = fmaf(a, w.z, acc[q * 4 + 2]);
            acc[q * 4 + 3] = fmaf(a, w.w, acc[q * 4 + 3]);
        }
    }

    float* dst = Z + (size_t)(tok0 + pp) * 512 + c0;
#pragma unroll
    for (int q = 0; q < 4; q++) {
        float4 bv = *(const float4*)(b + c0 + q * 4);
        float4 o;
        o.x = acc[q * 4 + 0] + bv.x;
        o.y = acc[q * 4 + 1] + bv.y;
        o.z = acc[q * 4 + 2] + bv.z;
        o.w = acc[q * 4 + 3] + bv.w;
        *(float4*)(dst + q * 4) = o;
    }
}

// ---------------- LSTM: z = Zx[token] + h @ U ------------------------------
// Block: 64 paths, 256 threads. Thread (tp=tid&7 -> 8 paths, tc=tid>>3 -> 4
// cols per gate). Per kk: 128 FMA vs 6 ds_read_b128 (2 HT + 4 UT).
// LDS: HT[128][68] (h, col-major, padded), Ut[2][8][512] double-buffered.

__device__ __forceinline__ float fsigmoid(float x) {
    return 1.f / (1.f + __expf(-x));
}
__device__ __forceinline__ float ftanh(float x) {
    return 2.f / (1.f + __expf(-2.f * x)) - 1.f;
}

typedef const __attribute__((address_space(1))) void GVoid;
typedef __attribute__((address_space(3))) void LVoid;

__device__ __forceinline__ void prefetch_tile(const float* __restrict__ U, int kt,
                                              float* dst, int tid) {
    const char* src = (const char*)(U + (size_t)kt * 4096);
    const int wv = tid >> 6;
    const int ln = tid & 63;
#pragma unroll
    for (int j = 0; j < 4; j++) {
        int chunkbase = j * 256 + wv * 64;
        __builtin_amdgcn_global_load_lds(
            (GVoid*)(src + (size_t)(chunkbase + ln) * 16),
            (LVoid*)((char*)dst + (size_t)chunkbase * 16),
            16, 0, 0);
    }
}

__global__ __launch_bounds__(256, 2) void lstm_kernel(
    const float* __restrict__ Zall,
    const float* __restrict__ Uf, const float* __restrict__ Ub,
    const int* __restrict__ path_elements, const int* __restrict__ path_lengths,
    const int* __restrict__ order,
    float* __restrict__ h_out)   // [2][P][128]
{
    const int dir = blockIdx.y;
    const float* Z = Zall + (size_t)dir * VNT * 512;
    const float* U = dir ? Ub : Uf;

    __shared__ float HT[128][68];     // [col][path], padded
    __shared__ float Ut[2][8][512];
    __shared__ int s_pid[PB];
    __shared__ int s_len[PB];

    const int tid = threadIdx.x;
    const int tp = tid & 7;            // path group: paths tp*8 .. +7
    const int tc = tid >> 3;           // col group: cols tc*4 .. +3 (per gate)
    const int p0 = tp * 8;
    const int c0 = tc * 4;

    if (tid < PB) {
        int idx = blockIdx.x * PB + tid;
        if (idx > PPP - 1) idx = PPP - 1;      // tail block: duplicate last path
        int pid = order[idx];
        s_pid[tid] = pid;
        s_len[tid] = path_lengths[pid];
    }
    for (int i = tid; i < 128 * 68; i += 256) ((float*)HT)[i] = 0.f;
    prefetch_tile(U, 0, &Ut[0][0][0], tid);
    __syncthreads();

    const int maxLen = s_len[0];       // descending sort: first is longest

    float4 c4[8];
#pragma unroll
    for (int p = 0; p < 8; p++) c4[p] = make_float4(0.f, 0.f, 0.f, 0.f);

    int pidLocal[8], lenLocal[8];
#pragma unroll
    for (int p = 0; p < 8; p++) {
        pidLocal[p] = s_pid[p0 + p];
        lenLocal[p] = s_len[p0 + p];
    }

    for (int step = 0; step < maxLen; step++) {
        const int t = dir ? (maxLen - 1 - step) : step;

        // acc init = Zx[token] gather (L2/L3 resident)
        float4 acc[4][8];                // [gate][path], components = 4 cols
#pragma unroll
        for (int p = 0; p < 8; p++) {
            int tok = path_elements[(size_t)pidLocal[p] * TT + t];
            const float* zr = Z + (size_t)tok * 512 + c0;
#pragma unroll
            for (int g = 0; g < 4; g++)
                acc[g][p] = *(const float4*)(zr + g * 128);
        }

        // h @ U over 16 double-buffered k-tiles
        for (int kt = 0; kt < 16; kt++) {
            __syncthreads();
            prefetch_tile(U, (kt + 1) & 15, &Ut[(kt + 1) & 1][0][0], tid);
            const float(*UT)[512] = Ut[kt & 1];
            const int kbase = kt * 8;
#pragma unroll
            for (int kk = 0; kk < 8; kk++) {
                float4 a0 = *(const float4*)&HT[kbase + kk][p0];
                float4 a1 = *(const float4*)&HT[kbase + kk][p0 + 4];
                float ap[8] = {a0.x, a0.y, a0.z, a0.w, a1.x, a1.y, a1.z, a1.w};
                float4 w[4];
#pragma unroll
                for (int g = 0; g < 4; g++)
                    w[g] = *(const float4*)&UT[kk][g * 128 + c0];
#pragma unroll
                for (int g = 0; g < 4; g++)
#pragma unroll
                    for (int p = 0; p < 8; p++) {
                        acc[g][p].x = fmaf(ap[p], w[g].x, acc[g][p].x);
                        acc[g][p].y = fmaf(ap[p], w[g].y, acc[g][p].y);
                        acc[g][p].z = fmaf(ap[p], w[g].z, acc[g][p].z);
                        acc[g][p].w = fmaf(ap[p], w[g].w, acc[g][p].w);
                    }
            }
        }
        __syncthreads();   // all HT reads done before gating writes

        // gating
#pragma unroll
        for (int p = 0; p < 8; p++) {
            bool valid = t < lenLocal[p];
            float zi[4] = {acc[0][p].x, acc[0][p].y, acc[0][p].z, acc[0][p].w};
            float zf[4] = {acc[1][p].x, acc[1][p].y, acc[1][p].z, acc[1][p].w};
            float zg[4] = {acc[2][p].x, acc[2][p].y, acc[2][p].z, acc[2][p].w};
            float zo[4] = {acc[3][p].x, acc[3][p].y, acc[3][p].z, acc[3][p].w};
            float* cp = &c4[p].x;
#pragma unroll
            for (int e = 0; e < 4; e++) {
                float ig = fsigmoid(zi[e]);
                float fg = fsigmoid(zf[e]);
                float gg = ftanh(zg[e]);
                float og = fsigmoid(zo[e]);
                float cn = fg * cp[e] + ig * gg;
                float hn = og * ftanh(cn);
                if (valid) {
                    cp[e] = cn;
                    HT[c0 + e][p0 + p] = hn;
                }
            }
        }
        // next step's kt=0 barrier makes gating writes visible
    }

    __syncthreads();
    // write final h: thread -> path pg, cols ch*32..+31
    {
        const int pg = tid >> 2;       // 0..63
        const int ch = tid & 3;        // 0..3
        float* dst = h_out + ((size_t)dir * PPP + s_pid[pg]) * 128 + ch * 32;
        float v[32];
#pragma unroll
        for (int j = 0; j < 32; j++) v[j] = HT[ch * 32 + j][pg];
#pragma unroll
        for (int q = 0; q < 8; q++)
            *(float4*)(dst + q * 4) = make_float4(v[q * 4 + 0], v[q * 4 + 1],
                                                  v[q * 4 + 2], v[q * 4 + 3]);
    }
}

// ---------------- projection + attention scores ----------------------------

__global__ __launch_bounds__(256) void proj_kernel(
    const float* __restrict__ leaf, const float* __restrict__ hbuf,
    const float* __restrict__ proj, const float* __restrict__ att,
    const int* __restrict__ leaf_idxs,
    float* __restrict__ full, float* __restrict__ scores)
{
    __shared__ float V[16][388];
    const int tid = threadIdx.x;
    const int p0 = blockIdx.x * 16;

    for (int idx = tid; idx < 16 * 96; idx += 256) {
        int p = idx / 96, off = idx % 96;
        const float* src;
        if (off < 16) {
            int l0 = leaf_idxs[(p0 + p) * 2 + 0];
            src = leaf + (size_t)l0 * 64 + off * 4;
        } else if (off < 32) {
            int l1 = leaf_idxs[(p0 + p) * 2 + 1];
            src = leaf + (size_t)l1 * 64 + (off - 16) * 4;
        } else if (off < 64) {
            src = hbuf + (size_t)(p0 + p) * 128 + (off - 32) * 4;
        } else {
            src = hbuf + ((size_t)PPP + p0 + p) * 128 + (off - 64) * 4;
        }
        *(float4*)&V[p][off * 4] = *(const float4*)src;
    }
    __syncthreads();

    const int pp = tid >> 4;
    const int cg = tid & 15;
    const int c0 = cg * 8;

    float acc[8];
#pragma unroll
    for (int j = 0; j < 8; j++) acc[j] = 0.f;

#pragma unroll 4
    for (int k = 0; k < 384; k++) {
        float a = V[pp][k];
        float4 w0 = *(const float4*)(proj + (size_t)k * 128 + c0);
        float4 w1 = *(const float4*)(proj + (size_t)k * 128 + c0 + 4);
        acc[0] = fmaf(a, w0.x, acc[0]);
        acc[1] = fmaf(a, w0.y, acc[1]);
        acc[2] = fmaf(a, w0.z, acc[2]);
        acc[3] = fmaf(a, w0.w, acc[3]);
        acc[4] = fmaf(a, w1.x, acc[4]);
        acc[5] = fmaf(a, w1.y, acc[5]);
        acc[6] = fmaf(a, w1.z, acc[6]);
        acc[7] = fmaf(a, w1.w, acc[7]);
    }

    float* fdst = full + (size_t)(p0 + pp) * 128 + c0;
    *(float4*)fdst = make_float4(acc[0], acc[1], acc[2], acc[3]);
    *(float4*)(fdst + 4) = make_float4(acc[4], acc[5], acc[6], acc[7]);

    float sp = 0.f;
#pragma unroll
    for (int j = 0; j < 8; j++) sp += acc[j] * att[c0 + j];
#pragma unroll
    for (int off = 8; off > 0; off >>= 1) sp += __shfl_down(sp, off, 16);
    if (cg == 0) scores[p0 + pp] = sp;
}

// ---------------- segment softmax + weighted sum ---------------------------

__global__ __launch_bounds__(128) void seg_kernel(
    const float* __restrict__ scores, const float* __restrict__ full,
    const int* __restrict__ seg, float* __restrict__ out)
{
    const int s = blockIdx.x;
    const int tid = threadIdx.x;

    int lo = 0, hi = PPP;
    while (lo < hi) { int mid = (lo + hi) >> 1; if (seg[mid] < s) lo = mid + 1; else hi = mid; }
    const int start = lo;
    lo = start; hi = PPP;
    while (lo < hi) { int mid = (lo + hi) >> 1; if (seg[mid] < s + 1) lo = mid + 1; else hi = mid; }
    const int end = lo;

    if (start >= end) { out[(size_t)s * 128 + tid] = 0.f; return; }

    __shared__ float red[128];

    float mx = -1e30f;
    for (int i = start + tid; i < end; i += 128) mx = fmaxf(mx, scores[i]);
    red[tid] = mx; __syncthreads();
    for (int off = 64; off > 0; off >>= 1) {
        if (tid < off) red[tid] = fmaxf(red[tid], red[tid + off]);
        __syncthreads();
    }
    mx = red[0]; __syncthreads();

    float den = 0.f;
    for (int i = start + tid; i < end; i += 128) den += __expf(scores[i] - mx);
    red[tid] = den; __syncthreads();
    for (int off = 64; off > 0; off >>= 1) {
        if (tid < off) red[tid] += red[tid + off];
        __syncthreads();
    }
    den = red[0];

    float acc = 0.f;
    for (int i = start; i < end; i++)
        acc = fmaf(__expf(scores[i] - mx), full[(size_t)i * 128 + tid], acc);
    out[(size_t)s * 128 + tid] = acc / den;
}

// ---------------- launch ---------------------------------------------------

extern "C" void kernel_launch(void* const* d_in, const int* in_sizes, int n_in,
                              void* d_out, int out_size, void* d_ws, size_t ws_size,
                              hipStream_t stream) {
    (void)in_sizes; (void)n_in; (void)out_size; (void)ws_size;

    const float* leaf = (const float*)d_in[0];
    const float* emb  = (const float*)d_in[1];
    const float* Wf   = (const float*)d_in[2];
    const float* Uf   = (const float*)d_in[3];
    const float* bf   = (const float*)d_in[4];
    const float* Wb   = (const float*)d_in[5];
    const float* Ub   = (const float*)d_in[6];
    const float* bb   = (const float*)d_in[7];
    const float* proj = (const float*)d_in[8];
    const float* att  = (const float*)d_in[9];
    const int* path_elements = (const int*)d_in[10];
    const int* path_lengths  = (const int*)d_in[11];
    const int* leaf_idxs     = (const int*)d_in[12];
    const int* seg           = (const int*)d_in[13];
    float* out = (float*)d_out;

    char* ws = (char*)d_ws;
    int*   order  = (int*)ws;                       // P ints = 80000 B
    int*   bins   = (int*)(ws + 80128);
    int*   cur    = (int*)(ws + 80384);
    float* Zall   = (float*)(ws + 81920);           // 2*VNT*512 f32 = 40,960,000 B
    float* hbuf   = (float*)(ws + 41041920);        // 2*P*128 f32 = 20,480,000 B
    float* full   = (float*)(ws + 61521920);        // P*128 f32 = 10,240,000 B
    float* scores = (float*)(ws + 71761920);        // P f32

    k_zero<<<1, 64, 0, stream>>>(bins);
    k_hist<<<(PPP + 255) / 256, 256, 0, stream>>>(path_lengths, bins);
    k_scan<<<1, 64, 0, stream>>>(bins, cur);
    k_scatter<<<(PPP + 255) / 256, 256, 0, stream>>>(path_lengths, cur, order);

    dim3 gz(VNT / 8, 2);
    zx_kernel<<<gz, 256, 0, stream>>>(emb, Wf, bf, Wb, bb, Zall);

    dim3 g((PPP + PB - 1) / PB, 2);
    lstm_kernel<<<g, 256, 0, stream>>>(Zall, Uf, Ub, path_elements, path_lengths,
                                       order, hbuf);

    proj_kernel<<<PPP / 16, 256, 0, stream>>>(leaf, hbuf, proj, att, leaf_idxs,
                                              full, scores);

    seg_kernel<<<SS, 128, 0, stream>>>(scores, full, seg, out);
}

// Round 4
// 1399.829 us; speedup vs baseline: 1.7553x; 1.7553x over previous
//
#include <hip/hip_runtime.h>
#include <math.h>

#define PPP 20000   // paths
#define TT  30      // max timesteps
#define SS  1000    // samples
#define VNT 10000   // non-terminal vocab
#define PB  64      // paths per LSTM block

typedef __attribute__((ext_vector_type(8))) short short8;
typedef __attribute__((ext_vector_type(4))) float float4v;
typedef unsigned short ushort;
typedef unsigned int uint;

__device__ __forceinline__ ushort f2bf(float x) {
    uint u = __builtin_bit_cast(uint, x);
    uint r = (u + 0x7fffu + ((u >> 16) & 1u)) >> 16;
    return (ushort)r;
}
__device__ __forceinline__ float bf2f(ushort h) {
    uint u = ((uint)h) << 16;
    return __builtin_bit_cast(float, u);
}
__device__ __forceinline__ float fsigmoid(float x) {
    return 1.f / (1.f + __expf(-x));
}
__device__ __forceinline__ float ftanh(float x) {
    return 2.f / (1.f + __expf(-2.f * x)) - 1.f;
}

// ---------------- length bucketing (counting sort, DESCENDING) -------------

__global__ void k_zero(int* bins) {
    if (threadIdx.x < 32) bins[threadIdx.x] = 0;
}
__global__ void k_hist(const int* __restrict__ len, int* __restrict__ bins) {
    int p = blockIdx.x * 256 + threadIdx.x;
    if (p < PPP) atomicAdd(&bins[len[p] - 1], 1);
}
__global__ void k_scan(const int* __restrict__ bins, int* __restrict__ cur) {
    if (threadIdx.x == 0 && blockIdx.x == 0) {
        int ofs = 0;
        for (int l = TT - 1; l >= 0; l--) { cur[l] = ofs; ofs += bins[l]; }
    }
}
__global__ void k_scatter(const int* __restrict__ len, int* __restrict__ cur,
                          int* __restrict__ order) {
    int p = blockIdx.x * 256 + threadIdx.x;
    if (p < PPP) {
        int pos = atomicAdd(&cur[len[p] - 1], 1);
        order[pos] = p;
    }
}

// ---------------- U -> bf16 B-fragment precompute ---------------------------
// Ufrag[d][kb][nt][lane][8] : frag elem j = U[kb*32 + (lane>>4)*8 + j][nt*16 + (lane&15)]

__global__ __launch_bounds__(256) void ufrag_kernel(
    const float* __restrict__ Uf, const float* __restrict__ Ub,
    ushort* __restrict__ Ufrag)
{
    const int kb = blockIdx.x;         // 0..3
    const int d  = blockIdx.y;         // 0..1
    const float* U = d ? Ub : Uf;
    const int tid = threadIdx.x;
    for (int s = tid; s < 2048; s += 256) {
        int nt = s >> 6, lane = s & 63;
        int krow = kb * 32 + (lane >> 4) * 8;
        int col  = nt * 16 + (lane & 15);
        ushort* dst = Ufrag + ((size_t)((d * 4 + kb) * 2048 + s)) * 8;
#pragma unroll
        for (int j = 0; j < 8; j++)
            dst[j] = f2bf(U[(size_t)(krow + j) * 512 + col]);
    }
}

// ---------------- Zx = emb @ W + b  -> bf16, permuted gather layout ---------
// For col c (0..511): g=c>>7, u=c&127, l=u&15, sub=(u>>4)&1, wq=u>>5
// stored at Zx[d][tok][(wq*16+l)*8 + sub*4 + g]

__global__ __launch_bounds__(256) void zx_kernel(
    const float* __restrict__ emb,
    const float* __restrict__ Wf, const float* __restrict__ bf,
    const float* __restrict__ Wb, const float* __restrict__ bb,
    ushort* __restrict__ Zall)
{
    const int dir = blockIdx.y;
    const float* W = dir ? Wb : Wf;
    const float* b = dir ? bb : bf;
    ushort* Z = Zall + (size_t)dir * VNT * 512;

    __shared__ float X[8][128];
    __shared__ float Zb[8][516];
    const int tid = threadIdx.x;
    const int tok0 = blockIdx.x * 8;

    {
        int tr = tid >> 5;
        int c4 = (tid & 31) * 4;
        *(float4*)&X[tr][c4] = *(const float4*)(emb + (size_t)(tok0 + tr) * 128 + c4);
    }
    __syncthreads();

    const int pp = tid >> 5;
    const int cg = tid & 31;
    const int c0 = cg * 16;

    float acc[16];
#pragma unroll
    for (int j = 0; j < 16; j++) acc[j] = 0.f;

    for (int k = 0; k < 128; k++) {
        float a = X[pp][k];
        const float* wr = W + (size_t)k * 512 + c0;
#pragma unroll
        for (int q = 0; q < 4; q++) {
            float4 w = *(const float4*)(wr + q * 4);
            acc[q * 4 + 0] = fmaf(a, w.x, acc[q * 4 + 0]);
            acc[q * 4 + 1] = fmaf(a, w.y, acc[q * 4 + 1]);
            acc[q * 4 + 2] = fmaf(a, w.z, acc[q * 4 + 2]);
            acc[q * 4 + 3] = fmaf(a, w.w, acc[q * 4 + 3]);
        }
    }

    // rotated write into LDS bounce buffer (avoids 16-way bank conflicts)
#pragma unroll
    for (int j = 0; j < 16; j++) {
        int jj = (j + cg) & 15;
        Zb[pp][c0 + jj] = acc[jj] + b[c0 + jj];
    }
    __syncthreads();

    // permuted gather -> bf16 -> coalesced 16B writes
    const int m  = tid & 63;           // (wq,l) pair
    const int wq = m >> 4, l = m & 15;
    const int pp2 = tid >> 6;
#pragma unroll
    for (int h = 0; h < 2; h++) {
        int pt = pp2 + h * 4;
        ushort v[8];
#pragma unroll
        for (int sub = 0; sub < 2; sub++)
#pragma unroll
            for (int g = 0; g < 4; g++)
                v[sub * 4 + g] = f2bf(Zb[pt][g * 128 + wq * 32 + sub * 16 + l]);
        *(int4*)(Z + (size_t)(tok0 + pt) * 512 + m * 8) = *(const int4*)v;
    }
}

// ---------------- MFMA LSTM -------------------------------------------------
// Block: 64 paths, 256 threads (4 waves). Wave w owns gate-cols [w*32,w*32+32)
// of each gate. acc[mt][g][sub] = 16x16 C-tile (M-tile mt, N-tile g*8+w*2+sub).
// h lives in LDS bf16 plane hp[64][136] (A-layout, padded); c fp32 in regs.

typedef const __attribute__((address_space(1))) void GVoid;
typedef __attribute__((address_space(3))) void LVoid;

__global__ __launch_bounds__(256, 2) void lstm_kernel(
    const ushort* __restrict__ Zall,
    const ushort* __restrict__ Ufrag,
    const int* __restrict__ path_elements, const int* __restrict__ path_lengths,
    const int* __restrict__ order,
    float* __restrict__ h_out)   // [2][P][128] fp32
{
    const int dir = blockIdx.y;
    const ushort* ZxD = Zall + (size_t)dir * VNT * 512;
    const ushort* UfD = Ufrag + (size_t)dir * 4 * 16384;

    __shared__ ushort hp[64][136];         // bf16 h plane, A-layout, +8 pad
    __shared__ ushort Ut[32 * 64 * 8];     // one K-block of B-frags (32 KB)
    __shared__ int s_tok[TT][64];
    __shared__ int s_pid[PB];
    __shared__ int s_len[PB];

    const int tid  = threadIdx.x;
    const int w    = tid >> 6;
    const int lane = tid & 63;
    const int quad = lane >> 4;
    const int l    = lane & 15;

    if (tid < PB) {
        int idx = blockIdx.x * PB + tid;
        if (idx > PPP - 1) idx = PPP - 1;
        int pid = order[idx];
        s_pid[tid] = pid;
        s_len[tid] = path_lengths[pid];
    }
    for (int i = tid; i < 64 * 136; i += 256) ((ushort*)hp)[i] = 0;
    __syncthreads();

    // stage all tokens once
    for (int i = tid; i < 64 * TT; i += 256) {
        int p = i & 63, t = i >> 6;
        s_tok[t][p] = path_elements[(size_t)s_pid[p] * TT + t];
    }
    __syncthreads();

    const int maxLen = s_len[0];           // descending sort

    float c_st[4][4][2];                   // [mt][r][sub]
#pragma unroll
    for (int mt = 0; mt < 4; mt++)
#pragma unroll
        for (int r = 0; r < 4; r++)
#pragma unroll
            for (int sub = 0; sub < 2; sub++) c_st[mt][r][sub] = 0.f;

    for (int step = 0; step < maxLen; step++) {
        const int t = dir ? (maxLen - 1 - step) : step;

        float4v acc[4][4][2];              // [mt][g][sub]
#pragma unroll
        for (int mt = 0; mt < 4; mt++)
#pragma unroll
            for (int g = 0; g < 4; g++)
#pragma unroll
                for (int sub = 0; sub < 2; sub++) {
                    float4v z4 = {0.f, 0.f, 0.f, 0.f};
                    acc[mt][g][sub] = z4;
                }

        // K loop: 4 K-blocks of 32
        for (int kb = 0; kb < 4; kb++) {
            {   // stage B-frags for this K-block (32 KB) via async DMA
                const ushort* src = UfD + (size_t)kb * 16384;
#pragma unroll
                for (int j = 0; j < 8; j++) {
                    int off = (j * 256 + tid) * 8;   // elements
                    __builtin_amdgcn_global_load_lds((GVoid*)(src + off),
                                                     (LVoid*)(Ut + off), 16, 0, 0);
                }
            }
            __syncthreads();

            short8 af[4];
#pragma unroll
            for (int mt = 0; mt < 4; mt++)
                af[mt] = *(const short8*)&hp[mt * 16 + l][kb * 32 + quad * 8];

#pragma unroll
            for (int g = 0; g < 4; g++)
#pragma unroll
                for (int sub = 0; sub < 2; sub++) {
                    int nt = g * 8 + w * 2 + sub;
                    short8 bfg = *(const short8*)&Ut[(nt * 64 + lane) * 8];
#pragma unroll
                    for (int mt = 0; mt < 4; mt++)
                        acc[mt][g][sub] = __builtin_amdgcn_mfma_f32_16x16x32_bf16(
                            af[mt], bfg, acc[mt][g][sub], 0, 0, 0);
                }
            __syncthreads();   // all reads of Ut done before next stage
        }

        // gating: z = acc + Zx[token]  (Zx gather: one 16B load per row)
#pragma unroll
        for (int ri = 0; ri < 16; ri++) {
            const int mt = ri >> 2, r = ri & 3;
            const int p = mt * 16 + quad * 4 + r;
            const int tok = s_tok[t][p];
            const int4 zv = *(const int4*)(ZxD + (size_t)tok * 512 + (w * 16 + l) * 8);
            const bool valid = t < s_len[p];
#pragma unroll
            for (int sub = 0; sub < 2; sub++) {
                float zg[4];
#pragma unroll
                for (int g = 0; g < 4; g++) {
                    int pos = sub * 4 + g;
                    uint word = ((const uint*)&zv)[pos >> 1];
                    ushort us = (pos & 1) ? (ushort)(word >> 16) : (ushort)(word & 0xffff);
                    zg[g] = acc[mt][g][sub][r] + bf2f(us);
                }
                float ig = fsigmoid(zg[0]);
                float fg = fsigmoid(zg[1]);
                float gg = ftanh(zg[2]);
                float og = fsigmoid(zg[3]);
                float cn = fg * c_st[mt][r][sub] + ig * gg;
                float hn = og * ftanh(cn);
                if (valid) {
                    c_st[mt][r][sub] = cn;
                    hp[p][w * 32 + sub * 16 + l] = f2bf(hn);
                }
            }
        }
        __syncthreads();   // h writes visible before next step's A-reads
    }

    // epilogue: hp (bf16) -> h_out (fp32)
    {
        const int pg = tid >> 2;       // 0..63
        const int ch = tid & 3;        // 0..3 -> cols ch*32..+31
        float* dst = h_out + ((size_t)dir * PPP + s_pid[pg]) * 128 + ch * 32;
#pragma unroll
        for (int q = 0; q < 4; q++) {
            short8 v = *(const short8*)&hp[pg][ch * 32 + q * 8];
            float o[8];
#pragma unroll
            for (int j = 0; j < 8; j++) o[j] = bf2f((ushort)v[j]);
            *(float4*)(dst + q * 8)     = make_float4(o[0], o[1], o[2], o[3]);
            *(float4*)(dst + q * 8 + 4) = make_float4(o[4], o[5], o[6], o[7]);
        }
    }
}

// ---------------- projection + attention scores ----------------------------

__global__ __launch_bounds__(256) void proj_kernel(
    const float* __restrict__ leaf, const float* __restrict__ hbuf,
    const float* __restrict__ proj, const float* __restrict__ att,
    const int* __restrict__ leaf_idxs,
    float* __restrict__ full, float* __restrict__ scores)
{
    __shared__ float V[16][388];
    const int tid = threadIdx.x;
    const int p0 = blockIdx.x * 16;

    for (int idx = tid; idx < 16 * 96; idx += 256) {
        int p = idx / 96, off = idx % 96;
        const float* src;
        if (off < 16) {
            int l0 = leaf_idxs[(p0 + p) * 2 + 0];
            src = leaf + (size_t)l0 * 64 + off * 4;
        } else if (off < 32) {
            int l1 = leaf_idxs[(p0 + p) * 2 + 1];
            src = leaf + (size_t)l1 * 64 + (off - 16) * 4;
        } else if (off < 64) {
            src = hbuf + (size_t)(p0 + p) * 128 + (off - 32) * 4;
        } else {
            src = hbuf + ((size_t)PPP + p0 + p) * 128 + (off - 64) * 4;
        }
        *(float4*)&V[p][off * 4] = *(const float4*)src;
    }
    __syncthreads();

    const int pp = tid >> 4;
    const int cg = tid & 15;
    const int c0 = cg * 8;

    float acc[8];
#pragma unroll
    for (int j = 0; j < 8; j++) acc[j] = 0.f;

#pragma unroll 4
    for (int k = 0; k < 384; k++) {
        float a = V[pp][k];
        float4 w0 = *(const float4*)(proj + (size_t)k * 128 + c0);
        float4 w1 = *(const float4*)(proj + (size_t)k * 128 + c0 + 4);
        acc[0] = fmaf(a, w0.x, acc[0]);
        acc[1] = fmaf(a, w0.y, acc[1]);
        acc[2] = fmaf(a, w0.z, acc[2]);
        acc[3] = fmaf(a, w0.w, acc[3]);
        acc[4] = fmaf(a, w1.x, acc[4]);
        acc[5] = fmaf(a, w1.y, acc[5]);
        acc[6] = fmaf(a, w1.z, acc[6]);
        acc[7] = fmaf(a, w1.w, acc[7]);
    }

    float* fdst = full + (size_t)(p0 + pp) * 128 + c0;
    *(float4*)fdst = make_float4(acc[0], acc[1], acc[2], acc[3]);
    *(float4*)(fdst + 4) = make_float4(acc[4], acc[5], acc[6], acc[7]);

    float sp = 0.f;
#pragma unroll
    for (int j = 0; j < 8; j++) sp += acc[j] * att[c0 + j];
#pragma unroll
    for (int off = 8; off > 0; off >>= 1) sp += __shfl_down(sp, off, 16);
    if (cg == 0) scores[p0 + pp] = sp;
}

// ---------------- segment softmax + weighted sum ---------------------------

__global__ __launch_bounds__(128) void seg_kernel(
    const float* __restrict__ scores, const float* __restrict__ full,
    const int* __restrict__ seg, float* __restrict__ out)
{
    const int s = blockIdx.x;
    const int tid = threadIdx.x;

    int lo = 0, hi = PPP;
    while (lo < hi) { int mid = (lo + hi) >> 1; if (seg[mid] < s) lo = mid + 1; else hi = mid; }
    const int start = lo;
    lo = start; hi = PPP;
    while (lo < hi) { int mid = (lo + hi) >> 1; if (seg[mid] < s + 1) lo = mid + 1; else hi = mid; }
    const int end = lo;

    if (start >= end) { out[(size_t)s * 128 + tid] = 0.f; return; }

    __shared__ float red[128];

    float mx = -1e30f;
    for (int i = start + tid; i < end; i += 128) mx = fmaxf(mx, scores[i]);
    red[tid] = mx; __syncthreads();
    for (int off = 64; off > 0; off >>= 1) {
        if (tid < off) red[tid] = fmaxf(red[tid], red[tid + off]);
        __syncthreads();
    }
    mx = red[0]; __syncthreads();

    float den = 0.f;
    for (int i = start + tid; i < end; i += 128) den += __expf(scores[i] - mx);
    red[tid] = den; __syncthreads();
    for (int off = 64; off > 0; off >>= 1) {
        if (tid < off) red[tid] += red[tid + off];
        __syncthreads();
    }
    den = red[0];

    float acc = 0.f;
    for (int i = start; i < end; i++)
        acc = fmaf(__expf(scores[i] - mx), full[(size_t)i * 128 + tid], acc);
    out[(size_t)s * 128 + tid] = acc / den;
}

// ---------------- launch ---------------------------------------------------

extern "C" void kernel_launch(void* const* d_in, const int* in_sizes, int n_in,
                              void* d_out, int out_size, void* d_ws, size_t ws_size,
                              hipStream_t stream) {
    (void)in_sizes; (void)n_in; (void)out_size; (void)ws_size;

    const float* leaf = (const float*)d_in[0];
    const float* emb  = (const float*)d_in[1];
    const float* Wf   = (const float*)d_in[2];
    const float* Uf   = (const float*)d_in[3];
    const float* bf   = (const float*)d_in[4];
    const float* Wb   = (const float*)d_in[5];
    const float* Ub   = (const float*)d_in[6];
    const float* bb   = (const float*)d_in[7];
    const float* proj = (const float*)d_in[8];
    const float* att  = (const float*)d_in[9];
    const int* path_elements = (const int*)d_in[10];
    const int* path_lengths  = (const int*)d_in[11];
    const int* leaf_idxs     = (const int*)d_in[12];
    const int* seg           = (const int*)d_in[13];
    float* out = (float*)d_out;

    char* ws = (char*)d_ws;
    int*    order  = (int*)ws;                         // 80000 B
    int*    bins   = (int*)(ws + 80128);
    int*    cur    = (int*)(ws + 80384);
    ushort* Zall   = (ushort*)(ws + 81920);            // 2*VNT*512*2 = 20,480,000
    ushort* Ufrag  = (ushort*)(ws + 20561920);         // 262,144
    float*  hbuf   = (float*)(ws + 20824064);          // 2*P*128*4 = 20,480,000
    float*  full   = (float*)(ws + 41304064);          // 10,240,000
    float*  scores = (float*)(ws + 51544064);          // 80,000

    k_zero<<<1, 64, 0, stream>>>(bins);
    k_hist<<<(PPP + 255) / 256, 256, 0, stream>>>(path_lengths, bins);
    k_scan<<<1, 64, 0, stream>>>(bins, cur);
    k_scatter<<<(PPP + 255) / 256, 256, 0, stream>>>(path_lengths, cur, order);

    dim3 gu(4, 2);
    ufrag_kernel<<<gu, 256, 0, stream>>>(Uf, Ub, Ufrag);

    dim3 gz(VNT / 8, 2);
    zx_kernel<<<gz, 256, 0, stream>>>(emb, Wf, bf, Wb, bb, Zall);

    dim3 g((PPP + PB - 1) / PB, 2);
    lstm_kernel<<<g, 256, 0, stream>>>(Zall, Ufrag, path_elements, path_lengths,
                                       order, hbuf);

    proj_kernel<<<PPP / 16, 256, 0, stream>>>(leaf, hbuf, proj, att, leaf_idxs,
                                              full, scores);

    seg_kernel<<<SS, 128, 0, stream>>>(scores, full, seg, out);
}

// Round 5
// 932.139 us; speedup vs baseline: 2.6359x; 1.5017x over previous
//
#include <hip/hip_runtime.h>
#include <math.h>

#define PPP 20000   // paths
#define TT  30      // max timesteps
#define SS  1000    // samples
#define VNT 10000   // non-terminal vocab
#define PB  64      // paths per LSTM block

typedef __attribute__((ext_vector_type(8))) short short8;
typedef __attribute__((ext_vector_type(4))) float float4v;
typedef unsigned short ushort;
typedef unsigned int uint;

__device__ __forceinline__ ushort f2bf(float x) {
    uint u = __builtin_bit_cast(uint, x);
    uint r = (u + 0x7fffu + ((u >> 16) & 1u)) >> 16;
    return (ushort)r;
}
__device__ __forceinline__ float bf2f(ushort h) {
    uint u = ((uint)h) << 16;
    return __builtin_bit_cast(float, u);
}
__device__ __forceinline__ float fsigmoid(float x) {
    return 1.f / (1.f + __expf(-x));
}
__device__ __forceinline__ float ftanh(float x) {
    return 2.f / (1.f + __expf(-2.f * x)) - 1.f;
}

// ---------------- length bucketing (counting sort, DESCENDING) -------------

__global__ void k_zero(int* bins) {
    if (threadIdx.x < 32) bins[threadIdx.x] = 0;
}
__global__ void k_hist(const int* __restrict__ len, int* __restrict__ bins) {
    int p = blockIdx.x * 256 + threadIdx.x;
    if (p < PPP) atomicAdd(&bins[len[p] - 1], 1);
}
__global__ void k_scan(const int* __restrict__ bins, int* __restrict__ cur) {
    if (threadIdx.x == 0 && blockIdx.x == 0) {
        int ofs = 0;
        for (int l = TT - 1; l >= 0; l--) { cur[l] = ofs; ofs += bins[l]; }
    }
}
__global__ void k_scatter(const int* __restrict__ len, int* __restrict__ cur,
                          int* __restrict__ order) {
    int p = blockIdx.x * 256 + threadIdx.x;
    if (p < PPP) {
        int pos = atomicAdd(&cur[len[p] - 1], 1);
        order[pos] = p;
    }
}

// ---------------- U -> bf16 B-fragment precompute ---------------------------
// slot s per dir (0..8191): lane=s&63, kb=(s>>6)&3, g=(s>>8)&3, w=s>>10
// frag elem j = U[kb*32 + (lane>>4)*8 + j][g*128 + w*16 + (lane&15)]

__global__ __launch_bounds__(256) void ufrag_kernel(
    const float* __restrict__ Uf, const float* __restrict__ Ub,
    ushort* __restrict__ Ufrag)
{
    const int d = blockIdx.y;
    const float* U = d ? Ub : Uf;
#pragma unroll
    for (int i = 0; i < 4; i++) {
        int s = blockIdx.x * 1024 + i * 256 + threadIdx.x;
        int lane = s & 63, kb = (s >> 6) & 3, g = (s >> 8) & 3, w = s >> 10;
        int krow = kb * 32 + (lane >> 4) * 8;
        int col  = g * 128 + w * 16 + (lane & 15);
        ushort* dst = Ufrag + ((size_t)d * 8192 + s) * 8;
#pragma unroll
        for (int j = 0; j < 8; j++)
            dst[j] = f2bf(U[(size_t)(krow + j) * 512 + col]);
    }
}

// ---------------- Zx = emb @ W + b  -> bf16, gather layout ------------------
// col c (0..511): g=c>>7, u=c&127 -> stored at Zx[d][tok][u*4 + g]

__global__ __launch_bounds__(256) void zx_kernel(
    const float* __restrict__ emb,
    const float* __restrict__ Wf, const float* __restrict__ bf,
    const float* __restrict__ Wb, const float* __restrict__ bb,
    ushort* __restrict__ Zall)
{
    const int dir = blockIdx.y;
    const float* W = dir ? Wb : Wf;
    const float* b = dir ? bb : bf;
    ushort* Z = Zall + (size_t)dir * VNT * 512;

    __shared__ float X[8][128];
    __shared__ float Zb[8][516];
    const int tid = threadIdx.x;
    const int tok0 = blockIdx.x * 8;

    {
        int tr = tid >> 5;
        int c4 = (tid & 31) * 4;
        *(float4*)&X[tr][c4] = *(const float4*)(emb + (size_t)(tok0 + tr) * 128 + c4);
    }
    __syncthreads();

    const int pp = tid >> 5;
    const int cg = tid & 31;
    const int c0 = cg * 16;

    float acc[16];
#pragma unroll
    for (int j = 0; j < 16; j++) acc[j] = 0.f;

    for (int k = 0; k < 128; k++) {
        float a = X[pp][k];
        const float* wr = W + (size_t)k * 512 + c0;
#pragma unroll
        for (int q = 0; q < 4; q++) {
            float4 w = *(const float4*)(wr + q * 4);
            acc[q * 4 + 0] = fmaf(a, w.x, acc[q * 4 + 0]);
            acc[q * 4 + 1] = fmaf(a, w.y, acc[q * 4 + 1]);
            acc[q * 4 + 2] = fmaf(a, w.z, acc[q * 4 + 2]);
            acc[q * 4 + 3] = fmaf(a, w.w, acc[q * 4 + 3]);
        }
    }

    // rotated write into LDS bounce buffer (avoids bank conflicts)
#pragma unroll
    for (int j = 0; j < 16; j++) {
        int jj = (j + cg) & 15;
        Zb[pp][c0 + jj] = acc[jj] + b[c0 + jj];
    }
    __syncthreads();

    // pack: 8 tokens x 128 col-slots, 4 gates -> 8 B each, coalesced
#pragma unroll
    for (int i = 0; i < 4; i++) {
        int s = i * 256 + tid;          // 0..1023
        int pt = s >> 7;                // token 0..7
        int pair = s & 127;             // col u = w*16+l
        ushort v[4];
#pragma unroll
        for (int g = 0; g < 4; g++)
            v[g] = f2bf(Zb[pt][g * 128 + pair]);
        *(uint2*)(Z + (size_t)(tok0 + pt) * 512 + pair * 4) = *(const uint2*)v;
    }
}

// ---------------- MFMA LSTM -------------------------------------------------
// Block: 64 paths, 512 threads (8 waves). Wave w owns hidden cols
// [w*16, w*16+16) of each of the 4 gates. B-fragments (U) live in REGISTERS,
// loaded once. h: LDS bf16 plane hp[64][140] (A-layout, pad->~2-way free).
// Per step: Zx prefetch (16x8B) -> 4 K-blocks x 16 MFMA -> barrier ->
// register gating -> barrier. c fp32 in registers.

__global__ __launch_bounds__(512, 2) void lstm_kernel(
    const ushort* __restrict__ Zall,
    const ushort* __restrict__ Ufrag,
    const int* __restrict__ path_elements, const int* __restrict__ path_lengths,
    const int* __restrict__ order,
    float* __restrict__ h_out)   // [2][P][128] fp32
{
    const int dir = blockIdx.y;
    const ushort* ZxD = Zall + (size_t)dir * VNT * 512;
    const ushort* UfD = Ufrag + (size_t)dir * 65536;

    __shared__ ushort hp[64][140];     // bf16 h plane (A-layout, padded)
    __shared__ int s_tok[TT][64];
    __shared__ int s_pid[PB];
    __shared__ int s_len[PB];

    const int tid  = threadIdx.x;
    const int w    = tid >> 6;         // wave 0..7
    const int lane = tid & 63;
    const int quad = lane >> 4;
    const int l    = lane & 15;

    if (tid < PB) {
        int idx = blockIdx.x * PB + tid;
        if (idx > PPP - 1) idx = PPP - 1;
        int pid = order[idx];
        s_pid[tid] = pid;
        s_len[tid] = path_lengths[pid];
    }
    for (int i = tid; i < 64 * 70; i += 512) ((uint*)hp)[i] = 0;
    __syncthreads();

    for (int i = tid; i < 64 * TT; i += 512) {
        int p = i & 63, t = i >> 6;
        s_tok[t][p] = path_elements[(size_t)s_pid[p] * TT + t];
    }

    // B-fragments in registers: [g][kb]
    short8 bfrag[4][4];
#pragma unroll
    for (int g = 0; g < 4; g++)
#pragma unroll
        for (int kb = 0; kb < 4; kb++)
            bfrag[g][kb] = *(const short8*)(UfD + (size_t)(((w * 4 + g) * 4 + kb) * 64 + lane) * 8);

    __syncthreads();

    const int maxLen = s_len[0];       // descending sort

    int lenp[16];
#pragma unroll
    for (int mt = 0; mt < 4; mt++)
#pragma unroll
        for (int r = 0; r < 4; r++)
            lenp[mt * 4 + r] = s_len[mt * 16 + quad * 4 + r];

    float c_st[16];
#pragma unroll
    for (int i = 0; i < 16; i++) c_st[i] = 0.f;

    for (int step = 0; step < maxLen; step++) {
        const int t = dir ? (maxLen - 1 - step) : step;

        // Zx prefetch: one 8B load per owned (path,row) -> in flight over MFMA
        uint2 zv[16];
#pragma unroll
        for (int mt = 0; mt < 4; mt++)
#pragma unroll
            for (int r = 0; r < 4; r++) {
                int tok = s_tok[t][mt * 16 + quad * 4 + r];
                zv[mt * 4 + r] = *(const uint2*)(ZxD + (size_t)tok * 512 + (w * 16 + l) * 4);
            }

        float4v acc[4][4];             // [mt][g]
#pragma unroll
        for (int mt = 0; mt < 4; mt++)
#pragma unroll
            for (int g = 0; g < 4; g++) {
                float4v z4 = {0.f, 0.f, 0.f, 0.f};
                acc[mt][g] = z4;
            }

#pragma unroll
        for (int kb = 0; kb < 4; kb++) {
            short8 af[4];
#pragma unroll
            for (int mt = 0; mt < 4; mt++)
                af[mt] = *(const short8*)&hp[mt * 16 + l][kb * 32 + quad * 8];
#pragma unroll
            for (int g = 0; g < 4; g++)
#pragma unroll
                for (int mt = 0; mt < 4; mt++)
                    acc[mt][g] = __builtin_amdgcn_mfma_f32_16x16x32_bf16(
                        af[mt], bfrag[g][kb], acc[mt][g], 0, 0, 0);
        }
        __syncthreads();   // all hp reads done before gating writes

        // gating: z = acc + Zx
#pragma unroll
        for (int mt = 0; mt < 4; mt++)
#pragma unroll
            for (int r = 0; r < 4; r++) {
                const int p = mt * 16 + quad * 4 + r;
                const bool valid = t < lenp[mt * 4 + r];
                const uint2 z2 = zv[mt * 4 + r];
                float zi = acc[mt][0][r] + bf2f((ushort)(z2.x & 0xffff));
                float zf = acc[mt][1][r] + bf2f((ushort)(z2.x >> 16));
                float zg = acc[mt][2][r] + bf2f((ushort)(z2.y & 0xffff));
                float zo = acc[mt][3][r] + bf2f((ushort)(z2.y >> 16));
                float ig = fsigmoid(zi);
                float fg = fsigmoid(zf);
                float gg = ftanh(zg);
                float og = fsigmoid(zo);
                float cn = fg * c_st[mt * 4 + r] + ig * gg;
                float hn = og * ftanh(cn);
                if (valid) {
                    c_st[mt * 4 + r] = cn;
                    hp[p][w * 16 + l] = f2bf(hn);
                }
            }
        __syncthreads();   // h writes visible before next step's A-reads
    }

    // epilogue: hp (bf16) -> h_out (fp32); thread -> path pg, cols ch*16..+15
    {
        const int pg = tid >> 3;       // 0..63
        const int ch = tid & 7;        // 0..7
        float* dst = h_out + ((size_t)dir * PPP + s_pid[pg]) * 128 + ch * 16;
#pragma unroll
        for (int q = 0; q < 2; q++) {
            short8 v = *(const short8*)&hp[pg][ch * 16 + q * 8];
            float o[8];
#pragma unroll
            for (int j = 0; j < 8; j++) o[j] = bf2f((ushort)v[j]);
            *(float4*)(dst + q * 8)     = make_float4(o[0], o[1], o[2], o[3]);
            *(float4*)(dst + q * 8 + 4) = make_float4(o[4], o[5], o[6], o[7]);
        }
    }
}

// ---------------- projection + attention scores ----------------------------

__global__ __launch_bounds__(256) void proj_kernel(
    const float* __restrict__ leaf, const float* __restrict__ hbuf,
    const float* __restrict__ proj, const float* __restrict__ att,
    const int* __restrict__ leaf_idxs,
    float* __restrict__ full, float* __restrict__ scores)
{
    __shared__ float V[16][388];
    const int tid = threadIdx.x;
    const int p0 = blockIdx.x * 16;

    for (int idx = tid; idx < 16 * 96; idx += 256) {
        int p = idx / 96, off = idx % 96;
        const float* src;
        if (off < 16) {
            int l0 = leaf_idxs[(p0 + p) * 2 + 0];
            src = leaf + (size_t)l0 * 64 + off * 4;
        } else if (off < 32) {
            int l1 = leaf_idxs[(p0 + p) * 2 + 1];
            src = leaf + (size_t)l1 * 64 + (off - 16) * 4;
        } else if (off < 64) {
            src = hbuf + (size_t)(p0 + p) * 128 + (off - 32) * 4;
        } else {
            src = hbuf + ((size_t)PPP + p0 + p) * 128 + (off - 64) * 4;
        }
        *(float4*)&V[p][off * 4] = *(const float4*)src;
    }
    __syncthreads();

    const int pp = tid >> 4;
    const int cg = tid & 15;
    const int c0 = cg * 8;

    float acc[8];
#pragma unroll
    for (int j = 0; j < 8; j++) acc[j] = 0.f;

#pragma unroll 4
    for (int k = 0; k < 384; k++) {
        float a = V[pp][k];
        float4 w0 = *(const float4*)(proj + (size_t)k * 128 + c0);
        float4 w1 = *(const float4*)(proj + (size_t)k * 128 + c0 + 4);
        acc[0] = fmaf(a, w0.x, acc[0]);
        acc[1] = fmaf(a, w0.y, acc[1]);
        acc[2] = fmaf(a, w0.z, acc[2]);
        acc[3] = fmaf(a, w0.w, acc[3]);
        acc[4] = fmaf(a, w1.x, acc[4]);
        acc[5] = fmaf(a, w1.y, acc[5]);
        acc[6] = fmaf(a, w1.z, acc[6]);
        acc[7] = fmaf(a, w1.w, acc[7]);
    }

    float* fdst = full + (size_t)(p0 + pp) * 128 + c0;
    *(float4*)fdst = make_float4(acc[0], acc[1], acc[2], acc[3]);
    *(float4*)(fdst + 4) = make_float4(acc[4], acc[5], acc[6], acc[7]);

    float sp = 0.f;
#pragma unroll
    for (int j = 0; j < 8; j++) sp += acc[j] * att[c0 + j];
#pragma unroll
    for (int off = 8; off > 0; off >>= 1) sp += __shfl_down(sp, off, 16);
    if (cg == 0) scores[p0 + pp] = sp;
}

// ---------------- segment softmax + weighted sum ---------------------------

__global__ __launch_bounds__(128) void seg_kernel(
    const float* __restrict__ scores, const float* __restrict__ full,
    const int* __restrict__ seg, float* __restrict__ out)
{
    const int s = blockIdx.x;
    const int tid = threadIdx.x;

    int lo = 0, hi = PPP;
    while (lo < hi) { int mid = (lo + hi) >> 1; if (seg[mid] < s) lo = mid + 1; else hi = mid; }
    const int start = lo;
    lo = start; hi = PPP;
    while (lo < hi) { int mid = (lo + hi) >> 1; if (seg[mid] < s + 1) lo = mid + 1; else hi = mid; }
    const int end = lo;

    if (start >= end) { out[(size_t)s * 128 + tid] = 0.f; return; }

    __shared__ float red[128];

    float mx = -1e30f;
    for (int i = start + tid; i < end; i += 128) mx = fmaxf(mx, scores[i]);
    red[tid] = mx; __syncthreads();
    for (int off = 64; off > 0; off >>= 1) {
        if (tid < off) red[tid] = fmaxf(red[tid], red[tid + off]);
        __syncthreads();
    }
    mx = red[0]; __syncthreads();

    float den = 0.f;
    for (int i = start + tid; i < end; i += 128) den += __expf(scores[i] - mx);
    red[tid] = den; __syncthreads();
    for (int off = 64; off > 0; off >>= 1) {
        if (tid < off) red[tid] += red[tid + off];
        __syncthreads();
    }
    den = red[0];

    float acc = 0.f;
    for (int i = start; i < end; i++)
        acc = fmaf(__expf(scores[i] - mx), full[(size_t)i * 128 + tid], acc);
    out[(size_t)s * 128 + tid] = acc / den;
}

// ---------------- launch ---------------------------------------------------

extern "C" void kernel_launch(void* const* d_in, const int* in_sizes, int n_in,
                              void* d_out, int out_size, void* d_ws, size_t ws_size,
                              hipStream_t stream) {
    (void)in_sizes; (void)n_in; (void)out_size; (void)ws_size;

    const float* leaf = (const float*)d_in[0];
    const float* emb  = (const float*)d_in[1];
    const float* Wf   = (const float*)d_in[2];
    const float* Uf   = (const float*)d_in[3];
    const float* bf   = (const float*)d_in[4];
    const float* Wb   = (const float*)d_in[5];
    const float* Ub   = (const float*)d_in[6];
    const float* bb   = (const float*)d_in[7];
    const float* proj = (const float*)d_in[8];
    const float* att  = (const float*)d_in[9];
    const int* path_elements = (const int*)d_in[10];
    const int* path_lengths  = (const int*)d_in[11];
    const int* leaf_idxs     = (const int*)d_in[12];
    const int* seg           = (const int*)d_in[13];
    float* out = (float*)d_out;

    char* ws = (char*)d_ws;
    int*    order  = (int*)ws;                         // 80000 B
    int*    bins   = (int*)(ws + 80128);
    int*    cur    = (int*)(ws + 80384);
    ushort* Zall   = (ushort*)(ws + 81920);            // 2*VNT*512*2 = 20,480,000
    ushort* Ufrag  = (ushort*)(ws + 20561920);         // 262,144
    float*  hbuf   = (float*)(ws + 20824064);          // 2*P*128*4 = 20,480,000
    float*  full   = (float*)(ws + 41304064);          // 10,240,000
    float*  scores = (float*)(ws + 51544064);          // 80,000

    k_zero<<<1, 64, 0, stream>>>(bins);
    k_hist<<<(PPP + 255) / 256, 256, 0, stream>>>(path_lengths, bins);
    k_scan<<<1, 64, 0, stream>>>(bins, cur);
    k_scatter<<<(PPP + 255) / 256, 256, 0, stream>>>(path_lengths, cur, order);

    dim3 gu(8, 2);
    ufrag_kernel<<<gu, 256, 0, stream>>>(Uf, Ub, Ufrag);

    dim3 gz(VNT / 8, 2);
    zx_kernel<<<gz, 256, 0, stream>>>(emb, Wf, bf, Wb, bb, Zall);

    dim3 g((PPP + PB - 1) / PB, 2);
    lstm_kernel<<<g, 512, 0, stream>>>(Zall, Ufrag, path_elements, path_lengths,
                                       order, hbuf);

    proj_kernel<<<PPP / 16, 256, 0, stream>>>(leaf, hbuf, proj, att, leaf_idxs,
                                              full, scores);

    seg_kernel<<<SS, 128, 0, stream>>>(scores, full, seg, out);
}

// Round 6
// 827.611 us; speedup vs baseline: 2.9689x; 1.1263x over previous
//
#include <hip/hip_runtime.h>
#include <math.h>

#define PPP 20000   // paths
#define TT  30      // max timesteps
#define SS  1000    // samples
#define VNT 10000   // non-terminal vocab
#define PB  64      // paths per LSTM block

typedef __attribute__((ext_vector_type(8))) short short8;
typedef __attribute__((ext_vector_type(4))) float float4v;
typedef unsigned short ushort;
typedef unsigned int uint;

__device__ __forceinline__ ushort f2bf(float x) {
    uint u = __builtin_bit_cast(uint, x);
    uint r = (u + 0x7fffu + ((u >> 16) & 1u)) >> 16;
    return (ushort)r;
}
__device__ __forceinline__ float bf2f(ushort h) {
    uint u = ((uint)h) << 16;
    return __builtin_bit_cast(float, u);
}
__device__ __forceinline__ float fsigmoid(float x) {
    return 1.f / (1.f + __expf(-x));
}
__device__ __forceinline__ float ftanh(float x) {
    return 2.f / (1.f + __expf(-2.f * x)) - 1.f;
}

// ---------------- length bucketing (counting sort, DESCENDING) -------------

__global__ void k_zero(int* bins) {
    if (threadIdx.x < 32) bins[threadIdx.x] = 0;
}
__global__ void k_hist(const int* __restrict__ len, int* __restrict__ bins,
                       float* __restrict__ scores) {
    int p = blockIdx.x * 256 + threadIdx.x;
    if (p < PPP) { atomicAdd(&bins[len[p] - 1], 1); scores[p] = 0.f; }
}
__global__ void k_scan(const int* __restrict__ bins, int* __restrict__ cur) {
    if (threadIdx.x == 0 && blockIdx.x == 0) {
        int ofs = 0;
        for (int l = TT - 1; l >= 0; l--) { cur[l] = ofs; ofs += bins[l]; }
    }
}
__global__ void k_scatter(const int* __restrict__ len, int* __restrict__ cur,
                          int* __restrict__ order) {
    int p = blockIdx.x * 256 + threadIdx.x;
    if (p < PPP) {
        int pos = atomicAdd(&cur[len[p] - 1], 1);
        order[pos] = p;
    }
}

// ---------------- U -> bf16 B-fragment precompute ---------------------------
// slot s per dir: lane=s&63, kb=(s>>6)&3, g=(s>>8)&3, w=s>>10
// frag elem j = U[kb*32 + (lane>>4)*8 + j][g*128 + w*16 + (lane&15)]

__global__ __launch_bounds__(256) void ufrag_kernel(
    const float* __restrict__ Uf, const float* __restrict__ Ub,
    ushort* __restrict__ Ufrag)
{
    const int d = blockIdx.y;
    const float* U = d ? Ub : Uf;
#pragma unroll
    for (int i = 0; i < 4; i++) {
        int s = blockIdx.x * 1024 + i * 256 + threadIdx.x;
        int lane = s & 63, kb = (s >> 6) & 3, g = (s >> 8) & 3, w = s >> 10;
        int krow = kb * 32 + (lane >> 4) * 8;
        int col  = g * 128 + w * 16 + (lane & 15);
        ushort* dst = Ufrag + ((size_t)d * 8192 + s) * 8;
#pragma unroll
        for (int j = 0; j < 8; j++)
            dst[j] = f2bf(U[(size_t)(krow + j) * 512 + col]);
    }
}

// ---------------- proj -> bf16 B-fragment precompute ------------------------
// slot s (0..6143): lane=s&63, kb=(s>>6)%12, nt=s/768
// frag elem j = proj[kb*32 + (lane>>4)*8 + j][nt*16 + (lane&15)]

__global__ __launch_bounds__(256) void projfrag_kernel(
    const float* __restrict__ proj, ushort* __restrict__ pfrag)
{
    int s = blockIdx.x * 256 + threadIdx.x;    // grid 24 -> 6144
    int lane = s & 63;
    int kb = (s >> 6) % 12;
    int nt = s / 768;
    int krow = kb * 32 + (lane >> 4) * 8;
    int col  = nt * 16 + (lane & 15);
    ushort* dst = pfrag + (size_t)s * 8;
#pragma unroll
    for (int j = 0; j < 8; j++)
        dst[j] = f2bf(proj[(size_t)(krow + j) * 128 + col]);
}

// ---------------- Zx = emb @ W + b  -> bf16, gather layout ------------------
// col c (0..511): g=c>>7, u=c&127 -> stored at Zx[d][tok][u*4 + g]

__global__ __launch_bounds__(256) void zx_kernel(
    const float* __restrict__ emb,
    const float* __restrict__ Wf, const float* __restrict__ bf,
    const float* __restrict__ Wb, const float* __restrict__ bb,
    ushort* __restrict__ Zall)
{
    const int dir = blockIdx.y;
    const float* W = dir ? Wb : Wf;
    const float* b = dir ? bb : bf;
    ushort* Z = Zall + (size_t)dir * VNT * 512;

    __shared__ float X[8][128];
    __shared__ float Zb[8][516];
    const int tid = threadIdx.x;
    const int tok0 = blockIdx.x * 8;

    {
        int tr = tid >> 5;
        int c4 = (tid & 31) * 4;
        *(float4*)&X[tr][c4] = *(const float4*)(emb + (size_t)(tok0 + tr) * 128 + c4);
    }
    __syncthreads();

    const int pp = tid >> 5;
    const int cg = tid & 31;
    const int c0 = cg * 16;

    float acc[16];
#pragma unroll
    for (int j = 0; j < 16; j++) acc[j] = 0.f;

    for (int k = 0; k < 128; k++) {
        float a = X[pp][k];
        const float* wr = W + (size_t)k * 512 + c0;
#pragma unroll
        for (int q = 0; q < 4; q++) {
            float4 w = *(const float4*)(wr + q * 4);
            acc[q * 4 + 0] = fmaf(a, w.x, acc[q * 4 + 0]);
            acc[q * 4 + 1] = fmaf(a, w.y, acc[q * 4 + 1]);
            acc[q * 4 + 2] = fmaf(a, w.z, acc[q * 4 + 2]);
            acc[q * 4 + 3] = fmaf(a, w.w, acc[q * 4 + 3]);
        }
    }

    // rotated write into LDS bounce buffer (avoids bank conflicts)
#pragma unroll
    for (int j = 0; j < 16; j++) {
        int jj = (j + cg) & 15;
        Zb[pp][c0 + jj] = acc[jj] + b[c0 + jj];
    }
    __syncthreads();

#pragma unroll
    for (int i = 0; i < 4; i++) {
        int s = i * 256 + tid;          // 0..1023
        int pt = s >> 7;                // token 0..7
        int pair = s & 127;             // col u
        ushort v[4];
#pragma unroll
        for (int g = 0; g < 4; g++)
            v[g] = f2bf(Zb[pt][g * 128 + pair]);
        *(uint2*)(Z + (size_t)(tok0 + pt) * 512 + pair * 4) = *(const uint2*)v;
    }
}

// ---------------- MFMA LSTM -------------------------------------------------
// 64 paths, 512 threads (8 waves). Wave w owns hidden cols [w*16,w*16+16) of
// each gate; U B-frags in registers. h: double-buffered bf16 planes
// hp[2][64][144] -> ONE barrier per step. Masked paths carry h via read-old.

__global__ __launch_bounds__(512, 2) void lstm_kernel(
    const ushort* __restrict__ Zall,
    const ushort* __restrict__ Ufrag,
    const int* __restrict__ path_elements, const int* __restrict__ path_lengths,
    const int* __restrict__ order,
    ushort* __restrict__ h_out)   // bf16 [2][P][128]
{
    const int dir = blockIdx.y;
    const ushort* ZxD = Zall + (size_t)dir * VNT * 512;
    const ushort* UfD = Ufrag + (size_t)dir * 65536;

    __shared__ ushort hp[2][64][144];  // bf16 h planes (A-layout, 16B-aligned rows)
    __shared__ int s_tok[TT][64];
    __shared__ int s_pid[PB];
    __shared__ int s_len[PB];

    const int tid  = threadIdx.x;
    const int w    = tid >> 6;         // wave 0..7
    const int lane = tid & 63;
    const int quad = lane >> 4;
    const int l    = lane & 15;

    if (tid < PB) {
        int idx = blockIdx.x * PB + tid;
        if (idx > PPP - 1) idx = PPP - 1;
        int pid = order[idx];
        s_pid[tid] = pid;
        s_len[tid] = path_lengths[pid];
    }
    for (int i = tid; i < 64 * 72; i += 512) ((uint*)&hp[0][0][0])[i] = 0;
    __syncthreads();

    for (int i = tid; i < 64 * TT; i += 512) {
        int p = i & 63, t = i >> 6;
        s_tok[t][p] = path_elements[(size_t)s_pid[p] * TT + t];
    }

    short8 bfrag[4][4];
#pragma unroll
    for (int g = 0; g < 4; g++)
#pragma unroll
        for (int kb = 0; kb < 4; kb++)
            bfrag[g][kb] = *(const short8*)(UfD + (size_t)(((w * 4 + g) * 4 + kb) * 64 + lane) * 8);

    __syncthreads();

    const int maxLen = s_len[0];       // descending sort

    int lenp[16];
#pragma unroll
    for (int mt = 0; mt < 4; mt++)
#pragma unroll
        for (int r = 0; r < 4; r++)
            lenp[mt * 4 + r] = s_len[mt * 16 + quad * 4 + r];

    float c_st[16];
#pragma unroll
    for (int i = 0; i < 16; i++) c_st[i] = 0.f;

    for (int step = 0; step < maxLen; step++) {
        const int cur = step & 1, nxt = cur ^ 1;
        const int t = dir ? (maxLen - 1 - step) : step;

        // Zx prefetch: in flight across the MFMA section
        uint2 zv[16];
#pragma unroll
        for (int mt = 0; mt < 4; mt++)
#pragma unroll
            for (int r = 0; r < 4; r++) {
                int tok = s_tok[t][mt * 16 + quad * 4 + r];
                zv[mt * 4 + r] = *(const uint2*)(ZxD + (size_t)tok * 512 + (w * 16 + l) * 4);
            }

        float4v acc[4][4];             // [mt][g]
#pragma unroll
        for (int mt = 0; mt < 4; mt++)
#pragma unroll
            for (int g = 0; g < 4; g++) {
                float4v z4 = {0.f, 0.f, 0.f, 0.f};
                acc[mt][g] = z4;
            }

#pragma unroll
        for (int kb = 0; kb < 4; kb++) {
            short8 af[4];
#pragma unroll
            for (int mt = 0; mt < 4; mt++)
                af[mt] = *(const short8*)&hp[cur][mt * 16 + l][kb * 32 + quad * 8];
#pragma unroll
            for (int g = 0; g < 4; g++)
#pragma unroll
                for (int mt = 0; mt < 4; mt++)
                    acc[mt][g] = __builtin_amdgcn_mfma_f32_16x16x32_bf16(
                        af[mt], bfrag[g][kb], acc[mt][g], 0, 0, 0);
        }

        // gating: writes go to the OTHER plane -> no barrier needed here
#pragma unroll
        for (int mt = 0; mt < 4; mt++)
#pragma unroll
            for (int r = 0; r < 4; r++) {
                const int p = mt * 16 + quad * 4 + r;
                const bool valid = t < lenp[mt * 4 + r];
                const ushort hold = hp[cur][p][w * 16 + l];   // carry value
                const uint2 z2 = zv[mt * 4 + r];
                float zi = acc[mt][0][r] + bf2f((ushort)(z2.x & 0xffff));
                float zf = acc[mt][1][r] + bf2f((ushort)(z2.x >> 16));
                float zg = acc[mt][2][r] + bf2f((ushort)(z2.y & 0xffff));
                float zo = acc[mt][3][r] + bf2f((ushort)(z2.y >> 16));
                float ig = fsigmoid(zi);
                float fg = fsigmoid(zf);
                float gg = ftanh(zg);
                float og = fsigmoid(zo);
                float cn = fg * c_st[mt * 4 + r] + ig * gg;
                float hn = og * ftanh(cn);
                if (valid) c_st[mt * 4 + r] = cn;
                hp[nxt][p][w * 16 + l] = valid ? f2bf(hn) : hold;
            }
        __syncthreads();   // writes to nxt visible; all reads of cur complete
    }

    // epilogue: final plane -> bf16 h_out
    {
        const int fin = maxLen & 1;
        const int pg = tid >> 3;       // 0..63
        const int ch = tid & 7;        // 0..7 -> 16 cols
        ushort* dst = h_out + ((size_t)dir * PPP + s_pid[pg]) * 128 + ch * 16;
        *(int4*)dst       = *(const int4*)&hp[fin][pg][ch * 16];
        *(int4*)(dst + 8) = *(const int4*)&hp[fin][pg][ch * 16 + 8];
    }
}

// ---------------- MFMA projection + fused attention scores -----------------
// 64 paths/block, 512 threads (8 waves). Wave w owns output cols
// [w*16, w*16+16). V = [leaf0|leaf1|h_f|h_b] staged bf16 in LDS.
// full (fp32) stored; scores accumulated via 16-lane shuffle + atomicAdd.

__global__ __launch_bounds__(512) void proj_kernel(
    const float* __restrict__ leaf, const ushort* __restrict__ hbuf,
    const ushort* __restrict__ pfrag, const float* __restrict__ att,
    const int* __restrict__ leaf_idxs,
    float* __restrict__ full, float* __restrict__ scores)
{
    __shared__ ushort Vb[64][400];     // bf16, 16B-aligned rows, ~2-way banks
    __shared__ int s_lidx[64][2];

    const int tid  = threadIdx.x;
    const int w    = tid >> 6;
    const int lane = tid & 63;
    const int quad = lane >> 4;
    const int l    = lane & 15;
    const int p0   = blockIdx.x * 64;

    if (tid < 128) {
        int p = tid >> 1;
        int pg = p0 + p; if (pg > PPP - 1) pg = PPP - 1;
        s_lidx[p][tid & 1] = leaf_idxs[(size_t)pg * 2 + (tid & 1)];
    }
    __syncthreads();

    // stage V rows (64 x 384 bf16) as uint pairs
    for (int s = tid; s < 64 * 192; s += 512) {
        int p = s / 192, cp = s % 192;
        int c = cp * 2;
        int pg = p0 + p; if (pg > PPP - 1) pg = PPP - 1;
        uint val;
        if (c < 128) {
            const float* src = leaf + (size_t)s_lidx[p][c >> 6] * 64 + (c & 63);
            float2 f = *(const float2*)src;
            val = (uint)f2bf(f.x) | ((uint)f2bf(f.y) << 16);
        } else {
            const ushort* src = hbuf + ((size_t)(c < 256 ? 0 : 1) * PPP + pg) * 128 + (c & 127);
            val = *(const uint*)src;
        }
        *(uint*)&Vb[p][c] = val;
    }

    short8 bq[12];
#pragma unroll
    for (int kb = 0; kb < 12; kb++)
        bq[kb] = *(const short8*)(pfrag + ((size_t)w * 768 + kb * 64 + lane) * 8);

    __syncthreads();

    float4v acc[4];
#pragma unroll
    for (int mt = 0; mt < 4; mt++) {
        float4v z4 = {0.f, 0.f, 0.f, 0.f};
        acc[mt] = z4;
    }

#pragma unroll
    for (int kb = 0; kb < 12; kb++) {
#pragma unroll
        for (int mt = 0; mt < 4; mt++) {
            short8 af = *(const short8*)&Vb[mt * 16 + l][kb * 32 + quad * 8];
            acc[mt] = __builtin_amdgcn_mfma_f32_16x16x32_bf16(af, bq[kb], acc[mt], 0, 0, 0);
        }
    }

    const int col = w * 16 + l;
    const float attc = att[col];
#pragma unroll
    for (int mt = 0; mt < 4; mt++)
#pragma unroll
        for (int r = 0; r < 4; r++) {
            int row = mt * 16 + quad * 4 + r;
            int pg = p0 + row;
            float v = acc[mt][r];
            if (pg < PPP) full[(size_t)pg * 128 + col] = v;
            float part = v * attc;
            part += __shfl_xor(part, 1);
            part += __shfl_xor(part, 2);
            part += __shfl_xor(part, 4);
            part += __shfl_xor(part, 8);
            if (l == 0 && pg < PPP) atomicAdd(&scores[pg], part);
        }
}

// ---------------- segment softmax + weighted sum ---------------------------

__global__ __launch_bounds__(128) void seg_kernel(
    const float* __restrict__ scores, const float* __restrict__ full,
    const int* __restrict__ seg, float* __restrict__ out)
{
    const int s = blockIdx.x;
    const int tid = threadIdx.x;

    int lo = 0, hi = PPP;
    while (lo < hi) { int mid = (lo + hi) >> 1; if (seg[mid] < s) lo = mid + 1; else hi = mid; }
    const int start = lo;
    lo = start; hi = PPP;
    while (lo < hi) { int mid = (lo + hi) >> 1; if (seg[mid] < s + 1) lo = mid + 1; else hi = mid; }
    const int end = lo;

    if (start >= end) { out[(size_t)s * 128 + tid] = 0.f; return; }

    __shared__ float red[128];

    float mx = -1e30f;
    for (int i = start + tid; i < end; i += 128) mx = fmaxf(mx, scores[i]);
    red[tid] = mx; __syncthreads();
    for (int off = 64; off > 0; off >>= 1) {
        if (tid < off) red[tid] = fmaxf(red[tid], red[tid + off]);
        __syncthreads();
    }
    mx = red[0]; __syncthreads();

    float den = 0.f;
    for (int i = start + tid; i < end; i += 128) den += __expf(scores[i] - mx);
    red[tid] = den; __syncthreads();
    for (int off = 64; off > 0; off >>= 1) {
        if (tid < off) red[tid] += red[tid + off];
        __syncthreads();
    }
    den = red[0];

    float acc = 0.f;
    for (int i = start; i < end; i++)
        acc = fmaf(__expf(scores[i] - mx), full[(size_t)i * 128 + tid], acc);
    out[(size_t)s * 128 + tid] = acc / den;
}

// ---------------- launch ---------------------------------------------------

extern "C" void kernel_launch(void* const* d_in, const int* in_sizes, int n_in,
                              void* d_out, int out_size, void* d_ws, size_t ws_size,
                              hipStream_t stream) {
    (void)in_sizes; (void)n_in; (void)out_size; (void)ws_size;

    const float* leaf = (const float*)d_in[0];
    const float* emb  = (const float*)d_in[1];
    const float* Wf   = (const float*)d_in[2];
    const float* Uf   = (const float*)d_in[3];
    const float* bf   = (const float*)d_in[4];
    const float* Wb   = (const float*)d_in[5];
    const float* Ub   = (const float*)d_in[6];
    const float* bb   = (const float*)d_in[7];
    const float* proj = (const float*)d_in[8];
    const float* att  = (const float*)d_in[9];
    const int* path_elements = (const int*)d_in[10];
    const int* path_lengths  = (const int*)d_in[11];
    const int* leaf_idxs     = (const int*)d_in[12];
    const int* seg           = (const int*)d_in[13];
    float* out = (float*)d_out;

    char* ws = (char*)d_ws;
    int*    order  = (int*)ws;                         // 80,000 B
    int*    bins   = (int*)(ws + 80128);
    int*    cur    = (int*)(ws + 80384);
    ushort* Zall   = (ushort*)(ws + 81920);            // 20,480,000
    ushort* Ufrag  = (ushort*)(ws + 20561920);         // 262,144
    ushort* pfrag  = (ushort*)(ws + 20824064);         // 98,304
    ushort* hbuf   = (ushort*)(ws + 20922368);         // 10,240,000 (bf16)
    float*  full   = (float*)(ws + 31162368);          // 10,240,000
    float*  scores = (float*)(ws + 41402368);          // 80,000

    k_zero<<<1, 64, 0, stream>>>(bins);
    k_hist<<<(PPP + 255) / 256, 256, 0, stream>>>(path_lengths, bins, scores);
    k_scan<<<1, 64, 0, stream>>>(bins, cur);
    k_scatter<<<(PPP + 255) / 256, 256, 0, stream>>>(path_lengths, cur, order);

    dim3 gu(8, 2);
    ufrag_kernel<<<gu, 256, 0, stream>>>(Uf, Ub, Ufrag);

    projfrag_kernel<<<24, 256, 0, stream>>>(proj, pfrag);

    dim3 gz(VNT / 8, 2);
    zx_kernel<<<gz, 256, 0, stream>>>(emb, Wf, bf, Wb, bb, Zall);

    dim3 g((PPP + PB - 1) / PB, 2);
    lstm_kernel<<<g, 512, 0, stream>>>(Zall, Ufrag, path_elements, path_lengths,
                                       order, hbuf);

    proj_kernel<<<(PPP + 63) / 64, 512, 0, stream>>>(leaf, hbuf, pfrag, att,
                                                     leaf_idxs, full, scores);

    seg_kernel<<<SS, 128, 0, stream>>>(scores, full, seg, out);
}

// Round 7
// 710.984 us; speedup vs baseline: 3.4559x; 1.1640x over previous
//
#include <hip/hip_runtime.h>
#include <math.h>

#define PPP 20000   // paths
#define TT  30      // max timesteps
#define SS  1000    // samples
#define VNT 10000   // non-terminal vocab
#define PB  64      // paths per LSTM block
#define HSTR 152    // hp row stride (ushorts): 304B = 76dw = 12 mod 32 -> 2-way (free), 16B-aligned

typedef __attribute__((ext_vector_type(8))) short short8;
typedef __attribute__((ext_vector_type(4))) float float4v;
typedef unsigned short ushort;
typedef unsigned int uint;

__device__ __forceinline__ ushort f2bf(float x) {
    uint u = __builtin_bit_cast(uint, x);
    uint r = (u + 0x7fffu + ((u >> 16) & 1u)) >> 16;
    return (ushort)r;
}
__device__ __forceinline__ float bf2f(ushort h) {
    uint u = ((uint)h) << 16;
    return __builtin_bit_cast(float, u);
}
// fast activations: v_exp_f32 + v_rcp_f32 (1-ulp; far below bf16 noise floor)
__device__ __forceinline__ float fsigmoid(float x) {
    float e = __builtin_amdgcn_exp2f(x * -1.442695040888963f);
    return __builtin_amdgcn_rcpf(1.f + e);
}
__device__ __forceinline__ float ftanh(float x) {
    float e = __builtin_amdgcn_exp2f(x * -2.885390081777927f);
    return fmaf(2.f, __builtin_amdgcn_rcpf(1.f + e), -1.f);
}

// ---------------- length bucketing (counting sort, DESCENDING) -------------

__global__ void k_zero(int* bins) {
    if (threadIdx.x < 32) bins[threadIdx.x] = 0;
}
__global__ void k_hist(const int* __restrict__ len, int* __restrict__ bins,
                       float* __restrict__ scores) {
    int p = blockIdx.x * 256 + threadIdx.x;
    if (p < PPP) { atomicAdd(&bins[len[p] - 1], 1); scores[p] = 0.f; }
}
__global__ void k_scan(const int* __restrict__ bins, int* __restrict__ cur) {
    if (threadIdx.x == 0 && blockIdx.x == 0) {
        int ofs = 0;
        for (int l = TT - 1; l >= 0; l--) { cur[l] = ofs; ofs += bins[l]; }
    }
}
__global__ void k_scatter(const int* __restrict__ len, int* __restrict__ cur,
                          int* __restrict__ order) {
    int p = blockIdx.x * 256 + threadIdx.x;
    if (p < PPP) {
        int pos = atomicAdd(&cur[len[p] - 1], 1);
        order[pos] = p;
    }
}

// ---------------- U -> bf16 B-fragment precompute ---------------------------
// slot s per dir: lane=s&63, kb=(s>>6)&3, g=(s>>8)&3, w=s>>10
// frag elem j = U[kb*32 + (lane>>4)*8 + j][g*128 + w*16 + (lane&15)]

__global__ __launch_bounds__(256) void ufrag_kernel(
    const float* __restrict__ Uf, const float* __restrict__ Ub,
    ushort* __restrict__ Ufrag)
{
    const int d = blockIdx.y;
    const float* U = d ? Ub : Uf;
#pragma unroll
    for (int i = 0; i < 4; i++) {
        int s = blockIdx.x * 1024 + i * 256 + threadIdx.x;
        int lane = s & 63, kb = (s >> 6) & 3, g = (s >> 8) & 3, w = s >> 10;
        int krow = kb * 32 + (lane >> 4) * 8;
        int col  = g * 128 + w * 16 + (lane & 15);
        ushort* dst = Ufrag + ((size_t)d * 8192 + s) * 8;
#pragma unroll
        for (int j = 0; j < 8; j++)
            dst[j] = f2bf(U[(size_t)(krow + j) * 512 + col]);
    }
}

// ---------------- proj -> bf16 B-fragment precompute ------------------------

__global__ __launch_bounds__(256) void projfrag_kernel(
    const float* __restrict__ proj, ushort* __restrict__ pfrag)
{
    int s = blockIdx.x * 256 + threadIdx.x;    // grid 24 -> 6144
    int lane = s & 63;
    int kb = (s >> 6) % 12;
    int nt = s / 768;
    int krow = kb * 32 + (lane >> 4) * 8;
    int col  = nt * 16 + (lane & 15);
    ushort* dst = pfrag + (size_t)s * 8;
#pragma unroll
    for (int j = 0; j < 8; j++)
        dst[j] = f2bf(proj[(size_t)(krow + j) * 128 + col]);
}

// ---------------- Zx = emb @ W + b  -> bf16, gather layout ------------------
// col c (0..511): g=c>>7, u=c&127 -> stored at Zx[d][tok][u*4 + g]

__global__ __launch_bounds__(256) void zx_kernel(
    const float* __restrict__ emb,
    const float* __restrict__ Wf, const float* __restrict__ bf,
    const float* __restrict__ Wb, const float* __restrict__ bb,
    ushort* __restrict__ Zall)
{
    const int dir = blockIdx.y;
    const float* W = dir ? Wb : Wf;
    const float* b = dir ? bb : bf;
    ushort* Z = Zall + (size_t)dir * VNT * 512;

    __shared__ float X[8][128];
    __shared__ float Zb[8][516];
    const int tid = threadIdx.x;
    const int tok0 = blockIdx.x * 8;

    {
        int tr = tid >> 5;
        int c4 = (tid & 31) * 4;
        *(float4*)&X[tr][c4] = *(const float4*)(emb + (size_t)(tok0 + tr) * 128 + c4);
    }
    __syncthreads();

    const int pp = tid >> 5;
    const int cg = tid & 31;
    const int c0 = cg * 16;

    float acc[16];
#pragma unroll
    for (int j = 0; j < 16; j++) acc[j] = 0.f;

#pragma unroll 2
    for (int k = 0; k < 128; k++) {
        float a = X[pp][k];
        const float* wr = W + (size_t)k * 512 + c0;
#pragma unroll
        for (int q = 0; q < 4; q++) {
            float4 w = *(const float4*)(wr + q * 4);
            acc[q * 4 + 0] = fmaf(a, w.x, acc[q * 4 + 0]);
            acc[q * 4 + 1] = fmaf(a, w.y, acc[q * 4 + 1]);
            acc[q * 4 + 2] = fmaf(a, w.z, acc[q * 4 + 2]);
            acc[q * 4 + 3] = fmaf(a, w.w, acc[q * 4 + 3]);
        }
    }

    // rotated write into LDS bounce buffer (avoids bank conflicts)
#pragma unroll
    for (int j = 0; j < 16; j++) {
        int jj = (j + cg) & 15;
        Zb[pp][c0 + jj] = acc[jj] + b[c0 + jj];
    }
    __syncthreads();

#pragma unroll
    for (int i = 0; i < 4; i++) {
        int s = i * 256 + tid;          // 0..1023
        int pt = s >> 7;                // token 0..7
        int pair = s & 127;             // col u
        ushort v[4];
#pragma unroll
        for (int g = 0; g < 4; g++)
            v[g] = f2bf(Zb[pt][g * 128 + pair]);
        *(uint2*)(Z + (size_t)(tok0 + pt) * 512 + pair * 4) = *(const uint2*)v;
    }
}

// ---------------- MFMA LSTM -------------------------------------------------
// 64 paths, 512 threads (8 waves). Wave w owns hidden cols [w*16,w*16+16) of
// each gate; U B-frags in registers. h: double-buffered bf16 planes
// hp[2][64][HSTR] -> ONE barrier per step. Masked paths carry h via read-old.

__global__ __launch_bounds__(512, 2) void lstm_kernel(
    const ushort* __restrict__ Zall,
    const ushort* __restrict__ Ufrag,
    const int* __restrict__ path_elements, const int* __restrict__ path_lengths,
    const int* __restrict__ order,
    ushort* __restrict__ h_out)   // bf16 [2][P][128]
{
    const int dir = blockIdx.y;
    const ushort* ZxD = Zall + (size_t)dir * VNT * 512;
    const ushort* UfD = Ufrag + (size_t)dir * 65536;

    __shared__ ushort hp[2][64][HSTR]; // bf16 h planes (A-layout)
    __shared__ int s_tok[TT][64];
    __shared__ int s_pid[PB];
    __shared__ int s_len[PB];

    const int tid  = threadIdx.x;
    const int w    = tid >> 6;         // wave 0..7
    const int lane = tid & 63;
    const int quad = lane >> 4;
    const int l    = lane & 15;

    if (tid < PB) {
        int idx = blockIdx.x * PB + tid;
        if (idx > PPP - 1) idx = PPP - 1;
        int pid = order[idx];
        s_pid[tid] = pid;
        s_len[tid] = path_lengths[pid];
    }
    for (int i = tid; i < 2 * 64 * (HSTR / 2); i += 512) ((uint*)&hp[0][0][0])[i] = 0;
    __syncthreads();

    for (int i = tid; i < 64 * TT; i += 512) {
        int p = i & 63, t = i >> 6;
        s_tok[t][p] = path_elements[(size_t)s_pid[p] * TT + t];
    }

    short8 bfrag[4][4];
#pragma unroll
    for (int g = 0; g < 4; g++)
#pragma unroll
        for (int kb = 0; kb < 4; kb++)
            bfrag[g][kb] = *(const short8*)(UfD + (size_t)(((w * 4 + g) * 4 + kb) * 64 + lane) * 8);

    __syncthreads();

    const int maxLen = s_len[0];       // descending sort

    int lenp[16];
#pragma unroll
    for (int mt = 0; mt < 4; mt++)
#pragma unroll
        for (int r = 0; r < 4; r++)
            lenp[mt * 4 + r] = s_len[mt * 16 + quad * 4 + r];

    float c_st[16];
#pragma unroll
    for (int i = 0; i < 16; i++) c_st[i] = 0.f;

    for (int step = 0; step < maxLen; step++) {
        const int cur = step & 1, nxt = cur ^ 1;
        const int t = dir ? (maxLen - 1 - step) : step;

        // Zx prefetch: in flight across the MFMA section
        uint2 zv[16];
#pragma unroll
        for (int mt = 0; mt < 4; mt++)
#pragma unroll
            for (int r = 0; r < 4; r++) {
                int tok = s_tok[t][mt * 16 + quad * 4 + r];
                zv[mt * 4 + r] = *(const uint2*)(ZxD + (size_t)tok * 512 + (w * 16 + l) * 4);
            }

        float4v acc[4][4];             // [mt][g]
#pragma unroll
        for (int mt = 0; mt < 4; mt++)
#pragma unroll
            for (int g = 0; g < 4; g++) {
                float4v z4 = {0.f, 0.f, 0.f, 0.f};
                acc[mt][g] = z4;
            }

#pragma unroll
        for (int kb = 0; kb < 4; kb++) {
            short8 af[4];
#pragma unroll
            for (int mt = 0; mt < 4; mt++)
                af[mt] = *(const short8*)&hp[cur][mt * 16 + l][kb * 32 + quad * 8];
#pragma unroll
            for (int g = 0; g < 4; g++)
#pragma unroll
                for (int mt = 0; mt < 4; mt++)
                    acc[mt][g] = __builtin_amdgcn_mfma_f32_16x16x32_bf16(
                        af[mt], bfrag[g][kb], acc[mt][g], 0, 0, 0);
        }

        // gating: writes go to the OTHER plane -> no barrier needed here
#pragma unroll
        for (int mt = 0; mt < 4; mt++)
#pragma unroll
            for (int r = 0; r < 4; r++) {
                const int p = mt * 16 + quad * 4 + r;
                const bool valid = t < lenp[mt * 4 + r];
                const ushort hold = hp[cur][p][w * 16 + l];   // carry value
                const uint2 z2 = zv[mt * 4 + r];
                float zi = acc[mt][0][r] + bf2f((ushort)(z2.x & 0xffff));
                float zf = acc[mt][1][r] + bf2f((ushort)(z2.x >> 16));
                float zg = acc[mt][2][r] + bf2f((ushort)(z2.y & 0xffff));
                float zo = acc[mt][3][r] + bf2f((ushort)(z2.y >> 16));
                float ig = fsigmoid(zi);
                float fg = fsigmoid(zf);
                float gg = ftanh(zg);
                float og = fsigmoid(zo);
                float cn = fg * c_st[mt * 4 + r] + ig * gg;
                float hn = og * ftanh(cn);
                if (valid) c_st[mt * 4 + r] = cn;
                hp[nxt][p][w * 16 + l] = valid ? f2bf(hn) : hold;
            }
        __syncthreads();   // writes to nxt visible; all reads of cur complete
    }

    // epilogue: final plane -> bf16 h_out
    {
        const int fin = maxLen & 1;
        const int pg = tid >> 3;       // 0..63
        const int ch = tid & 7;        // 0..7 -> 16 cols
        ushort* dst = h_out + ((size_t)dir * PPP + s_pid[pg]) * 128 + ch * 16;
        *(int4*)dst       = *(const int4*)&hp[fin][pg][ch * 16];
        *(int4*)(dst + 8) = *(const int4*)&hp[fin][pg][ch * 16 + 8];
    }
}

// ---------------- MFMA projection + fused attention scores -----------------

__global__ __launch_bounds__(512) void proj_kernel(
    const float* __restrict__ leaf, const ushort* __restrict__ hbuf,
    const ushort* __restrict__ pfrag, const float* __restrict__ att,
    const int* __restrict__ leaf_idxs,
    float* __restrict__ full, float* __restrict__ scores)
{
    __shared__ ushort Vb[64][400];     // bf16, 16B-aligned rows
    __shared__ int s_lidx[64][2];

    const int tid  = threadIdx.x;
    const int w    = tid >> 6;
    const int lane = tid & 63;
    const int quad = lane >> 4;
    const int l    = lane & 15;
    const int p0   = blockIdx.x * 64;

    if (tid < 128) {
        int p = tid >> 1;
        int pg = p0 + p; if (pg > PPP - 1) pg = PPP - 1;
        s_lidx[p][tid & 1] = leaf_idxs[(size_t)pg * 2 + (tid & 1)];
    }
    __syncthreads();

    for (int s = tid; s < 64 * 192; s += 512) {
        int p = s / 192, cp = s % 192;
        int c = cp * 2;
        int pg = p0 + p; if (pg > PPP - 1) pg = PPP - 1;
        uint val;
        if (c < 128) {
            const float* src = leaf + (size_t)s_lidx[p][c >> 6] * 64 + (c & 63);
            float2 f = *(const float2*)src;
            val = (uint)f2bf(f.x) | ((uint)f2bf(f.y) << 16);
        } else {
            const ushort* src = hbuf + ((size_t)(c < 256 ? 0 : 1) * PPP + pg) * 128 + (c & 127);
            val = *(const uint*)src;
        }
        *(uint*)&Vb[p][c] = val;
    }

    short8 bq[12];
#pragma unroll
    for (int kb = 0; kb < 12; kb++)
        bq[kb] = *(const short8*)(pfrag + ((size_t)w * 768 + kb * 64 + lane) * 8);

    __syncthreads();

    float4v acc[4];
#pragma unroll
    for (int mt = 0; mt < 4; mt++) {
        float4v z4 = {0.f, 0.f, 0.f, 0.f};
        acc[mt] = z4;
    }

#pragma unroll
    for (int kb = 0; kb < 12; kb++) {
#pragma unroll
        for (int mt = 0; mt < 4; mt++) {
            short8 af = *(const short8*)&Vb[mt * 16 + l][kb * 32 + quad * 8];
            acc[mt] = __builtin_amdgcn_mfma_f32_16x16x32_bf16(af, bq[kb], acc[mt], 0, 0, 0);
        }
    }

    const int col = w * 16 + l;
    const float attc = att[col];
#pragma unroll
    for (int mt = 0; mt < 4; mt++)
#pragma unroll
        for (int r = 0; r < 4; r++) {
            int row = mt * 16 + quad * 4 + r;
            int pg = p0 + row;
            float v = acc[mt][r];
            if (pg < PPP) full[(size_t)pg * 128 + col] = v;
            float part = v * attc;
            part += __shfl_xor(part, 1);
            part += __shfl_xor(part, 2);
            part += __shfl_xor(part, 4);
            part += __shfl_xor(part, 8);
            if (l == 0 && pg < PPP) atomicAdd(&scores[pg], part);
        }
}

// ---------------- segment softmax + weighted sum ---------------------------

__global__ __launch_bounds__(128) void seg_kernel(
    const float* __restrict__ scores, const float* __restrict__ full,
    const int* __restrict__ seg, float* __restrict__ out)
{
    const int s = blockIdx.x;
    const int tid = threadIdx.x;

    int lo = 0, hi = PPP;
    while (lo < hi) { int mid = (lo + hi) >> 1; if (seg[mid] < s) lo = mid + 1; else hi = mid; }
    const int start = lo;
    lo = start; hi = PPP;
    while (lo < hi) { int mid = (lo + hi) >> 1; if (seg[mid] < s + 1) lo = mid + 1; else hi = mid; }
    const int end = lo;

    if (start >= end) { out[(size_t)s * 128 + tid] = 0.f; return; }

    __shared__ float red[128];

    float mx = -1e30f;
    for (int i = start + tid; i < end; i += 128) mx = fmaxf(mx, scores[i]);
    red[tid] = mx; __syncthreads();
    for (int off = 64; off > 0; off >>= 1) {
        if (tid < off) red[tid] = fmaxf(red[tid], red[tid + off]);
        __syncthreads();
    }
    mx = red[0]; __syncthreads();

    float den = 0.f;
    for (int i = start + tid; i < end; i += 128) den += __expf(scores[i] - mx);
    red[tid] = den; __syncthreads();
    for (int off = 64; off > 0; off >>= 1) {
        if (tid < off) red[tid] += red[tid + off];
        __syncthreads();
    }
    den = red[0];

    float acc = 0.f;
    for (int i = start; i < end; i++)
        acc = fmaf(__expf(scores[i] - mx), full[(size_t)i * 128 + tid], acc);
    out[(size_t)s * 128 + tid] = acc / den;
}

// ---------------- launch ---------------------------------------------------

extern "C" void kernel_launch(void* const* d_in, const int* in_sizes, int n_in,
                              void* d_out, int out_size, void* d_ws, size_t ws_size,
                              hipStream_t stream) {
    (void)in_sizes; (void)n_in; (void)out_size; (void)ws_size;

    const float* leaf = (const float*)d_in[0];
    const float* emb  = (const float*)d_in[1];
    const float* Wf   = (const float*)d_in[2];
    const float* Uf   = (const float*)d_in[3];
    const float* bf   = (const float*)d_in[4];
    const float* Wb   = (const float*)d_in[5];
    const float* Ub   = (const float*)d_in[6];
    const float* bb   = (const float*)d_in[7];
    const float* proj = (const float*)d_in[8];
    const float* att  = (const float*)d_in[9];
    const int* path_elements = (const int*)d_in[10];
    const int* path_lengths  = (const int*)d_in[11];
    const int* leaf_idxs     = (const int*)d_in[12];
    const int* seg           = (const int*)d_in[13];
    float* out = (float*)d_out;

    char* ws = (char*)d_ws;
    int*    order  = (int*)ws;                         // 80,000 B
    int*    bins   = (int*)(ws + 80128);
    int*    cur    = (int*)(ws + 80384);
    ushort* Zall   = (ushort*)(ws + 81920);            // 20,480,000
    ushort* Ufrag  = (ushort*)(ws + 20561920);         // 262,144
    ushort* pfrag  = (ushort*)(ws + 20824064);         // 98,304
    ushort* hbuf   = (ushort*)(ws + 20922368);         // 10,240,000 (bf16)
    float*  full   = (float*)(ws + 31162368);          // 10,240,000
    float*  scores = (float*)(ws + 41402368);          // 80,000

    k_zero<<<1, 64, 0, stream>>>(bins);
    k_hist<<<(PPP + 255) / 256, 256, 0, stream>>>(path_lengths, bins, scores);
    k_scan<<<1, 64, 0, stream>>>(bins, cur);
    k_scatter<<<(PPP + 255) / 256, 256, 0, stream>>>(path_lengths, cur, order);

    dim3 gu(8, 2);
    ufrag_kernel<<<gu, 256, 0, stream>>>(Uf, Ub, Ufrag);

    projfrag_kernel<<<24, 256, 0, stream>>>(proj, pfrag);

    dim3 gz(VNT / 8, 2);
    zx_kernel<<<gz, 256, 0, stream>>>(emb, Wf, bf, Wb, bb, Zall);

    dim3 g((PPP + PB - 1) / PB, 2);
    lstm_kernel<<<g, 512, 0, stream>>>(Zall, Ufrag, path_elements, path_lengths,
                                       order, hbuf);

    proj_kernel<<<(PPP + 63) / 64, 512, 0, stream>>>(leaf, hbuf, pfrag, att,
                                                     leaf_idxs, full, scores);

    seg_kernel<<<SS, 128, 0, stream>>>(scores, full, seg, out);
}

// Round 8
// 442.021 us; speedup vs baseline: 5.5587x; 1.6085x over previous
//
#include <hip/hip_runtime.h>
#include <math.h>

#define PPP 20000   // paths
#define TT  30      // max timesteps
#define SS  1000    // samples
#define VNT 10000   // non-terminal vocab
#define PB  64      // paths per LSTM block
#define HSTR 152    // LDS row stride (ushorts): 304B = 76dw = 12 mod 32 -> ~2-way (free), 16B-aligned

typedef __attribute__((ext_vector_type(8))) short short8;
typedef __attribute__((ext_vector_type(4))) float float4v;
typedef unsigned short ushort;
typedef unsigned int uint;

__device__ __forceinline__ ushort f2bf(float x) {
    uint u = __builtin_bit_cast(uint, x);
    uint r = (u + 0x7fffu + ((u >> 16) & 1u)) >> 16;
    return (ushort)r;
}
__device__ __forceinline__ float bf2f(ushort h) {
    uint u = ((uint)h) << 16;
    return __builtin_bit_cast(float, u);
}
// fast activations: v_exp_f32 + v_rcp_f32 (1-ulp; far below bf16 noise floor)
__device__ __forceinline__ float fsigmoid(float x) {
    float e = __builtin_amdgcn_exp2f(x * -1.442695040888963f);
    return __builtin_amdgcn_rcpf(1.f + e);
}
__device__ __forceinline__ float ftanh(float x) {
    float e = __builtin_amdgcn_exp2f(x * -2.885390081777927f);
    return fmaf(2.f, __builtin_amdgcn_rcpf(1.f + e), -1.f);
}

// ---------------- length bucketing (counting sort, DESCENDING) -------------

__global__ void k_zero(int* bins) {
    if (threadIdx.x < 32) bins[threadIdx.x] = 0;
}
__global__ void k_hist(const int* __restrict__ len, int* __restrict__ bins,
                       float* __restrict__ scores) {
    int p = blockIdx.x * 256 + threadIdx.x;
    if (p < PPP) { atomicAdd(&bins[len[p] - 1], 1); scores[p] = 0.f; }
}
__global__ void k_scan(const int* __restrict__ bins, int* __restrict__ cur) {
    if (threadIdx.x == 0 && blockIdx.x == 0) {
        int ofs = 0;
        for (int l = TT - 1; l >= 0; l--) { cur[l] = ofs; ofs += bins[l]; }
    }
}
__global__ void k_scatter(const int* __restrict__ len, int* __restrict__ cur,
                          int* __restrict__ order) {
    int p = blockIdx.x * 256 + threadIdx.x;
    if (p < PPP) {
        int pos = atomicAdd(&cur[len[p] - 1], 1);
        order[pos] = p;
    }
}

// ---------------- U -> bf16 B-fragment precompute ---------------------------
// slot s per dir: lane=s&63, kb=(s>>6)&3, g=(s>>8)&3, w=s>>10
// frag elem j = U[kb*32 + (lane>>4)*8 + j][g*128 + w*16 + (lane&15)]

__global__ __launch_bounds__(256) void ufrag_kernel(
    const float* __restrict__ Uf, const float* __restrict__ Ub,
    ushort* __restrict__ Ufrag)
{
    const int d = blockIdx.y;
    const float* U = d ? Ub : Uf;
#pragma unroll
    for (int i = 0; i < 4; i++) {
        int s = blockIdx.x * 1024 + i * 256 + threadIdx.x;
        int lane = s & 63, kb = (s >> 6) & 3, g = (s >> 8) & 3, w = s >> 10;
        int krow = kb * 32 + (lane >> 4) * 8;
        int col  = g * 128 + w * 16 + (lane & 15);
        ushort* dst = Ufrag + ((size_t)d * 8192 + s) * 8;
#pragma unroll
        for (int j = 0; j < 8; j++)
            dst[j] = f2bf(U[(size_t)(krow + j) * 512 + col]);
    }
}

// ---------------- W -> bf16 B-fragment precompute ---------------------------
// slot s per dir (0..8191): lane=s&63, kb=(s>>6)&3, nt=s>>8 (0..31)
// frag elem j = W[kb*32 + (lane>>4)*8 + j][nt*16 + (lane&15)]

__global__ __launch_bounds__(256) void wfrag_kernel(
    const float* __restrict__ Wf, const float* __restrict__ Wb,
    ushort* __restrict__ Wfrag)
{
    const int d = blockIdx.y;
    const float* W = d ? Wb : Wf;
    int s = blockIdx.x * 256 + threadIdx.x;   // grid.x = 32 -> 8192
    int lane = s & 63, kb = (s >> 6) & 3, nt = s >> 8;
    int krow = kb * 32 + (lane >> 4) * 8;
    int col  = nt * 16 + (lane & 15);
    ushort* dst = Wfrag + ((size_t)d * 8192 + s) * 8;
#pragma unroll
    for (int j = 0; j < 8; j++)
        dst[j] = f2bf(W[(size_t)(krow + j) * 512 + col]);
}

// ---------------- proj -> bf16 B-fragment precompute ------------------------

__global__ __launch_bounds__(256) void projfrag_kernel(
    const float* __restrict__ proj, ushort* __restrict__ pfrag)
{
    int s = blockIdx.x * 256 + threadIdx.x;    // grid 24 -> 6144
    int lane = s & 63;
    int kb = (s >> 6) % 12;
    int nt = s / 768;
    int krow = kb * 32 + (lane >> 4) * 8;
    int col  = nt * 16 + (lane & 15);
    ushort* dst = pfrag + (size_t)s * 8;
#pragma unroll
    for (int j = 0; j < 8; j++)
        dst[j] = f2bf(proj[(size_t)(krow + j) * 128 + col]);
}

// ---------------- Zx = emb @ W + b via MFMA -> bf16 gather layout -----------
// Block: 64 tokens x 512 cols, 512 threads (8 waves). Wave w owns N-tiles
// w*4..w*4+3 (cols w*64..w*64+63). A (emb) staged bf16 in LDS; B (W) frags
// from wfrag in registers. Epilogue bounces C through an LDS plane (union'd
// with the A tile) then packs Zx[tok][u*4+g] with coalesced 8B stores.

__global__ __launch_bounds__(512) void zx_kernel(
    const float* __restrict__ emb,
    const ushort* __restrict__ Wfrag,
    const float* __restrict__ bf, const float* __restrict__ bb,
    ushort* __restrict__ Zall)
{
    const int dir = blockIdx.y;
    const ushort* WfD = Wfrag + (size_t)dir * 65536;
    const float* bias = dir ? bb : bf;
    ushort* Z = Zall + (size_t)dir * VNT * 512;

    __shared__ union {
        ushort At[64][HSTR];   // A tile: 64 tokens x 128 k (bf16)
        ushort Zt[64][520];    // C bounce: 64 tokens x 512 cols (bf16)
    } sm;

    const int tid  = threadIdx.x;
    const int w    = tid >> 6;
    const int lane = tid & 63;
    const int quad = lane >> 4;
    const int l    = lane & 15;
    const int tok0 = blockIdx.x * 64;

    // stage A: thread -> token p=tid>>3, cols (tid&7)*16..+15
    {
        const int p = tid >> 3, ch = tid & 7;
        int tok = tok0 + p; if (tok > VNT - 1) tok = VNT - 1;
        const float4* src = (const float4*)(emb + (size_t)tok * 128 + ch * 16);
        ushort v[16];
#pragma unroll
        for (int q = 0; q < 4; q++) {
            float4 f = src[q];
            v[q * 4 + 0] = f2bf(f.x); v[q * 4 + 1] = f2bf(f.y);
            v[q * 4 + 2] = f2bf(f.z); v[q * 4 + 3] = f2bf(f.w);
        }
        *(int4*)&sm.At[p][ch * 16]     = *(const int4*)&v[0];
        *(int4*)&sm.At[p][ch * 16 + 8] = *(const int4*)&v[8];
    }

    // B fragments in registers
    short8 bq[4][4];   // [nt4][kb]
#pragma unroll
    for (int nt4 = 0; nt4 < 4; nt4++)
#pragma unroll
        for (int kb = 0; kb < 4; kb++)
            bq[nt4][kb] = *(const short8*)(WfD + (size_t)(((w * 4 + nt4) * 4 + kb) * 64 + lane) * 8);

    __syncthreads();

    float4v acc[4][4];     // [mt][nt4]
#pragma unroll
    for (int mt = 0; mt < 4; mt++)
#pragma unroll
        for (int nt4 = 0; nt4 < 4; nt4++) {
            float4v z4 = {0.f, 0.f, 0.f, 0.f};
            acc[mt][nt4] = z4;
        }

#pragma unroll
    for (int kb = 0; kb < 4; kb++) {
        short8 af[4];
#pragma unroll
        for (int mt = 0; mt < 4; mt++)
            af[mt] = *(const short8*)&sm.At[mt * 16 + l][kb * 32 + quad * 8];
#pragma unroll
        for (int nt4 = 0; nt4 < 4; nt4++)
#pragma unroll
            for (int mt = 0; mt < 4; mt++)
                acc[mt][nt4] = __builtin_amdgcn_mfma_f32_16x16x32_bf16(
                    af[mt], bq[nt4][kb], acc[mt][nt4], 0, 0, 0);
    }

    float bv[4];
#pragma unroll
    for (int nt4 = 0; nt4 < 4; nt4++)
        bv[nt4] = bias[(w * 4 + nt4) * 16 + l];

    __syncthreads();   // all At reads done; union switches to Zt

    // C -> Zt (bf16, bias added)
#pragma unroll
    for (int mt = 0; mt < 4; mt++)
#pragma unroll
        for (int r = 0; r < 4; r++) {
            const int p = mt * 16 + quad * 4 + r;
#pragma unroll
            for (int nt4 = 0; nt4 < 4; nt4++)
                sm.Zt[p][(w * 4 + nt4) * 16 + l] = f2bf(acc[mt][nt4][r] + bv[nt4]);
        }
    __syncthreads();

    // pack & store: col c = g*128+u -> Zx[tok][u*4+g]; 8B per (tok,u)
#pragma unroll
    for (int i = 0; i < 16; i++) {
        int s = i * 512 + tid;          // 0..8191
        int pt = s >> 7;                // token row 0..63
        int u  = s & 127;
        int tok = tok0 + pt;
        if (tok < VNT) {
            ushort v[4];
#pragma unroll
            for (int g = 0; g < 4; g++)
                v[g] = sm.Zt[pt][g * 128 + u];
            *(uint2*)(Z + (size_t)tok * 512 + u * 4) = *(const uint2*)v;
        }
    }
}

// ---------------- MFMA LSTM -------------------------------------------------
// 64 paths, 512 threads (8 waves). Wave w owns hidden cols [w*16,w*16+16) of
// each gate; U B-frags in registers. h: double-buffered bf16 planes
// hp[2][64][HSTR] -> ONE barrier per step. Masked paths carry h via read-old.

__global__ __launch_bounds__(512, 2) void lstm_kernel(
    const ushort* __restrict__ Zall,
    const ushort* __restrict__ Ufrag,
    const int* __restrict__ path_elements, const int* __restrict__ path_lengths,
    const int* __restrict__ order,
    ushort* __restrict__ h_out)   // bf16 [2][P][128]
{
    const int dir = blockIdx.y;
    const ushort* ZxD = Zall + (size_t)dir * VNT * 512;
    const ushort* UfD = Ufrag + (size_t)dir * 65536;

    __shared__ ushort hp[2][64][HSTR]; // bf16 h planes (A-layout)
    __shared__ int s_tok[TT][64];
    __shared__ int s_pid[PB];
    __shared__ int s_len[PB];

    const int tid  = threadIdx.x;
    const int w    = tid >> 6;         // wave 0..7
    const int lane = tid & 63;
    const int quad = lane >> 4;
    const int l    = lane & 15;

    if (tid < PB) {
        int idx = blockIdx.x * PB + tid;
        if (idx > PPP - 1) idx = PPP - 1;
        int pid = order[idx];
        s_pid[tid] = pid;
        s_len[tid] = path_lengths[pid];
    }
    for (int i = tid; i < 2 * 64 * (HSTR / 2); i += 512) ((uint*)&hp[0][0][0])[i] = 0;
    __syncthreads();

    for (int i = tid; i < 64 * TT; i += 512) {
        int p = i & 63, t = i >> 6;
        s_tok[t][p] = path_elements[(size_t)s_pid[p] * TT + t];
    }

    short8 bfrag[4][4];
#pragma unroll
    for (int g = 0; g < 4; g++)
#pragma unroll
        for (int kb = 0; kb < 4; kb++)
            bfrag[g][kb] = *(const short8*)(UfD + (size_t)(((w * 4 + g) * 4 + kb) * 64 + lane) * 8);

    __syncthreads();

    const int maxLen = s_len[0];       // descending sort

    int lenp[16];
#pragma unroll
    for (int mt = 0; mt < 4; mt++)
#pragma unroll
        for (int r = 0; r < 4; r++)
            lenp[mt * 4 + r] = s_len[mt * 16 + quad * 4 + r];

    float c_st[16];
#pragma unroll
    for (int i = 0; i < 16; i++) c_st[i] = 0.f;

    for (int step = 0; step < maxLen; step++) {
        const int cur = step & 1, nxt = cur ^ 1;
        const int t = dir ? (maxLen - 1 - step) : step;

        // Zx prefetch: in flight across the MFMA section
        uint2 zv[16];
#pragma unroll
        for (int mt = 0; mt < 4; mt++)
#pragma unroll
            for (int r = 0; r < 4; r++) {
                int tok = s_tok[t][mt * 16 + quad * 4 + r];
                zv[mt * 4 + r] = *(const uint2*)(ZxD + (size_t)tok * 512 + (w * 16 + l) * 4);
            }

        float4v acc[4][4];             // [mt][g]
#pragma unroll
        for (int mt = 0; mt < 4; mt++)
#pragma unroll
            for (int g = 0; g < 4; g++) {
                float4v z4 = {0.f, 0.f, 0.f, 0.f};
                acc[mt][g] = z4;
            }

#pragma unroll
        for (int kb = 0; kb < 4; kb++) {
            short8 af[4];
#pragma unroll
            for (int mt = 0; mt < 4; mt++)
                af[mt] = *(const short8*)&hp[cur][mt * 16 + l][kb * 32 + quad * 8];
#pragma unroll
            for (int g = 0; g < 4; g++)
#pragma unroll
                for (int mt = 0; mt < 4; mt++)
                    acc[mt][g] = __builtin_amdgcn_mfma_f32_16x16x32_bf16(
                        af[mt], bfrag[g][kb], acc[mt][g], 0, 0, 0);
        }

        // gating: writes go to the OTHER plane -> no barrier needed here
#pragma unroll
        for (int mt = 0; mt < 4; mt++)
#pragma unroll
            for (int r = 0; r < 4; r++) {
                const int p = mt * 16 + quad * 4 + r;
                const bool valid = t < lenp[mt * 4 + r];
                const ushort hold = hp[cur][p][w * 16 + l];   // carry value
                const uint2 z2 = zv[mt * 4 + r];
                float zi = acc[mt][0][r] + bf2f((ushort)(z2.x & 0xffff));
                float zf = acc[mt][1][r] + bf2f((ushort)(z2.x >> 16));
                float zg = acc[mt][2][r] + bf2f((ushort)(z2.y & 0xffff));
                float zo = acc[mt][3][r] + bf2f((ushort)(z2.y >> 16));
                float ig = fsigmoid(zi);
                float fg = fsigmoid(zf);
                float gg = ftanh(zg);
                float og = fsigmoid(zo);
                float cn = fg * c_st[mt * 4 + r] + ig * gg;
                float hn = og * ftanh(cn);
                if (valid) c_st[mt * 4 + r] = cn;
                hp[nxt][p][w * 16 + l] = valid ? f2bf(hn) : hold;
            }
        __syncthreads();   // writes to nxt visible; all reads of cur complete
    }

    // epilogue: final plane -> bf16 h_out
    {
        const int fin = maxLen & 1;
        const int pg = tid >> 3;       // 0..63
        const int ch = tid & 7;        // 0..7 -> 16 cols
        ushort* dst = h_out + ((size_t)dir * PPP + s_pid[pg]) * 128 + ch * 16;
        *(int4*)dst       = *(const int4*)&hp[fin][pg][ch * 16];
        *(int4*)(dst + 8) = *(const int4*)&hp[fin][pg][ch * 16 + 8];
    }
}

// ---------------- MFMA projection + fused attention scores -----------------

__global__ __launch_bounds__(512) void proj_kernel(
    const float* __restrict__ leaf, const ushort* __restrict__ hbuf,
    const ushort* __restrict__ pfrag, const float* __restrict__ att,
    const int* __restrict__ leaf_idxs,
    float* __restrict__ full, float* __restrict__ scores)
{
    __shared__ ushort Vb[64][400];     // bf16, 16B-aligned rows
    __shared__ int s_lidx[64][2];

    const int tid  = threadIdx.x;
    const int w    = tid >> 6;
    const int lane = tid & 63;
    const int quad = lane >> 4;
    const int l    = lane & 15;
    const int p0   = blockIdx.x * 64;

    if (tid < 128) {
        int p = tid >> 1;
        int pg = p0 + p; if (pg > PPP - 1) pg = PPP - 1;
        s_lidx[p][tid & 1] = leaf_idxs[(size_t)pg * 2 + (tid & 1)];
    }
    __syncthreads();

    for (int s = tid; s < 64 * 192; s += 512) {
        int p = s / 192, cp = s % 192;
        int c = cp * 2;
        int pg = p0 + p; if (pg > PPP - 1) pg = PPP - 1;
        uint val;
        if (c < 128) {
            const float* src = leaf + (size_t)s_lidx[p][c >> 6] * 64 + (c & 63);
            float2 f = *(const float2*)src;
            val = (uint)f2bf(f.x) | ((uint)f2bf(f.y) << 16);
        } else {
            const ushort* src = hbuf + ((size_t)(c < 256 ? 0 : 1) * PPP + pg) * 128 + (c & 127);
            val = *(const uint*)src;
        }
        *(uint*)&Vb[p][c] = val;
    }

    short8 bq[12];
#pragma unroll
    for (int kb = 0; kb < 12; kb++)
        bq[kb] = *(const short8*)(pfrag + ((size_t)w * 768 + kb * 64 + lane) * 8);

    __syncthreads();

    float4v acc[4];
#pragma unroll
    for (int mt = 0; mt < 4; mt++) {
        float4v z4 = {0.f, 0.f, 0.f, 0.f};
        acc[mt] = z4;
    }

#pragma unroll
    for (int kb = 0; kb < 12; kb++) {
#pragma unroll
        for (int mt = 0; mt < 4; mt++) {
            short8 af = *(const short8*)&Vb[mt * 16 + l][kb * 32 + quad * 8];
            acc[mt] = __builtin_amdgcn_mfma_f32_16x16x32_bf16(af, bq[kb], acc[mt], 0, 0, 0);
        }
    }

    const int col = w * 16 + l;
    const float attc = att[col];
#pragma unroll
    for (int mt = 0; mt < 4; mt++)
#pragma unroll
        for (int r = 0; r < 4; r++) {
            int row = mt * 16 + quad * 4 + r;
            int pg = p0 + row;
            float v = acc[mt][r];
            if (pg < PPP) full[(size_t)pg * 128 + col] = v;
            float part = v * attc;
            part += __shfl_xor(part, 1);
            part += __shfl_xor(part, 2);
            part += __shfl_xor(part, 4);
            part += __shfl_xor(part, 8);
            if (l == 0 && pg < PPP) atomicAdd(&scores[pg], part);
        }
}

// ---------------- segment softmax + weighted sum ---------------------------

__global__ __launch_bounds__(128) void seg_kernel(
    const float* __restrict__ scores, const float* __restrict__ full,
    const int* __restrict__ seg, float* __restrict__ out)
{
    const int s = blockIdx.x;
    const int tid = threadIdx.x;

    int lo = 0, hi = PPP;
    while (lo < hi) { int mid = (lo + hi) >> 1; if (seg[mid] < s) lo = mid + 1; else hi = mid; }
    const int start = lo;
    lo = start; hi = PPP;
    while (lo < hi) { int mid = (lo + hi) >> 1; if (seg[mid] < s + 1) lo = mid + 1; else hi = mid; }
    const int end = lo;

    if (start >= end) { out[(size_t)s * 128 + tid] = 0.f; return; }

    __shared__ float red[128];

    float mx = -1e30f;
    for (int i = start + tid; i < end; i += 128) mx = fmaxf(mx, scores[i]);
    red[tid] = mx; __syncthreads();
    for (int off = 64; off > 0; off >>= 1) {
        if (tid < off) red[tid] = fmaxf(red[tid], red[tid + off]);
        __syncthreads();
    }
    mx = red[0]; __syncthreads();

    float den = 0.f;
    for (int i = start + tid; i < end; i += 128) den += __expf(scores[i] - mx);
    red[tid] = den; __syncthreads();
    for (int off = 64; off > 0; off >>= 1) {
        if (tid < off) red[tid] += red[tid + off];
        __syncthreads();
    }
    den = red[0];

    float acc = 0.f;
    for (int i = start; i < end; i++)
        acc = fmaf(__expf(scores[i] - mx), full[(size_t)i * 128 + tid], acc);
    out[(size_t)s * 128 + tid] = acc / den;
}

// ---------------- launch ---------------------------------------------------

extern "C" void kernel_launch(void* const* d_in, const int* in_sizes, int n_in,
                              void* d_out, int out_size, void* d_ws, size_t ws_size,
                              hipStream_t stream) {
    (void)in_sizes; (void)n_in; (void)out_size; (void)ws_size;

    const float* leaf = (const float*)d_in[0];
    const float* emb  = (const float*)d_in[1];
    const float* Wf   = (const float*)d_in[2];
    const float* Uf   = (const float*)d_in[3];
    const float* bf   = (const float*)d_in[4];
    const float* Wb   = (const float*)d_in[5];
    const float* Ub   = (const float*)d_in[6];
    const float* bb   = (const float*)d_in[7];
    const float* proj = (const float*)d_in[8];
    const float* att  = (const float*)d_in[9];
    const int* path_elements = (const int*)d_in[10];
    const int* path_lengths  = (const int*)d_in[11];
    const int* leaf_idxs     = (const int*)d_in[12];
    const int* seg           = (const int*)d_in[13];
    float* out = (float*)d_out;

    char* ws = (char*)d_ws;
    int*    order  = (int*)ws;                         // 80,000 B
    int*    bins   = (int*)(ws + 80128);
    int*    cur    = (int*)(ws + 80384);
    ushort* Zall   = (ushort*)(ws + 81920);            // 20,480,000
    ushort* Ufrag  = (ushort*)(ws + 20561920);         // 262,144
    ushort* pfrag  = (ushort*)(ws + 20824064);         // 98,304
    ushort* Wfrag  = (ushort*)(ws + 20922368);         // 262,144
    ushort* hbuf   = (ushort*)(ws + 21184512);         // 10,240,000 (bf16)
    float*  full   = (float*)(ws + 31424512);          // 10,240,000
    float*  scores = (float*)(ws + 41664512);          // 80,000

    k_zero<<<1, 64, 0, stream>>>(bins);
    k_hist<<<(PPP + 255) / 256, 256, 0, stream>>>(path_lengths, bins, scores);
    k_scan<<<1, 64, 0, stream>>>(bins, cur);
    k_scatter<<<(PPP + 255) / 256, 256, 0, stream>>>(path_lengths, cur, order);

    dim3 gu(8, 2);
    ufrag_kernel<<<gu, 256, 0, stream>>>(Uf, Ub, Ufrag);

    dim3 gw(32, 2);
    wfrag_kernel<<<gw, 256, 0, stream>>>(Wf, Wb, Wfrag);

    projfrag_kernel<<<24, 256, 0, stream>>>(proj, pfrag);

    dim3 gz((VNT + 63) / 64, 2);
    zx_kernel<<<gz, 512, 0, stream>>>(emb, Wfrag, bf, bb, Zall);

    dim3 g((PPP + PB - 1) / PB, 2);
    lstm_kernel<<<g, 512, 0, stream>>>(Zall, Ufrag, path_elements, path_lengths,
                                       order, hbuf);

    proj_kernel<<<(PPP + 63) / 64, 512, 0, stream>>>(leaf, hbuf, pfrag, att,
                                                     leaf_idxs, full, scores);

    seg_kernel<<<SS, 128, 0, stream>>>(scores, full, seg, out);
}

// Round 9
// 398.666 us; speedup vs baseline: 6.1632x; 1.1088x over previous
//
#include <hip/hip_runtime.h>
#include <math.h>

#define PPP 20000   // paths
#define TT  30      // max timesteps
#define SS  1000    // samples
#define VNT 10000   // non-terminal vocab
#define PB  64      // paths per LSTM block
#define HSTR 152    // LDS row stride (ushorts): 304B, 16B-aligned

typedef __attribute__((ext_vector_type(8))) short short8;
typedef __attribute__((ext_vector_type(4))) float float4v;
typedef unsigned short ushort;
typedef unsigned int uint;

__device__ __forceinline__ ushort f2bf(float x) {
    uint u = __builtin_bit_cast(uint, x);
    uint r = (u + 0x7fffu + ((u >> 16) & 1u)) >> 16;
    return (ushort)r;
}
__device__ __forceinline__ float bf2f(ushort h) {
    uint u = ((uint)h) << 16;
    return __builtin_bit_cast(float, u);
}
// fast activations: v_exp_f32 + v_rcp_f32 (1-ulp; far below bf16 noise floor)
__device__ __forceinline__ float fsigmoid(float x) {
    float e = __builtin_amdgcn_exp2f(x * -1.442695040888963f);
    return __builtin_amdgcn_rcpf(1.f + e);
}
__device__ __forceinline__ float ftanh(float x) {
    float e = __builtin_amdgcn_exp2f(x * -2.885390081777927f);
    return fmaf(2.f, __builtin_amdgcn_rcpf(1.f + e), -1.f);
}

// ---------------- length bucketing (counting sort, DESCENDING) -------------

__global__ void k_zero(int* bins) {
    if (threadIdx.x < 32) bins[threadIdx.x] = 0;
}
__global__ void k_hist(const int* __restrict__ len, int* __restrict__ bins,
                       float* __restrict__ scores) {
    int p = blockIdx.x * 256 + threadIdx.x;
    if (p < PPP) { atomicAdd(&bins[len[p] - 1], 1); scores[p] = 0.f; }
}
__global__ void k_scan(const int* __restrict__ bins, int* __restrict__ cur) {
    if (threadIdx.x == 0 && blockIdx.x == 0) {
        int ofs = 0;
        for (int l = TT - 1; l >= 0; l--) { cur[l] = ofs; ofs += bins[l]; }
    }
}
__global__ void k_scatter(const int* __restrict__ len, int* __restrict__ cur,
                          int* __restrict__ order) {
    int p = blockIdx.x * 256 + threadIdx.x;
    if (p < PPP) {
        int pos = atomicAdd(&cur[len[p] - 1], 1);
        order[pos] = p;
    }
}

// ---------------- U -> bf16 B-fragment precompute ---------------------------

__global__ __launch_bounds__(256) void ufrag_kernel(
    const float* __restrict__ Uf, const float* __restrict__ Ub,
    ushort* __restrict__ Ufrag)
{
    const int d = blockIdx.y;
    const float* U = d ? Ub : Uf;
#pragma unroll
    for (int i = 0; i < 4; i++) {
        int s = blockIdx.x * 1024 + i * 256 + threadIdx.x;
        int lane = s & 63, kb = (s >> 6) & 3, g = (s >> 8) & 3, w = s >> 10;
        int krow = kb * 32 + (lane >> 4) * 8;
        int col  = g * 128 + w * 16 + (lane & 15);
        ushort* dst = Ufrag + ((size_t)d * 8192 + s) * 8;
#pragma unroll
        for (int j = 0; j < 8; j++)
            dst[j] = f2bf(U[(size_t)(krow + j) * 512 + col]);
    }
}

// ---------------- W -> bf16 B-fragment precompute ---------------------------

__global__ __launch_bounds__(256) void wfrag_kernel(
    const float* __restrict__ Wf, const float* __restrict__ Wb,
    ushort* __restrict__ Wfrag)
{
    const int d = blockIdx.y;
    const float* W = d ? Wb : Wf;
    int s = blockIdx.x * 256 + threadIdx.x;   // grid.x = 32 -> 8192
    int lane = s & 63, kb = (s >> 6) & 3, nt = s >> 8;
    int krow = kb * 32 + (lane >> 4) * 8;
    int col  = nt * 16 + (lane & 15);
    ushort* dst = Wfrag + ((size_t)d * 8192 + s) * 8;
#pragma unroll
    for (int j = 0; j < 8; j++)
        dst[j] = f2bf(W[(size_t)(krow + j) * 512 + col]);
}

// ---------------- proj -> bf16 B-fragment precompute ------------------------

__global__ __launch_bounds__(256) void projfrag_kernel(
    const float* __restrict__ proj, ushort* __restrict__ pfrag)
{
    int s = blockIdx.x * 256 + threadIdx.x;    // grid 24 -> 6144
    int lane = s & 63;
    int kb = (s >> 6) % 12;
    int nt = s / 768;
    int krow = kb * 32 + (lane >> 4) * 8;
    int col  = nt * 16 + (lane & 15);
    ushort* dst = pfrag + (size_t)s * 8;
#pragma unroll
    for (int j = 0; j < 8; j++)
        dst[j] = f2bf(proj[(size_t)(krow + j) * 128 + col]);
}

// ---------------- Zx = emb @ W + b via MFMA -> bf16 gather layout -----------

__global__ __launch_bounds__(512) void zx_kernel(
    const float* __restrict__ emb,
    const ushort* __restrict__ Wfrag,
    const float* __restrict__ bf, const float* __restrict__ bb,
    ushort* __restrict__ Zall)
{
    const int dir = blockIdx.y;
    const ushort* WfD = Wfrag + (size_t)dir * 65536;
    const float* bias = dir ? bb : bf;
    ushort* Z = Zall + (size_t)dir * VNT * 512;

    __shared__ union {
        ushort At[64][HSTR];   // A tile: 64 tokens x 128 k (bf16)
        ushort Zt[64][520];    // C bounce: 64 tokens x 512 cols (bf16)
    } sm;

    const int tid  = threadIdx.x;
    const int w    = tid >> 6;
    const int lane = tid & 63;
    const int quad = lane >> 4;
    const int l    = lane & 15;
    const int tok0 = blockIdx.x * 64;

    {
        const int p = tid >> 3, ch = tid & 7;
        int tok = tok0 + p; if (tok > VNT - 1) tok = VNT - 1;
        const float4* src = (const float4*)(emb + (size_t)tok * 128 + ch * 16);
        ushort v[16];
#pragma unroll
        for (int q = 0; q < 4; q++) {
            float4 f = src[q];
            v[q * 4 + 0] = f2bf(f.x); v[q * 4 + 1] = f2bf(f.y);
            v[q * 4 + 2] = f2bf(f.z); v[q * 4 + 3] = f2bf(f.w);
        }
        *(int4*)&sm.At[p][ch * 16]     = *(const int4*)&v[0];
        *(int4*)&sm.At[p][ch * 16 + 8] = *(const int4*)&v[8];
    }

    short8 bq[4][4];   // [nt4][kb]
#pragma unroll
    for (int nt4 = 0; nt4 < 4; nt4++)
#pragma unroll
        for (int kb = 0; kb < 4; kb++)
            bq[nt4][kb] = *(const short8*)(WfD + (size_t)(((w * 4 + nt4) * 4 + kb) * 64 + lane) * 8);

    __syncthreads();

    float4v acc[4][4];     // [mt][nt4]
#pragma unroll
    for (int mt = 0; mt < 4; mt++)
#pragma unroll
        for (int nt4 = 0; nt4 < 4; nt4++) {
            float4v z4 = {0.f, 0.f, 0.f, 0.f};
            acc[mt][nt4] = z4;
        }

#pragma unroll
    for (int kb = 0; kb < 4; kb++) {
        short8 af[4];
#pragma unroll
        for (int mt = 0; mt < 4; mt++)
            af[mt] = *(const short8*)&sm.At[mt * 16 + l][kb * 32 + quad * 8];
#pragma unroll
        for (int nt4 = 0; nt4 < 4; nt4++)
#pragma unroll
            for (int mt = 0; mt < 4; mt++)
                acc[mt][nt4] = __builtin_amdgcn_mfma_f32_16x16x32_bf16(
                    af[mt], bq[nt4][kb], acc[mt][nt4], 0, 0, 0);
    }

    float bv[4];
#pragma unroll
    for (int nt4 = 0; nt4 < 4; nt4++)
        bv[nt4] = bias[(w * 4 + nt4) * 16 + l];

    __syncthreads();   // all At reads done; union switches to Zt

#pragma unroll
    for (int mt = 0; mt < 4; mt++)
#pragma unroll
        for (int r = 0; r < 4; r++) {
            const int p = mt * 16 + quad * 4 + r;
#pragma unroll
            for (int nt4 = 0; nt4 < 4; nt4++)
                sm.Zt[p][(w * 4 + nt4) * 16 + l] = f2bf(acc[mt][nt4][r] + bv[nt4]);
        }
    __syncthreads();

#pragma unroll
    for (int i = 0; i < 16; i++) {
        int s = i * 512 + tid;          // 0..8191
        int pt = s >> 7;                // token row 0..63
        int u  = s & 127;
        int tok = tok0 + pt;
        if (tok < VNT) {
            ushort v[4];
#pragma unroll
            for (int g = 0; g < 4; g++)
                v[g] = sm.Zt[pt][g * 128 + u];
            *(uint2*)(Z + (size_t)tok * 512 + u * 4) = *(const uint2*)v;
        }
    }
}

// ---------------- MFMA LSTM (zv software-pipelined) -------------------------
// 64 paths, 512 threads (8 waves). Wave w owns hidden cols [w*16,w*16+16) of
// each gate; U B-frags in registers. h: double-buffered bf16 planes.
// Zx gather double-buffered in registers: step t+1's loads issue before step
// t's MFMA section -> full step of latency cover. acc C-operand preloaded
// with the Zx contribution (identical fp32 math).

__global__ __launch_bounds__(512) void lstm_kernel(
    const ushort* __restrict__ Zall,
    const ushort* __restrict__ Ufrag,
    const int* __restrict__ path_elements, const int* __restrict__ path_lengths,
    const int* __restrict__ order,
    ushort* __restrict__ h_out)   // bf16 [2][P][128]
{
    const int dir = blockIdx.y;
    const ushort* ZxD = Zall + (size_t)dir * VNT * 512;
    const ushort* UfD = Ufrag + (size_t)dir * 65536;

    __shared__ ushort hp[2][64][HSTR]; // bf16 h planes (A-layout)
    __shared__ int s_tok[TT][64];
    __shared__ int s_pid[PB];
    __shared__ int s_len[PB];

    const int tid  = threadIdx.x;
    const int w    = tid >> 6;         // wave 0..7
    const int lane = tid & 63;
    const int quad = lane >> 4;
    const int l    = lane & 15;

    if (tid < PB) {
        int idx = blockIdx.x * PB + tid;
        if (idx > PPP - 1) idx = PPP - 1;
        int pid = order[idx];
        s_pid[tid] = pid;
        s_len[tid] = path_lengths[pid];
    }
    for (int i = tid; i < 2 * 64 * (HSTR / 2); i += 512) ((uint*)&hp[0][0][0])[i] = 0;
    __syncthreads();

    for (int i = tid; i < 64 * TT; i += 512) {
        int p = i & 63, t = i >> 6;
        s_tok[t][p] = path_elements[(size_t)s_pid[p] * TT + t];
    }

    short8 bfrag[4][4];
#pragma unroll
    for (int g = 0; g < 4; g++)
#pragma unroll
        for (int kb = 0; kb < 4; kb++)
            bfrag[g][kb] = *(const short8*)(UfD + (size_t)(((w * 4 + g) * 4 + kb) * 64 + lane) * 8);

    __syncthreads();

    const int maxLen = s_len[0];       // descending sort

    // min length over my 16 rows (largest p I own -> shortest path)
    int lenMin = s_len[3 * 16 + quad * 4 + 3];

    float c_st[16];
#pragma unroll
    for (int i = 0; i < 16; i++) c_st[i] = 0.f;

    uint2 zvA[16], zvB[16];
    {
        const int t0 = dir ? (maxLen - 1) : 0;
#pragma unroll
        for (int mt = 0; mt < 4; mt++)
#pragma unroll
            for (int r = 0; r < 4; r++) {
                int tok = s_tok[t0][mt * 16 + quad * 4 + r];
                zvA[mt * 4 + r] = *(const uint2*)(ZxD + (size_t)tok * 512 + (w * 16 + l) * 4);
            }
    }

    auto stepBody = [&](int step, uint2 (&zvC)[16], uint2 (&zvN)[16]) {
        const int cu = step & 1, nx = cu ^ 1;
        const int t = dir ? (maxLen - 1 - step) : step;

        // acc preload: C = Zx contribution (bf16->f32), arrived last step
        float4v acc[4][4];             // [mt][g]
#pragma unroll
        for (int mt = 0; mt < 4; mt++)
#pragma unroll
            for (int r = 0; r < 4; r++) {
                const uint2 z2 = zvC[mt * 4 + r];
                acc[mt][0][r] = bf2f((ushort)(z2.x & 0xffff));
                acc[mt][1][r] = bf2f((ushort)(z2.x >> 16));
                acc[mt][2][r] = bf2f((ushort)(z2.y & 0xffff));
                acc[mt][3][r] = bf2f((ushort)(z2.y >> 16));
            }

        // prefetch next step's Zx (covered by MFMA + gating + barrier)
        {
            const int stepn = (step + 1 < maxLen) ? step + 1 : step;
            const int tn = dir ? (maxLen - 1 - stepn) : stepn;
#pragma unroll
            for (int mt = 0; mt < 4; mt++)
#pragma unroll
                for (int r = 0; r < 4; r++) {
                    int tok = s_tok[tn][mt * 16 + quad * 4 + r];
                    zvN[mt * 4 + r] = *(const uint2*)(ZxD + (size_t)tok * 512 + (w * 16 + l) * 4);
                }
        }

#pragma unroll
        for (int kb = 0; kb < 4; kb++) {
            short8 af[4];
#pragma unroll
            for (int mt = 0; mt < 4; mt++)
                af[mt] = *(const short8*)&hp[cu][mt * 16 + l][kb * 32 + quad * 8];
#pragma unroll
            for (int g = 0; g < 4; g++)
#pragma unroll
                for (int mt = 0; mt < 4; mt++)
                    acc[mt][g] = __builtin_amdgcn_mfma_f32_16x16x32_bf16(
                        af[mt], bfrag[g][kb], acc[mt][g], 0, 0, 0);
        }

        if (t < lenMin) {
            // fast path: all my 16 paths valid (most blocks are single-length)
#pragma unroll
            for (int mt = 0; mt < 4; mt++)
#pragma unroll
                for (int r = 0; r < 4; r++) {
                    const int p = mt * 16 + quad * 4 + r;
                    float ig = fsigmoid(acc[mt][0][r]);
                    float fg = fsigmoid(acc[mt][1][r]);
                    float gg = ftanh(acc[mt][2][r]);
                    float og = fsigmoid(acc[mt][3][r]);
                    float cn = fg * c_st[mt * 4 + r] + ig * gg;
                    float hn = og * ftanh(cn);
                    c_st[mt * 4 + r] = cn;
                    hp[nx][p][w * 16 + l] = f2bf(hn);
                }
        } else {
#pragma unroll
            for (int mt = 0; mt < 4; mt++)
#pragma unroll
                for (int r = 0; r < 4; r++) {
                    const int p = mt * 16 + quad * 4 + r;
                    const bool valid = t < s_len[p];
                    const ushort hold = hp[cu][p][w * 16 + l];
                    float ig = fsigmoid(acc[mt][0][r]);
                    float fg = fsigmoid(acc[mt][1][r]);
                    float gg = ftanh(acc[mt][2][r]);
                    float og = fsigmoid(acc[mt][3][r]);
                    float cn = fg * c_st[mt * 4 + r] + ig * gg;
                    float hn = og * ftanh(cn);
                    if (valid) c_st[mt * 4 + r] = cn;
                    hp[nx][p][w * 16 + l] = valid ? f2bf(hn) : hold;
                }
        }
        __syncthreads();
    };

    for (int step = 0; step < maxLen; step += 2) {
        stepBody(step, zvA, zvB);
        if (step + 1 < maxLen) stepBody(step + 1, zvB, zvA);
    }

    // epilogue: final plane -> bf16 h_out
    {
        const int fin = maxLen & 1;
        const int pg = tid >> 3;       // 0..63
        const int ch = tid & 7;        // 0..7 -> 16 cols
        ushort* dst = h_out + ((size_t)dir * PPP + s_pid[pg]) * 128 + ch * 16;
        *(int4*)dst       = *(const int4*)&hp[fin][pg][ch * 16];
        *(int4*)(dst + 8) = *(const int4*)&hp[fin][pg][ch * 16 + 8];
    }
}

// ---------------- MFMA projection + fused attention scores -----------------

__global__ __launch_bounds__(512) void proj_kernel(
    const float* __restrict__ leaf, const ushort* __restrict__ hbuf,
    const ushort* __restrict__ pfrag, const float* __restrict__ att,
    const int* __restrict__ leaf_idxs,
    float* __restrict__ full, float* __restrict__ scores)
{
    __shared__ ushort Vb[64][400];     // bf16, 16B-aligned rows
    __shared__ int s_lidx[64][2];

    const int tid  = threadIdx.x;
    const int w    = tid >> 6;
    const int lane = tid & 63;
    const int quad = lane >> 4;
    const int l    = lane & 15;
    const int p0   = blockIdx.x * 64;

    if (tid < 128) {
        int p = tid >> 1;
        int pg = p0 + p; if (pg > PPP - 1) pg = PPP - 1;
        s_lidx[p][tid & 1] = leaf_idxs[(size_t)pg * 2 + (tid & 1)];
    }
    __syncthreads();

    for (int s = tid; s < 64 * 192; s += 512) {
        int p = s / 192, cp = s % 192;
        int c = cp * 2;
        int pg = p0 + p; if (pg > PPP - 1) pg = PPP - 1;
        uint val;
        if (c < 128) {
            const float* src = leaf + (size_t)s_lidx[p][c >> 6] * 64 + (c & 63);
            float2 f = *(const float2*)src;
            val = (uint)f2bf(f.x) | ((uint)f2bf(f.y) << 16);
        } else {
            const ushort* src = hbuf + ((size_t)(c < 256 ? 0 : 1) * PPP + pg) * 128 + (c & 127);
            val = *(const uint*)src;
        }
        *(uint*)&Vb[p][c] = val;
    }

    short8 bq[12];
#pragma unroll
    for (int kb = 0; kb < 12; kb++)
        bq[kb] = *(const short8*)(pfrag + ((size_t)w * 768 + kb * 64 + lane) * 8);

    __syncthreads();

    float4v acc[4];
#pragma unroll
    for (int mt = 0; mt < 4; mt++) {
        float4v z4 = {0.f, 0.f, 0.f, 0.f};
        acc[mt] = z4;
    }

#pragma unroll
    for (int kb = 0; kb < 12; kb++) {
#pragma unroll
        for (int mt = 0; mt < 4; mt++) {
            short8 af = *(const short8*)&Vb[mt * 16 + l][kb * 32 + quad * 8];
            acc[mt] = __builtin_amdgcn_mfma_f32_16x16x32_bf16(af, bq[kb], acc[mt], 0, 0, 0);
        }
    }

    const int col = w * 16 + l;
    const float attc = att[col];
#pragma unroll
    for (int mt = 0; mt < 4; mt++)
#pragma unroll
        for (int r = 0; r < 4; r++) {
            int row = mt * 16 + quad * 4 + r;
            int pg = p0 + row;
            float v = acc[mt][r];
            if (pg < PPP) full[(size_t)pg * 128 + col] = v;
            float part = v * attc;
            part += __shfl_xor(part, 1);
            part += __shfl_xor(part, 2);
            part += __shfl_xor(part, 4);
            part += __shfl_xor(part, 8);
            if (l == 0 && pg < PPP) atomicAdd(&scores[pg], part);
        }
}

// ---------------- segment softmax + weighted sum (512 threads) --------------

__global__ __launch_bounds__(512) void seg_kernel(
    const float* __restrict__ scores, const float* __restrict__ full,
    const int* __restrict__ seg, float* __restrict__ out)
{
    const int s = blockIdx.x;
    const int tid = threadIdx.x;

    int lo = 0, hi = PPP;
    while (lo < hi) { int mid = (lo + hi) >> 1; if (seg[mid] < s) lo = mid + 1; else hi = mid; }
    const int start = lo;
    lo = start; hi = PPP;
    while (lo < hi) { int mid = (lo + hi) >> 1; if (seg[mid] < s + 1) lo = mid + 1; else hi = mid; }
    const int end = lo;

    if (start >= end) {
        if (tid < 128) out[(size_t)s * 128 + tid] = 0.f;
        return;
    }

    __shared__ float red[512];

    float mx = -1e30f;
    for (int i = start + tid; i < end; i += 512) mx = fmaxf(mx, scores[i]);
    red[tid] = mx; __syncthreads();
    for (int off = 256; off > 0; off >>= 1) {
        if (tid < off) red[tid] = fmaxf(red[tid], red[tid + off]);
        __syncthreads();
    }
    mx = red[0]; __syncthreads();

    float den = 0.f;
    for (int i = start + tid; i < end; i += 512) den += __expf(scores[i] - mx);
    red[tid] = den; __syncthreads();
    for (int off = 256; off > 0; off >>= 1) {
        if (tid < off) red[tid] += red[tid + off];
        __syncthreads();
    }
    den = red[0]; __syncthreads();

    const int col = tid & 127;
    const int pp  = tid >> 7;         // 0..3: 4 paths in flight
    float acc = 0.f;
    for (int i = start + pp; i < end; i += 4)
        acc = fmaf(__expf(scores[i] - mx), full[(size_t)i * 128 + col], acc);
    red[tid] = acc; __syncthreads();
    if (tid < 128)
        out[(size_t)s * 128 + tid] =
            (red[tid] + red[tid + 128] + red[tid + 256] + red[tid + 384]) / den;
}

// ---------------- launch ---------------------------------------------------

extern "C" void kernel_launch(void* const* d_in, const int* in_sizes, int n_in,
                              void* d_out, int out_size, void* d_ws, size_t ws_size,
                              hipStream_t stream) {
    (void)in_sizes; (void)n_in; (void)out_size; (void)ws_size;

    const float* leaf = (const float*)d_in[0];
    const float* emb  = (const float*)d_in[1];
    const float* Wf   = (const float*)d_in[2];
    const float* Uf   = (const float*)d_in[3];
    const float* bf   = (const float*)d_in[4];
    const float* Wb   = (const float*)d_in[5];
    const float* Ub   = (const float*)d_in[6];
    const float* bb   = (const float*)d_in[7];
    const float* proj = (const float*)d_in[8];
    const float* att  = (const float*)d_in[9];
    const int* path_elements = (const int*)d_in[10];
    const int* path_lengths  = (const int*)d_in[11];
    const int* leaf_idxs     = (const int*)d_in[12];
    const int* seg           = (const int*)d_in[13];
    float* out = (float*)d_out;

    char* ws = (char*)d_ws;
    int*    order  = (int*)ws;                         // 80,000 B
    int*    bins   = (int*)(ws + 80128);
    int*    cur    = (int*)(ws + 80384);
    ushort* Zall   = (ushort*)(ws + 81920);            // 20,480,000
    ushort* Ufrag  = (ushort*)(ws + 20561920);         // 262,144
    ushort* pfrag  = (ushort*)(ws + 20824064);         // 98,304
    ushort* Wfrag  = (ushort*)(ws + 20922368);         // 262,144
    ushort* hbuf   = (ushort*)(ws + 21184512);         // 10,240,000 (bf16)
    float*  full   = (float*)(ws + 31424512);          // 10,240,000
    float*  scores = (float*)(ws + 41664512);          // 80,000

    k_zero<<<1, 64, 0, stream>>>(bins);
    k_hist<<<(PPP + 255) / 256, 256, 0, stream>>>(path_lengths, bins, scores);
    k_scan<<<1, 64, 0, stream>>>(bins, cur);
    k_scatter<<<(PPP + 255) / 256, 256, 0, stream>>>(path_lengths, cur, order);

    dim3 gu(8, 2);
    ufrag_kernel<<<gu, 256, 0, stream>>>(Uf, Ub, Ufrag);

    dim3 gw(32, 2);
    wfrag_kernel<<<gw, 256, 0, stream>>>(Wf, Wb, Wfrag);

    projfrag_kernel<<<24, 256, 0, stream>>>(proj, pfrag);

    dim3 gz((VNT + 63) / 64, 2);
    zx_kernel<<<gz, 512, 0, stream>>>(emb, Wfrag, bf, bb, Zall);

    dim3 g((PPP + PB - 1) / PB, 2);
    lstm_kernel<<<g, 512, 0, stream>>>(Zall, Ufrag, path_elements, path_lengths,
                                       order, hbuf);

    proj_kernel<<<(PPP + 63) / 64, 512, 0, stream>>>(leaf, hbuf, pfrag, att,
                                                     leaf_idxs, full, scores);

    seg_kernel<<<SS, 512, 0, stream>>>(scores, full, seg, out);
}

// Round 10
// 386.145 us; speedup vs baseline: 6.3631x; 1.0324x over previous
//
#include <hip/hip_runtime.h>
#include <math.h>

#define PPP 20000   // paths
#define TT  30      // max timesteps
#define SS  1000    // samples
#define VNT 10000   // non-terminal vocab
#define PB  64      // paths per LSTM block
#define HSTR 152    // LDS row stride (ushorts): 304B, 16B-aligned

typedef __attribute__((ext_vector_type(8))) short short8;
typedef __attribute__((ext_vector_type(4))) float float4v;
typedef unsigned short ushort;
typedef unsigned int uint;

#define NLOG2E  -1.442695040888963f   // -log2(e): fold for sigmoid gates
#define N2LOG2E -2.885390081777927f   // -2log2(e): fold for tanh gate

__device__ __forceinline__ ushort f2bf(float x) {
    uint u = __builtin_bit_cast(uint, x);
    uint r = (u + 0x7fffu + ((u >> 16) & 1u)) >> 16;
    return (ushort)r;
}
__device__ __forceinline__ float bf2f(ushort h) {
    uint u = ((uint)h) << 16;
    return __builtin_bit_cast(float, u);
}
// pre-scaled activations: input already multiplied by -log2e (sig) / -2log2e (tanh)
__device__ __forceinline__ float fsig_s(float zs) {          // zs = -log2e * z
    return __builtin_amdgcn_rcpf(1.f + __builtin_amdgcn_exp2f(zs));
}
__device__ __forceinline__ float ftanh_s(float zs) {         // zs = -2log2e * z
    return fmaf(2.f, __builtin_amdgcn_rcpf(1.f + __builtin_amdgcn_exp2f(zs)), -1.f);
}
__device__ __forceinline__ float ftanh(float x) {            // runtime scale (for cn)
    return ftanh_s(x * N2LOG2E);
}

// ---------------- length bucketing (counting sort, DESCENDING) -------------

__global__ void k_zero(int* bins) {
    if (threadIdx.x < 32) bins[threadIdx.x] = 0;
}
__global__ void k_hist(const int* __restrict__ len, int* __restrict__ bins,
                       float* __restrict__ scores) {
    int p = blockIdx.x * 256 + threadIdx.x;
    if (p < PPP) { atomicAdd(&bins[len[p] - 1], 1); scores[p] = 0.f; }
}
__global__ void k_scan(const int* __restrict__ bins, int* __restrict__ cur) {
    if (threadIdx.x == 0 && blockIdx.x == 0) {
        int ofs = 0;
        for (int l = TT - 1; l >= 0; l--) { cur[l] = ofs; ofs += bins[l]; }
    }
}
__global__ void k_scatter(const int* __restrict__ len, int* __restrict__ cur,
                          int* __restrict__ order) {
    int p = blockIdx.x * 256 + threadIdx.x;
    if (p < PPP) {
        int pos = atomicAdd(&cur[len[p] - 1], 1);
        order[pos] = p;
    }
}

// ---------------- fused fragment precompute ---------------------------------
// U/W frags get the per-gate activation scale FOLDED IN (i,f,o: -log2e;
// g: -2log2e). slots: [0,16384) ufrag, [16384,32768) wfrag, [32768,38912) pfrag.

__global__ __launch_bounds__(256) void frag_kernel(
    const float* __restrict__ Uf, const float* __restrict__ Ub,
    const float* __restrict__ Wf, const float* __restrict__ Wb,
    const float* __restrict__ proj,
    ushort* __restrict__ Ufrag, ushort* __restrict__ Wfrag,
    ushort* __restrict__ pfrag)
{
    const float gsc[4] = {NLOG2E, NLOG2E, N2LOG2E, NLOG2E};
    int gs = blockIdx.x * 256 + threadIdx.x;     // 0..38911
    if (gs < 16384) {                            // ufrag
        int d = gs >> 13, s = gs & 8191;
        const float* U = d ? Ub : Uf;
        int lane = s & 63, kb = (s >> 6) & 3, g = (s >> 8) & 3, w = s >> 10;
        int krow = kb * 32 + (lane >> 4) * 8;
        int col  = g * 128 + w * 16 + (lane & 15);
        float sc = gsc[g];
        ushort* dst = Ufrag + (size_t)gs * 8;
#pragma unroll
        for (int j = 0; j < 8; j++)
            dst[j] = f2bf(U[(size_t)(krow + j) * 512 + col] * sc);
    } else if (gs < 32768) {                     // wfrag
        int t = gs - 16384;
        int d = t >> 13, s = t & 8191;
        const float* W = d ? Wb : Wf;
        int lane = s & 63, kb = (s >> 6) & 3, nt = s >> 8;
        int krow = kb * 32 + (lane >> 4) * 8;
        int col  = nt * 16 + (lane & 15);
        float sc = gsc[col >> 7];
        ushort* dst = Wfrag + (size_t)t * 8;
#pragma unroll
        for (int j = 0; j < 8; j++)
            dst[j] = f2bf(W[(size_t)(krow + j) * 512 + col] * sc);
    } else {                                     // pfrag (no scaling)
        int s = gs - 32768;                      // 0..6143
        int lane = s & 63;
        int kb = (s >> 6) % 12;
        int nt = s / 768;
        int krow = kb * 32 + (lane >> 4) * 8;
        int col  = nt * 16 + (lane & 15);
        ushort* dst = pfrag + (size_t)s * 8;
#pragma unroll
        for (int j = 0; j < 8; j++)
            dst[j] = f2bf(proj[(size_t)(krow + j) * 128 + col]);
    }
}

// ---------------- Zx = emb @ W + b via MFMA -> bf16 gather layout -----------
// (W already gate-scaled; bias scaled here to match)

__global__ __launch_bounds__(512) void zx_kernel(
    const float* __restrict__ emb,
    const ushort* __restrict__ Wfrag,
    const float* __restrict__ bf, const float* __restrict__ bb,
    ushort* __restrict__ Zall)
{
    const float gsc[4] = {NLOG2E, NLOG2E, N2LOG2E, NLOG2E};
    const int dir = blockIdx.y;
    const ushort* WfD = Wfrag + (size_t)dir * 65536;
    const float* bias = dir ? bb : bf;
    ushort* Z = Zall + (size_t)dir * VNT * 512;

    __shared__ union {
        ushort At[64][HSTR];   // A tile: 64 tokens x 128 k (bf16)
        ushort Zt[64][520];    // C bounce: 64 tokens x 512 cols (bf16)
    } sm;

    const int tid  = threadIdx.x;
    const int w    = tid >> 6;
    const int lane = tid & 63;
    const int quad = lane >> 4;
    const int l    = lane & 15;
    const int tok0 = blockIdx.x * 64;

    {
        const int p = tid >> 3, ch = tid & 7;
        int tok = tok0 + p; if (tok > VNT - 1) tok = VNT - 1;
        const float4* src = (const float4*)(emb + (size_t)tok * 128 + ch * 16);
        ushort v[16];
#pragma unroll
        for (int q = 0; q < 4; q++) {
            float4 f = src[q];
            v[q * 4 + 0] = f2bf(f.x); v[q * 4 + 1] = f2bf(f.y);
            v[q * 4 + 2] = f2bf(f.z); v[q * 4 + 3] = f2bf(f.w);
        }
        *(int4*)&sm.At[p][ch * 16]     = *(const int4*)&v[0];
        *(int4*)&sm.At[p][ch * 16 + 8] = *(const int4*)&v[8];
    }

    short8 bq[4][4];   // [nt4][kb]
#pragma unroll
    for (int nt4 = 0; nt4 < 4; nt4++)
#pragma unroll
        for (int kb = 0; kb < 4; kb++)
            bq[nt4][kb] = *(const short8*)(WfD + (size_t)(((w * 4 + nt4) * 4 + kb) * 64 + lane) * 8);

    __syncthreads();

    float4v acc[4][4];     // [mt][nt4]
#pragma unroll
    for (int mt = 0; mt < 4; mt++)
#pragma unroll
        for (int nt4 = 0; nt4 < 4; nt4++) {
            float4v z4 = {0.f, 0.f, 0.f, 0.f};
            acc[mt][nt4] = z4;
        }

#pragma unroll
    for (int kb = 0; kb < 4; kb++) {
        short8 af[4];
#pragma unroll
        for (int mt = 0; mt < 4; mt++)
            af[mt] = *(const short8*)&sm.At[mt * 16 + l][kb * 32 + quad * 8];
#pragma unroll
        for (int nt4 = 0; nt4 < 4; nt4++)
#pragma unroll
            for (int mt = 0; mt < 4; mt++)
                acc[mt][nt4] = __builtin_amdgcn_mfma_f32_16x16x32_bf16(
                    af[mt], bq[nt4][kb], acc[mt][nt4], 0, 0, 0);
    }

    float bv[4];
#pragma unroll
    for (int nt4 = 0; nt4 < 4; nt4++) {
        int col = (w * 4 + nt4) * 16 + l;
        bv[nt4] = bias[col] * gsc[col >> 7];
    }

    __syncthreads();   // all At reads done; union switches to Zt

#pragma unroll
    for (int mt = 0; mt < 4; mt++)
#pragma unroll
        for (int r = 0; r < 4; r++) {
            const int p = mt * 16 + quad * 4 + r;
#pragma unroll
            for (int nt4 = 0; nt4 < 4; nt4++)
                sm.Zt[p][(w * 4 + nt4) * 16 + l] = f2bf(acc[mt][nt4][r] + bv[nt4]);
        }
    __syncthreads();

#pragma unroll
    for (int i = 0; i < 16; i++) {
        int s = i * 512 + tid;          // 0..8191
        int pt = s >> 7;                // token row 0..63
        int u  = s & 127;
        int tok = tok0 + pt;
        if (tok < VNT) {
            ushort v[4];
#pragma unroll
            for (int g = 0; g < 4; g++)
                v[g] = sm.Zt[pt][g * 128 + u];
            *(uint2*)(Z + (size_t)tok * 512 + u * 4) = *(const uint2*)v;
        }
    }
}

// ---------------- MFMA LSTM (zv software-pipelined, scales folded) ----------

__global__ __launch_bounds__(512) void lstm_kernel(
    const ushort* __restrict__ Zall,
    const ushort* __restrict__ Ufrag,
    const int* __restrict__ path_elements, const int* __restrict__ path_lengths,
    const int* __restrict__ order,
    ushort* __restrict__ h_out)   // bf16 [2][P][128]
{
    const int dir = blockIdx.y;
    const ushort* ZxD = Zall + (size_t)dir * VNT * 512;
    const ushort* UfD = Ufrag + (size_t)dir * 65536;

    __shared__ ushort hp[2][64][HSTR]; // bf16 h planes (A-layout)
    __shared__ int s_tok[TT][64];
    __shared__ int s_pid[PB];
    __shared__ int s_len[PB];

    const int tid  = threadIdx.x;
    const int w    = tid >> 6;         // wave 0..7
    const int lane = tid & 63;
    const int quad = lane >> 4;
    const int l    = lane & 15;

    if (tid < PB) {
        int idx = blockIdx.x * PB + tid;
        if (idx > PPP - 1) idx = PPP - 1;
        int pid = order[idx];
        s_pid[tid] = pid;
        s_len[tid] = path_lengths[pid];
    }
    for (int i = tid; i < 2 * 64 * (HSTR / 2); i += 512) ((uint*)&hp[0][0][0])[i] = 0;
    __syncthreads();

    for (int i = tid; i < 64 * TT; i += 512) {
        int p = i & 63, t = i >> 6;
        s_tok[t][p] = path_elements[(size_t)s_pid[p] * TT + t];
    }

    short8 bfrag[4][4];
#pragma unroll
    for (int g = 0; g < 4; g++)
#pragma unroll
        for (int kb = 0; kb < 4; kb++)
            bfrag[g][kb] = *(const short8*)(UfD + (size_t)(((w * 4 + g) * 4 + kb) * 64 + lane) * 8);

    __syncthreads();

    const int maxLen = s_len[0];       // descending sort

    // min length over my 16 rows (largest p I own -> shortest path)
    int lenMin = s_len[3 * 16 + quad * 4 + 3];

    float c_st[16];
#pragma unroll
    for (int i = 0; i < 16; i++) c_st[i] = 0.f;

    uint2 zvA[16], zvB[16];
    {
        const int t0 = dir ? (maxLen - 1) : 0;
#pragma unroll
        for (int mt = 0; mt < 4; mt++)
#pragma unroll
            for (int r = 0; r < 4; r++) {
                int tok = s_tok[t0][mt * 16 + quad * 4 + r];
                zvA[mt * 4 + r] = *(const uint2*)(ZxD + (size_t)tok * 512 + (w * 16 + l) * 4);
            }
    }

    auto stepBody = [&](int step, uint2 (&zvC)[16], uint2 (&zvN)[16]) {
        const int cu = step & 1, nx = cu ^ 1;
        const int t = dir ? (maxLen - 1 - step) : step;

        // acc preload: C = Zx contribution (bf16->f32), arrived last step
        float4v acc[4][4];             // [mt][g]
#pragma unroll
        for (int mt = 0; mt < 4; mt++)
#pragma unroll
            for (int r = 0; r < 4; r++) {
                const uint2 z2 = zvC[mt * 4 + r];
                acc[mt][0][r] = bf2f((ushort)(z2.x & 0xffff));
                acc[mt][1][r] = bf2f((ushort)(z2.x >> 16));
                acc[mt][2][r] = bf2f((ushort)(z2.y & 0xffff));
                acc[mt][3][r] = bf2f((ushort)(z2.y >> 16));
            }

        // prefetch next step's Zx (covered by MFMA + gating + barrier)
        {
            const int stepn = (step + 1 < maxLen) ? step + 1 : step;
            const int tn = dir ? (maxLen - 1 - stepn) : stepn;
#pragma unroll
            for (int mt = 0; mt < 4; mt++)
#pragma unroll
                for (int r = 0; r < 4; r++) {
                    int tok = s_tok[tn][mt * 16 + quad * 4 + r];
                    zvN[mt * 4 + r] = *(const uint2*)(ZxD + (size_t)tok * 512 + (w * 16 + l) * 4);
                }
        }

#pragma unroll
        for (int kb = 0; kb < 4; kb++) {
            short8 af[4];
#pragma unroll
            for (int mt = 0; mt < 4; mt++)
                af[mt] = *(const short8*)&hp[cu][mt * 16 + l][kb * 32 + quad * 8];
#pragma unroll
            for (int g = 0; g < 4; g++)
#pragma unroll
                for (int mt = 0; mt < 4; mt++)
                    acc[mt][g] = __builtin_amdgcn_mfma_f32_16x16x32_bf16(
                        af[mt], bfrag[g][kb], acc[mt][g], 0, 0, 0);
        }

        if (t < lenMin) {
            // fast path: all my 16 paths valid
#pragma unroll
            for (int mt = 0; mt < 4; mt++)
#pragma unroll
                for (int r = 0; r < 4; r++) {
                    const int p = mt * 16 + quad * 4 + r;
                    float ig = fsig_s(acc[mt][0][r]);
                    float fg = fsig_s(acc[mt][1][r]);
                    float gg = ftanh_s(acc[mt][2][r]);
                    float og = fsig_s(acc[mt][3][r]);
                    float cn = fg * c_st[mt * 4 + r] + ig * gg;
                    float hn = og * ftanh(cn);
                    c_st[mt * 4 + r] = cn;
                    hp[nx][p][w * 16 + l] = f2bf(hn);
                }
        } else {
#pragma unroll
            for (int mt = 0; mt < 4; mt++)
#pragma unroll
                for (int r = 0; r < 4; r++) {
                    const int p = mt * 16 + quad * 4 + r;
                    const bool valid = t < s_len[p];
                    const ushort hold = hp[cu][p][w * 16 + l];
                    float ig = fsig_s(acc[mt][0][r]);
                    float fg = fsig_s(acc[mt][1][r]);
                    float gg = ftanh_s(acc[mt][2][r]);
                    float og = fsig_s(acc[mt][3][r]);
                    float cn = fg * c_st[mt * 4 + r] + ig * gg;
                    float hn = og * ftanh(cn);
                    if (valid) c_st[mt * 4 + r] = cn;
                    hp[nx][p][w * 16 + l] = valid ? f2bf(hn) : hold;
                }
        }
        __syncthreads();
    };

    for (int step = 0; step < maxLen; step += 2) {
        stepBody(step, zvA, zvB);
        if (step + 1 < maxLen) stepBody(step + 1, zvB, zvA);
    }

    // epilogue: final plane -> bf16 h_out
    {
        const int fin = maxLen & 1;
        const int pg = tid >> 3;       // 0..63
        const int ch = tid & 7;        // 0..7 -> 16 cols
        ushort* dst = h_out + ((size_t)dir * PPP + s_pid[pg]) * 128 + ch * 16;
        *(int4*)dst       = *(const int4*)&hp[fin][pg][ch * 16];
        *(int4*)(dst + 8) = *(const int4*)&hp[fin][pg][ch * 16 + 8];
    }
}

// ---------------- MFMA projection + fused attention scores -----------------

__global__ __launch_bounds__(512) void proj_kernel(
    const float* __restrict__ leaf, const ushort* __restrict__ hbuf,
    const ushort* __restrict__ pfrag, const float* __restrict__ att,
    const int* __restrict__ leaf_idxs,
    float* __restrict__ full, float* __restrict__ scores)
{
    __shared__ ushort Vb[64][400];     // bf16, 16B-aligned rows
    __shared__ int s_lidx[64][2];

    const int tid  = threadIdx.x;
    const int w    = tid >> 6;
    const int lane = tid & 63;
    const int quad = lane >> 4;
    const int l    = lane & 15;
    const int p0   = blockIdx.x * 64;

    if (tid < 128) {
        int p = tid >> 1;
        int pg = p0 + p; if (pg > PPP - 1) pg = PPP - 1;
        s_lidx[p][tid & 1] = leaf_idxs[(size_t)pg * 2 + (tid & 1)];
    }
    __syncthreads();

    for (int s = tid; s < 64 * 192; s += 512) {
        int p = s / 192, cp = s % 192;
        int c = cp * 2;
        int pg = p0 + p; if (pg > PPP - 1) pg = PPP - 1;
        uint val;
        if (c < 128) {
            const float* src = leaf + (size_t)s_lidx[p][c >> 6] * 64 + (c & 63);
            float2 f = *(const float2*)src;
            val = (uint)f2bf(f.x) | ((uint)f2bf(f.y) << 16);
        } else {
            const ushort* src = hbuf + ((size_t)(c < 256 ? 0 : 1) * PPP + pg) * 128 + (c & 127);
            val = *(const uint*)src;
        }
        *(uint*)&Vb[p][c] = val;
    }

    short8 bq[12];
#pragma unroll
    for (int kb = 0; kb < 12; kb++)
        bq[kb] = *(const short8*)(pfrag + ((size_t)w * 768 + kb * 64 + lane) * 8);

    __syncthreads();

    float4v acc[4];
#pragma unroll
    for (int mt = 0; mt < 4; mt++) {
        float4v z4 = {0.f, 0.f, 0.f, 0.f};
        acc[mt] = z4;
    }

#pragma unroll
    for (int kb = 0; kb < 12; kb++) {
#pragma unroll
        for (int mt = 0; mt < 4; mt++) {
            short8 af = *(const short8*)&Vb[mt * 16 + l][kb * 32 + quad * 8];
            acc[mt] = __builtin_amdgcn_mfma_f32_16x16x32_bf16(af, bq[kb], acc[mt], 0, 0, 0);
        }
    }

    const int col = w * 16 + l;
    const float attc = att[col];
#pragma unroll
    for (int mt = 0; mt < 4; mt++)
#pragma unroll
        for (int r = 0; r < 4; r++) {
            int row = mt * 16 + quad * 4 + r;
            int pg = p0 + row;
            float v = acc[mt][r];
            if (pg < PPP) full[(size_t)pg * 128 + col] = v;
            float part = v * attc;
            part += __shfl_xor(part, 1);
            part += __shfl_xor(part, 2);
            part += __shfl_xor(part, 4);
            part += __shfl_xor(part, 8);
            if (l == 0 && pg < PPP) atomicAdd(&scores[pg], part);
        }
}

// ---------------- segment softmax + weighted sum (512 threads) --------------

__global__ __launch_bounds__(512) void seg_kernel(
    const float* __restrict__ scores, const float* __restrict__ full,
    const int* __restrict__ seg, float* __restrict__ out)
{
    const int s = blockIdx.x;
    const int tid = threadIdx.x;

    int lo = 0, hi = PPP;
    while (lo < hi) { int mid = (lo + hi) >> 1; if (seg[mid] < s) lo = mid + 1; else hi = mid; }
    const int start = lo;
    lo = start; hi = PPP;
    while (lo < hi) { int mid = (lo + hi) >> 1; if (seg[mid] < s + 1) lo = mid + 1; else hi = mid; }
    const int end = lo;

    if (start >= end) {
        if (tid < 128) out[(size_t)s * 128 + tid] = 0.f;
        return;
    }

    __shared__ float red[512];

    float mx = -1e30f;
    for (int i = start + tid; i < end; i += 512) mx = fmaxf(mx, scores[i]);
    red[tid] = mx; __syncthreads();
    for (int off = 256; off > 0; off >>= 1) {
        if (tid < off) red[tid] = fmaxf(red[tid], red[tid + off]);
        __syncthreads();
    }
    mx = red[0]; __syncthreads();

    float den = 0.f;
    for (int i = start + tid; i < end; i += 512) den += __expf(scores[i] - mx);
    red[tid] = den; __syncthreads();
    for (int off = 256; off > 0; off >>= 1) {
        if (tid < off) red[tid] += red[tid + off];
        __syncthreads();
    }
    den = red[0]; __syncthreads();

    const int col = tid & 127;
    const int pp  = tid >> 7;         // 0..3: 4 paths in flight
    float acc = 0.f;
    for (int i = start + pp; i < end; i += 4)
        acc = fmaf(__expf(scores[i] - mx), full[(size_t)i * 128 + col], acc);
    red[tid] = acc; __syncthreads();
    if (tid < 128)
        out[(size_t)s * 128 + tid] =
            (red[tid] + red[tid + 128] + red[tid + 256] + red[tid + 384]) / den;
}

// ---------------- launch ---------------------------------------------------

extern "C" void kernel_launch(void* const* d_in, const int* in_sizes, int n_in,
                              void* d_out, int out_size, void* d_ws, size_t ws_size,
                              hipStream_t stream) {
    (void)in_sizes; (void)n_in; (void)out_size; (void)ws_size;

    const float* leaf = (const float*)d_in[0];
    const float* emb  = (const float*)d_in[1];
    const float* Wf   = (const float*)d_in[2];
    const float* Uf   = (const float*)d_in[3];
    const float* bf   = (const float*)d_in[4];
    const float* Wb   = (const float*)d_in[5];
    const float* Ub   = (const float*)d_in[6];
    const float* bb   = (const float*)d_in[7];
    const float* proj = (const float*)d_in[8];
    const float* att  = (const float*)d_in[9];
    const int* path_elements = (const int*)d_in[10];
    const int* path_lengths  = (const int*)d_in[11];
    const int* leaf_idxs     = (const int*)d_in[12];
    const int* seg           = (const int*)d_in[13];
    float* out = (float*)d_out;

    char* ws = (char*)d_ws;
    int*    order  = (int*)ws;                         // 80,000 B
    int*    bins   = (int*)(ws + 80128);
    int*    cur    = (int*)(ws + 80384);
    ushort* Zall   = (ushort*)(ws + 81920);            // 20,480,000
    ushort* Ufrag  = (ushort*)(ws + 20561920);         // 262,144
    ushort* pfrag  = (ushort*)(ws + 20824064);         // 98,304
    ushort* Wfrag  = (ushort*)(ws + 20922368);         // 262,144
    ushort* hbuf   = (ushort*)(ws + 21184512);         // 10,240,000 (bf16)
    float*  full   = (float*)(ws + 31424512);          // 10,240,000
    float*  scores = (float*)(ws + 41664512);          // 80,000

    k_zero<<<1, 64, 0, stream>>>(bins);
    k_hist<<<(PPP + 255) / 256, 256, 0, stream>>>(path_lengths, bins, scores);
    k_scan<<<1, 64, 0, stream>>>(bins, cur);
    k_scatter<<<(PPP + 255) / 256, 256, 0, stream>>>(path_lengths, cur, order);

    frag_kernel<<<152, 256, 0, stream>>>(Uf, Ub, Wf, Wb, proj,
                                         Ufrag, Wfrag, pfrag);

    dim3 gz((VNT + 63) / 64, 2);
    zx_kernel<<<gz, 512, 0, stream>>>(emb, Wfrag, bf, bb, Zall);

    dim3 g((PPP + PB - 1) / PB, 2);
    lstm_kernel<<<g, 512, 0, stream>>>(Zall, Ufrag, path_elements, path_lengths,
                                       order, hbuf);

    proj_kernel<<<(PPP + 63) / 64, 512, 0, stream>>>(leaf, hbuf, pfrag, att,
                                                     leaf_idxs, full, scores);

    seg_kernel<<<SS, 512, 0, stream>>>(scores, full, seg, out);
}

// Round 11
// 381.805 us; speedup vs baseline: 6.4354x; 1.0114x over previous
//
#include <hip/hip_runtime.h>
#include <math.h>

#define PPP 20000   // paths
#define TT  30      // max timesteps
#define SS  1000    // samples
#define VNT 10000   // non-terminal vocab
#define PB  64      // paths per LSTM block
#define HSTR 152    // LDS row stride (ushorts): 304B, 16B-aligned

typedef __attribute__((ext_vector_type(8))) short short8;
typedef __attribute__((ext_vector_type(4))) float float4v;
typedef unsigned short ushort;
typedef unsigned int uint;

#define NLOG2E  -1.442695040888963f   // -log2(e): fold for sigmoid gates
#define N2LOG2E -2.885390081777927f   // -2log2(e): fold for tanh gate

__device__ __forceinline__ ushort f2bf(float x) {
    uint u = __builtin_bit_cast(uint, x);
    uint r = (u + 0x7fffu + ((u >> 16) & 1u)) >> 16;
    return (ushort)r;
}
__device__ __forceinline__ float bf2f(ushort h) {
    uint u = ((uint)h) << 16;
    return __builtin_bit_cast(float, u);
}
// pre-scaled activations: input already multiplied by -log2e (sig) / -2log2e (tanh)
__device__ __forceinline__ float fsig_s(float zs) {
    return __builtin_amdgcn_rcpf(1.f + __builtin_amdgcn_exp2f(zs));
}
__device__ __forceinline__ float ftanh_s(float zs) {
    return fmaf(2.f, __builtin_amdgcn_rcpf(1.f + __builtin_amdgcn_exp2f(zs)), -1.f);
}
__device__ __forceinline__ float ftanh(float x) {
    return ftanh_s(x * N2LOG2E);
}

// ---------------- length bucketing (counting sort, DESCENDING) -------------

__global__ void k_hist(const int* __restrict__ len, int* __restrict__ bins,
                       float* __restrict__ scores) {
    int p = blockIdx.x * 256 + threadIdx.x;
    if (p < PPP) { atomicAdd(&bins[len[p] - 1], 1); scores[p] = 0.f; }
}
__global__ void k_scan(const int* __restrict__ bins, int* __restrict__ cur) {
    if (threadIdx.x == 0 && blockIdx.x == 0) {
        int ofs = 0;
        for (int l = TT - 1; l >= 0; l--) { cur[l] = ofs; ofs += bins[l]; }
    }
}
__global__ void k_scatter(const int* __restrict__ len, int* __restrict__ cur,
                          int* __restrict__ order) {
    int p = blockIdx.x * 256 + threadIdx.x;
    if (p < PPP) {
        int pos = atomicAdd(&cur[len[p] - 1], 1);
        order[pos] = p;
    }
}

// ---------------- fused fragment precompute (+ bins zero) -------------------
// U/W frags get the per-gate activation scale FOLDED IN (i,f,o: -log2e;
// g: -2log2e). slots: [0,16384) ufrag, [16384,32768) wfrag, [32768,38912) pfrag.

__global__ __launch_bounds__(256) void frag_kernel(
    const float* __restrict__ Uf, const float* __restrict__ Ub,
    const float* __restrict__ Wf, const float* __restrict__ Wb,
    const float* __restrict__ proj,
    ushort* __restrict__ Ufrag, ushort* __restrict__ Wfrag,
    ushort* __restrict__ pfrag, int* __restrict__ bins)
{
    if (blockIdx.x == 0 && threadIdx.x < 32) bins[threadIdx.x] = 0;

    const float gsc[4] = {NLOG2E, NLOG2E, N2LOG2E, NLOG2E};
    int gs = blockIdx.x * 256 + threadIdx.x;     // 0..38911
    if (gs < 16384) {                            // ufrag
        int d = gs >> 13, s = gs & 8191;
        const float* U = d ? Ub : Uf;
        int lane = s & 63, kb = (s >> 6) & 3, g = (s >> 8) & 3, w = s >> 10;
        int krow = kb * 32 + (lane >> 4) * 8;
        int col  = g * 128 + w * 16 + (lane & 15);
        float sc = gsc[g];
        ushort* dst = Ufrag + (size_t)gs * 8;
#pragma unroll
        for (int j = 0; j < 8; j++)
            dst[j] = f2bf(U[(size_t)(krow + j) * 512 + col] * sc);
    } else if (gs < 32768) {                     // wfrag
        int t = gs - 16384;
        int d = t >> 13, s = t & 8191;
        const float* W = d ? Wb : Wf;
        int lane = s & 63, kb = (s >> 6) & 3, nt = s >> 8;
        int krow = kb * 32 + (lane >> 4) * 8;
        int col  = nt * 16 + (lane & 15);
        float sc = gsc[col >> 7];
        ushort* dst = Wfrag + (size_t)t * 8;
#pragma unroll
        for (int j = 0; j < 8; j++)
            dst[j] = f2bf(W[(size_t)(krow + j) * 512 + col] * sc);
    } else {                                     // pfrag (no scaling)
        int s = gs - 32768;                      // 0..6143
        int lane = s & 63;
        int kb = (s >> 6) % 12;
        int nt = s / 768;
        int krow = kb * 32 + (lane >> 4) * 8;
        int col  = nt * 16 + (lane & 15);
        ushort* dst = pfrag + (size_t)s * 8;
#pragma unroll
        for (int j = 0; j < 8; j++)
            dst[j] = f2bf(proj[(size_t)(krow + j) * 128 + col]);
    }
}

// ---------------- Zx = emb @ W + b via MFMA -> bf16 gather layout -----------

__global__ __launch_bounds__(512) void zx_kernel(
    const float* __restrict__ emb,
    const ushort* __restrict__ Wfrag,
    const float* __restrict__ bf, const float* __restrict__ bb,
    ushort* __restrict__ Zall)
{
    const float gsc[4] = {NLOG2E, NLOG2E, N2LOG2E, NLOG2E};
    const int dir = blockIdx.y;
    const ushort* WfD = Wfrag + (size_t)dir * 65536;
    const float* bias = dir ? bb : bf;
    ushort* Z = Zall + (size_t)dir * VNT * 512;

    __shared__ union {
        ushort At[64][HSTR];   // A tile: 64 tokens x 128 k (bf16)
        ushort Zt[64][520];    // C bounce: 64 tokens x 512 cols (bf16)
    } sm;

    const int tid  = threadIdx.x;
    const int w    = tid >> 6;
    const int lane = tid & 63;
    const int quad = lane >> 4;
    const int l    = lane & 15;
    const int tok0 = blockIdx.x * 64;

    {
        const int p = tid >> 3, ch = tid & 7;
        int tok = tok0 + p; if (tok > VNT - 1) tok = VNT - 1;
        const float4* src = (const float4*)(emb + (size_t)tok * 128 + ch * 16);
        ushort v[16];
#pragma unroll
        for (int q = 0; q < 4; q++) {
            float4 f = src[q];
            v[q * 4 + 0] = f2bf(f.x); v[q * 4 + 1] = f2bf(f.y);
            v[q * 4 + 2] = f2bf(f.z); v[q * 4 + 3] = f2bf(f.w);
        }
        *(int4*)&sm.At[p][ch * 16]     = *(const int4*)&v[0];
        *(int4*)&sm.At[p][ch * 16 + 8] = *(const int4*)&v[8];
    }

    short8 bq[4][4];   // [nt4][kb]
#pragma unroll
    for (int nt4 = 0; nt4 < 4; nt4++)
#pragma unroll
        for (int kb = 0; kb < 4; kb++)
            bq[nt4][kb] = *(const short8*)(WfD + (size_t)(((w * 4 + nt4) * 4 + kb) * 64 + lane) * 8);

    __syncthreads();

    float4v acc[4][4];     // [mt][nt4]
#pragma unroll
    for (int mt = 0; mt < 4; mt++)
#pragma unroll
        for (int nt4 = 0; nt4 < 4; nt4++) {
            float4v z4 = {0.f, 0.f, 0.f, 0.f};
            acc[mt][nt4] = z4;
        }

#pragma unroll
    for (int kb = 0; kb < 4; kb++) {
        short8 af[4];
#pragma unroll
        for (int mt = 0; mt < 4; mt++)
            af[mt] = *(const short8*)&sm.At[mt * 16 + l][kb * 32 + quad * 8];
#pragma unroll
        for (int nt4 = 0; nt4 < 4; nt4++)
#pragma unroll
            for (int mt = 0; mt < 4; mt++)
                acc[mt][nt4] = __builtin_amdgcn_mfma_f32_16x16x32_bf16(
                    af[mt], bq[nt4][kb], acc[mt][nt4], 0, 0, 0);
    }

    float bv[4];
#pragma unroll
    for (int nt4 = 0; nt4 < 4; nt4++) {
        int col = (w * 4 + nt4) * 16 + l;
        bv[nt4] = bias[col] * gsc[col >> 7];
    }

    __syncthreads();   // all At reads done; union switches to Zt

#pragma unroll
    for (int mt = 0; mt < 4; mt++)
#pragma unroll
        for (int r = 0; r < 4; r++) {
            const int p = mt * 16 + quad * 4 + r;
#pragma unroll
            for (int nt4 = 0; nt4 < 4; nt4++)
                sm.Zt[p][(w * 4 + nt4) * 16 + l] = f2bf(acc[mt][nt4][r] + bv[nt4]);
        }
    __syncthreads();

#pragma unroll
    for (int i = 0; i < 16; i++) {
        int s = i * 512 + tid;          // 0..8191
        int pt = s >> 7;                // token row 0..63
        int u  = s & 127;
        int tok = tok0 + pt;
        if (tok < VNT) {
            ushort v[4];
#pragma unroll
            for (int g = 0; g < 4; g++)
                v[g] = sm.Zt[pt][g * 128 + u];
            *(uint2*)(Z + (size_t)tok * 512 + u * 4) = *(const uint2*)v;
        }
    }
}

// ---------------- MFMA LSTM (zv pipelined, 1 block/CU, no spill) ------------
// __launch_bounds__(512,1): ~240 VGPR budget so zvN+acc+bfrag+c_st stay in
// registers (R10's 128-VGPR cap spilled ~10KB/block-step to scratch).

__global__ __launch_bounds__(512, 1) void lstm_kernel(
    const ushort* __restrict__ Zall,
    const ushort* __restrict__ Ufrag,
    const int* __restrict__ path_elements, const int* __restrict__ path_lengths,
    const int* __restrict__ order,
    ushort* __restrict__ h_out)   // bf16 [2][P][128]
{
    const int dir = blockIdx.y;
    const ushort* ZxD = Zall + (size_t)dir * VNT * 512;
    const ushort* UfD = Ufrag + (size_t)dir * 65536;

    __shared__ ushort hp[2][64][HSTR]; // bf16 h planes (A-layout)
    __shared__ int s_tok[TT][64];      // pre-shifted byte offsets (tok<<10)
    __shared__ int s_pid[PB];
    __shared__ int s_len[PB];

    const int tid  = threadIdx.x;
    const int w    = tid >> 6;         // wave 0..7
    const int lane = tid & 63;
    const int quad = lane >> 4;
    const int l    = lane & 15;

    if (tid < PB) {
        int idx = blockIdx.x * PB + tid;
        if (idx > PPP - 1) idx = PPP - 1;
        int pid = order[idx];
        s_pid[tid] = pid;
        s_len[tid] = path_lengths[pid];
    }
    for (int i = tid; i < 2 * 64 * (HSTR / 2); i += 512) ((uint*)&hp[0][0][0])[i] = 0;
    __syncthreads();

    for (int i = tid; i < 64 * TT; i += 512) {
        int p = i & 63, t = i >> 6;
        s_tok[t][p] = path_elements[(size_t)s_pid[p] * TT + t] << 10;  // *1024B
    }

    short8 bfrag[4][4];
#pragma unroll
    for (int g = 0; g < 4; g++)
#pragma unroll
        for (int kb = 0; kb < 4; kb++)
            bfrag[g][kb] = *(const short8*)(UfD + (size_t)(((w * 4 + g) * 4 + kb) * 64 + lane) * 8);

    __syncthreads();

    const int maxLen = s_len[0];       // descending sort
    const int myoff  = (w * 16 + l) * 8;
    const char* Zbase = (const char*)ZxD;

    // min length over my 16 rows (largest p I own -> shortest path)
    int lenMin = s_len[3 * 16 + quad * 4 + 3];

    float c_st[16];
#pragma unroll
    for (int i = 0; i < 16; i++) c_st[i] = 0.f;

    uint2 zvA[16], zvB[16];
    {
        const int t0 = dir ? (maxLen - 1) : 0;
#pragma unroll
        for (int mt = 0; mt < 4; mt++)
#pragma unroll
            for (int r = 0; r < 4; r++) {
                int off = s_tok[t0][mt * 16 + quad * 4 + r];
                zvA[mt * 4 + r] = *(const uint2*)(Zbase + off + myoff);
            }
    }

    auto stepBody = [&](int step, uint2 (&zvC)[16], uint2 (&zvN)[16]) {
        const int cu = step & 1, nx = cu ^ 1;
        const int t = dir ? (maxLen - 1 - step) : step;

        // acc preload: C = Zx contribution (bf16->f32), arrived last step
        float4v acc[4][4];             // [mt][g]
#pragma unroll
        for (int mt = 0; mt < 4; mt++)
#pragma unroll
            for (int r = 0; r < 4; r++) {
                const uint2 z2 = zvC[mt * 4 + r];
                acc[mt][0][r] = bf2f((ushort)(z2.x & 0xffff));
                acc[mt][1][r] = bf2f((ushort)(z2.x >> 16));
                acc[mt][2][r] = bf2f((ushort)(z2.y & 0xffff));
                acc[mt][3][r] = bf2f((ushort)(z2.y >> 16));
            }

        // prefetch next step's Zx (covered by MFMA + gating + barrier)
        {
            const int stepn = (step + 1 < maxLen) ? step + 1 : step;
            const int tn = dir ? (maxLen - 1 - stepn) : stepn;
#pragma unroll
            for (int mt = 0; mt < 4; mt++)
#pragma unroll
                for (int r = 0; r < 4; r++) {
                    int off = s_tok[tn][mt * 16 + quad * 4 + r];
                    zvN[mt * 4 + r] = *(const uint2*)(Zbase + off + myoff);
                }
        }

#pragma unroll
        for (int kb = 0; kb < 4; kb++) {
            short8 af[4];
#pragma unroll
            for (int mt = 0; mt < 4; mt++)
                af[mt] = *(const short8*)&hp[cu][mt * 16 + l][kb * 32 + quad * 8];
#pragma unroll
            for (int g = 0; g < 4; g++)
#pragma unroll
                for (int mt = 0; mt < 4; mt++)
                    acc[mt][g] = __builtin_amdgcn_mfma_f32_16x16x32_bf16(
                        af[mt], bfrag[g][kb], acc[mt][g], 0, 0, 0);
        }

        if (t < lenMin) {
            // fast path: all my 16 paths valid
#pragma unroll
            for (int mt = 0; mt < 4; mt++)
#pragma unroll
                for (int r = 0; r < 4; r++) {
                    const int p = mt * 16 + quad * 4 + r;
                    float ig = fsig_s(acc[mt][0][r]);
                    float fg = fsig_s(acc[mt][1][r]);
                    float gg = ftanh_s(acc[mt][2][r]);
                    float og = fsig_s(acc[mt][3][r]);
                    float cn = fg * c_st[mt * 4 + r] + ig * gg;
                    float hn = og * ftanh(cn);
                    c_st[mt * 4 + r] = cn;
                    hp[nx][p][w * 16 + l] = f2bf(hn);
                }
        } else {
#pragma unroll
            for (int mt = 0; mt < 4; mt++)
#pragma unroll
                for (int r = 0; r < 4; r++) {
                    const int p = mt * 16 + quad * 4 + r;
                    const bool valid = t < s_len[p];
                    const ushort hold = hp[cu][p][w * 16 + l];
                    float ig = fsig_s(acc[mt][0][r]);
                    float fg = fsig_s(acc[mt][1][r]);
                    float gg = ftanh_s(acc[mt][2][r]);
                    float og = fsig_s(acc[mt][3][r]);
                    float cn = fg * c_st[mt * 4 + r] + ig * gg;
                    float hn = og * ftanh(cn);
                    if (valid) c_st[mt * 4 + r] = cn;
                    hp[nx][p][w * 16 + l] = valid ? f2bf(hn) : hold;
                }
        }
        __syncthreads();
    };

    for (int step = 0; step < maxLen; step += 2) {
        stepBody(step, zvA, zvB);
        if (step + 1 < maxLen) stepBody(step + 1, zvB, zvA);
    }

    // epilogue: final plane -> bf16 h_out
    {
        const int fin = maxLen & 1;
        const int pg = tid >> 3;       // 0..63
        const int ch = tid & 7;        // 0..7 -> 16 cols
        ushort* dst = h_out + ((size_t)dir * PPP + s_pid[pg]) * 128 + ch * 16;
        *(int4*)dst       = *(const int4*)&hp[fin][pg][ch * 16];
        *(int4*)(dst + 8) = *(const int4*)&hp[fin][pg][ch * 16 + 8];
    }
}

// ---------------- MFMA projection + fused attention scores -----------------

__global__ __launch_bounds__(512) void proj_kernel(
    const float* __restrict__ leaf, const ushort* __restrict__ hbuf,
    const ushort* __restrict__ pfrag, const float* __restrict__ att,
    const int* __restrict__ leaf_idxs,
    float* __restrict__ full, float* __restrict__ scores)
{
    __shared__ ushort Vb[64][400];     // bf16, 16B-aligned rows
    __shared__ int s_lidx[64][2];

    const int tid  = threadIdx.x;
    const int w    = tid >> 6;
    const int lane = tid & 63;
    const int quad = lane >> 4;
    const int l    = lane & 15;
    const int p0   = blockIdx.x * 64;

    if (tid < 128) {
        int p = tid >> 1;
        int pg = p0 + p; if (pg > PPP - 1) pg = PPP - 1;
        s_lidx[p][tid & 1] = leaf_idxs[(size_t)pg * 2 + (tid & 1)];
    }
    __syncthreads();

    for (int s = tid; s < 64 * 192; s += 512) {
        int p = s / 192, cp = s % 192;
        int c = cp * 2;
        int pg = p0 + p; if (pg > PPP - 1) pg = PPP - 1;
        uint val;
        if (c < 128) {
            const float* src = leaf + (size_t)s_lidx[p][c >> 6] * 64 + (c & 63);
            float2 f = *(const float2*)src;
            val = (uint)f2bf(f.x) | ((uint)f2bf(f.y) << 16);
        } else {
            const ushort* src = hbuf + ((size_t)(c < 256 ? 0 : 1) * PPP + pg) * 128 + (c & 127);
            val = *(const uint*)src;
        }
        *(uint*)&Vb[p][c] = val;
    }

    short8 bq[12];
#pragma unroll
    for (int kb = 0; kb < 12; kb++)
        bq[kb] = *(const short8*)(pfrag + ((size_t)w * 768 + kb * 64 + lane) * 8);

    __syncthreads();

    float4v acc[4];
#pragma unroll
    for (int mt = 0; mt < 4; mt++) {
        float4v z4 = {0.f, 0.f, 0.f, 0.f};
        acc[mt] = z4;
    }

#pragma unroll
    for (int kb = 0; kb < 12; kb++) {
#pragma unroll
        for (int mt = 0; mt < 4; mt++) {
            short8 af = *(const short8*)&Vb[mt * 16 + l][kb * 32 + quad * 8];
            acc[mt] = __builtin_amdgcn_mfma_f32_16x16x32_bf16(af, bq[kb], acc[mt], 0, 0, 0);
        }
    }

    const int col = w * 16 + l;
    const float attc = att[col];
#pragma unroll
    for (int mt = 0; mt < 4; mt++)
#pragma unroll
        for (int r = 0; r < 4; r++) {
            int row = mt * 16 + quad * 4 + r;
            int pg = p0 + row;
            float v = acc[mt][r];
            if (pg < PPP) full[(size_t)pg * 128 + col] = v;
            float part = v * attc;
            part += __shfl_xor(part, 1);
            part += __shfl_xor(part, 2);
            part += __shfl_xor(part, 4);
            part += __shfl_xor(part, 8);
            if (l == 0 && pg < PPP) atomicAdd(&scores[pg], part);
        }
}

// ---------------- segment softmax + weighted sum (512 threads) --------------

__global__ __launch_bounds__(512) void seg_kernel(
    const float* __restrict__ scores, const float* __restrict__ full,
    const int* __restrict__ seg, float* __restrict__ out)
{
    const int s = blockIdx.x;
    const int tid = threadIdx.x;

    int lo = 0, hi = PPP;
    while (lo < hi) { int mid = (lo + hi) >> 1; if (seg[mid] < s) lo = mid + 1; else hi = mid; }
    const int start = lo;
    lo = start; hi = PPP;
    while (lo < hi) { int mid = (lo + hi) >> 1; if (seg[mid] < s + 1) lo = mid + 1; else hi = mid; }
    const int end = lo;

    if (start >= end) {
        if (tid < 128) out[(size_t)s * 128 + tid] = 0.f;
        return;
    }

    __shared__ float red[512];

    float mx = -1e30f;
    for (int i = start + tid; i < end; i += 512) mx = fmaxf(mx, scores[i]);
    red[tid] = mx; __syncthreads();
    for (int off = 256; off > 0; off >>= 1) {
        if (tid < off) red[tid] = fmaxf(red[tid], red[tid + off]);
        __syncthreads();
    }
    mx = red[0]; __syncthreads();

    float den = 0.f;
    for (int i = start + tid; i < end; i += 512) den += __expf(scores[i] - mx);
    red[tid] = den; __syncthreads();
    for (int off = 256; off > 0; off >>= 1) {
        if (tid < off) red[tid] += red[tid + off];
        __syncthreads();
    }
    den = red[0]; __syncthreads();

    const int col = tid & 127;
    const int pp  = tid >> 7;         // 0..3: 4 paths in flight
    float acc = 0.f;
    for (int i = start + pp; i < end; i += 4)
        acc = fmaf(__expf(scores[i] - mx), full[(size_t)i * 128 + col], acc);
    red[tid] = acc; __syncthreads();
    if (tid < 128)
        out[(size_t)s * 128 + tid] =
            (red[tid] + red[tid + 128] + red[tid + 256] + red[tid + 384]) / den;
}

// ---------------- launch ---------------------------------------------------

extern "C" void kernel_launch(void* const* d_in, const int* in_sizes, int n_in,
                              void* d_out, int out_size, void* d_ws, size_t ws_size,
                              hipStream_t stream) {
    (void)in_sizes; (void)n_in; (void)out_size; (void)ws_size;

    const float* leaf = (const float*)d_in[0];
    const float* emb  = (const float*)d_in[1];
    const float* Wf   = (const float*)d_in[2];
    const float* Uf   = (const float*)d_in[3];
    const float* bf   = (const float*)d_in[4];
    const float* Wb   = (const float*)d_in[5];
    const float* Ub   = (const float*)d_in[6];
    const float* bb   = (const float*)d_in[7];
    const float* proj = (const float*)d_in[8];
    const float* att  = (const float*)d_in[9];
    const int* path_elements = (const int*)d_in[10];
    const int* path_lengths  = (const int*)d_in[11];
    const int* leaf_idxs     = (const int*)d_in[12];
    const int* seg           = (const int*)d_in[13];
    float* out = (float*)d_out;

    char* ws = (char*)d_ws;
    int*    order  = (int*)ws;                         // 80,000 B
    int*    bins   = (int*)(ws + 80128);
    int*    cur    = (int*)(ws + 80384);
    ushort* Zall   = (ushort*)(ws + 81920);            // 20,480,000
    ushort* Ufrag  = (ushort*)(ws + 20561920);         // 262,144
    ushort* pfrag  = (ushort*)(ws + 20824064);         // 98,304
    ushort* Wfrag  = (ushort*)(ws + 20922368);         // 262,144
    ushort* hbuf   = (ushort*)(ws + 21184512);         // 10,240,000 (bf16)
    float*  full   = (float*)(ws + 31424512);          // 10,240,000
    float*  scores = (float*)(ws + 41664512);          // 80,000

    frag_kernel<<<152, 256, 0, stream>>>(Uf, Ub, Wf, Wb, proj,
                                         Ufrag, Wfrag, pfrag, bins);

    k_hist<<<(PPP + 255) / 256, 256, 0, stream>>>(path_lengths, bins, scores);
    k_scan<<<1, 64, 0, stream>>>(bins, cur);
    k_scatter<<<(PPP + 255) / 256, 256, 0, stream>>>(path_lengths, cur, order);

    dim3 gz((VNT + 63) / 64, 2);
    zx_kernel<<<gz, 512, 0, stream>>>(emb, Wfrag, bf, bb, Zall);

    dim3 g((PPP + PB - 1) / PB, 2);
    lstm_kernel<<<g, 512, 0, stream>>>(Zall, Ufrag, path_elements, path_lengths,
                                       order, hbuf);

    proj_kernel<<<(PPP + 63) / 64, 512, 0, stream>>>(leaf, hbuf, pfrag, att,
                                                     leaf_idxs, full, scores);

    seg_kernel<<<SS, 512, 0, stream>>>(scores, full, seg, out);
}

// Round 12
// 359.902 us; speedup vs baseline: 6.8270x; 1.0609x over previous
//
#include <hip/hip_runtime.h>
#include <math.h>

#define PPP 20000   // paths
#define TT  30      // max timesteps
#define SS  1000    // samples
#define VNT 10000   // non-terminal vocab
#define PB  32      // paths per LSTM block
#define HSTR 152    // LDS row stride (ushorts): 304B, 16B-aligned

typedef __attribute__((ext_vector_type(8))) short short8;
typedef __attribute__((ext_vector_type(4))) float float4v;
typedef unsigned short ushort;
typedef unsigned int uint;

#define NLOG2E  -1.442695040888963f   // -log2(e): fold for sigmoid gates
#define N2LOG2E -2.885390081777927f   // -2log2(e): fold for tanh gate

__device__ __forceinline__ ushort f2bf(float x) {
    uint u = __builtin_bit_cast(uint, x);
    uint r = (u + 0x7fffu + ((u >> 16) & 1u)) >> 16;
    return (ushort)r;
}
__device__ __forceinline__ float bf2f(ushort h) {
    uint u = ((uint)h) << 16;
    return __builtin_bit_cast(float, u);
}
// pre-scaled activations: input already multiplied by -log2e (sig) / -2log2e (tanh)
__device__ __forceinline__ float fsig_s(float zs) {
    return __builtin_amdgcn_rcpf(1.f + __builtin_amdgcn_exp2f(zs));
}
__device__ __forceinline__ float ftanh_s(float zs) {
    return fmaf(2.f, __builtin_amdgcn_rcpf(1.f + __builtin_amdgcn_exp2f(zs)), -1.f);
}
__device__ __forceinline__ float ftanh(float x) {
    return ftanh_s(x * N2LOG2E);
}

// ---------------- length bucketing (counting sort, DESCENDING) -------------

__global__ void k_hist(const int* __restrict__ len, int* __restrict__ bins,
                       float* __restrict__ scores) {
    int p = blockIdx.x * 256 + threadIdx.x;
    if (p < PPP) { atomicAdd(&bins[len[p] - 1], 1); scores[p] = 0.f; }
}
__global__ void k_scan(const int* __restrict__ bins, int* __restrict__ cur) {
    if (threadIdx.x == 0 && blockIdx.x == 0) {
        int ofs = 0;
        for (int l = TT - 1; l >= 0; l--) { cur[l] = ofs; ofs += bins[l]; }
    }
}
__global__ void k_scatter(const int* __restrict__ len, int* __restrict__ cur,
                          int* __restrict__ order) {
    int p = blockIdx.x * 256 + threadIdx.x;
    if (p < PPP) {
        int pos = atomicAdd(&cur[len[p] - 1], 1);
        order[pos] = p;
    }
}

// ---------------- fused fragment precompute (+ bins zero) -------------------
// U/W frags get the per-gate activation scale FOLDED IN (i,f,o: -log2e;
// g: -2log2e). slots: [0,16384) ufrag, [16384,32768) wfrag, [32768,38912) pfrag.

__global__ __launch_bounds__(256) void frag_kernel(
    const float* __restrict__ Uf, const float* __restrict__ Ub,
    const float* __restrict__ Wf, const float* __restrict__ Wb,
    const float* __restrict__ proj,
    ushort* __restrict__ Ufrag, ushort* __restrict__ Wfrag,
    ushort* __restrict__ pfrag, int* __restrict__ bins)
{
    if (blockIdx.x == 0 && threadIdx.x < 32) bins[threadIdx.x] = 0;

    const float gsc[4] = {NLOG2E, NLOG2E, N2LOG2E, NLOG2E};
    int gs = blockIdx.x * 256 + threadIdx.x;     // 0..38911
    if (gs < 16384) {                            // ufrag
        int d = gs >> 13, s = gs & 8191;
        const float* U = d ? Ub : Uf;
        int lane = s & 63, kb = (s >> 6) & 3, g = (s >> 8) & 3, w = s >> 10;
        int krow = kb * 32 + (lane >> 4) * 8;
        int col  = g * 128 + w * 16 + (lane & 15);
        float sc = gsc[g];
        ushort* dst = Ufrag + (size_t)gs * 8;
#pragma unroll
        for (int j = 0; j < 8; j++)
            dst[j] = f2bf(U[(size_t)(krow + j) * 512 + col] * sc);
    } else if (gs < 32768) {                     // wfrag
        int t = gs - 16384;
        int d = t >> 13, s = t & 8191;
        const float* W = d ? Wb : Wf;
        int lane = s & 63, kb = (s >> 6) & 3, nt = s >> 8;
        int krow = kb * 32 + (lane >> 4) * 8;
        int col  = nt * 16 + (lane & 15);
        float sc = gsc[col >> 7];
        ushort* dst = Wfrag + (size_t)t * 8;
#pragma unroll
        for (int j = 0; j < 8; j++)
            dst[j] = f2bf(W[(size_t)(krow + j) * 512 + col] * sc);
    } else {                                     // pfrag (no scaling)
        int s = gs - 32768;                      // 0..6143
        int lane = s & 63;
        int kb = (s >> 6) % 12;
        int nt = s / 768;
        int krow = kb * 32 + (lane >> 4) * 8;
        int col  = nt * 16 + (lane & 15);
        ushort* dst = pfrag + (size_t)s * 8;
#pragma unroll
        for (int j = 0; j < 8; j++)
            dst[j] = f2bf(proj[(size_t)(krow + j) * 128 + col]);
    }
}

// ---------------- Zx = emb @ W + b via MFMA -> bf16 gather layout -----------

__global__ __launch_bounds__(512) void zx_kernel(
    const float* __restrict__ emb,
    const ushort* __restrict__ Wfrag,
    const float* __restrict__ bf, const float* __restrict__ bb,
    ushort* __restrict__ Zall)
{
    const float gsc[4] = {NLOG2E, NLOG2E, N2LOG2E, NLOG2E};
    const int dir = blockIdx.y;
    const ushort* WfD = Wfrag + (size_t)dir * 65536;
    const float* bias = dir ? bb : bf;
    ushort* Z = Zall + (size_t)dir * VNT * 512;

    __shared__ union {
        ushort At[64][HSTR];   // A tile: 64 tokens x 128 k (bf16)
        ushort Zt[64][520];    // C bounce: 64 tokens x 512 cols (bf16)
    } sm;

    const int tid  = threadIdx.x;
    const int w    = tid >> 6;
    const int lane = tid & 63;
    const int quad = lane >> 4;
    const int l    = lane & 15;
    const int tok0 = blockIdx.x * 64;

    {
        const int p = tid >> 3, ch = tid & 7;
        int tok = tok0 + p; if (tok > VNT - 1) tok = VNT - 1;
        const float4* src = (const float4*)(emb + (size_t)tok * 128 + ch * 16);
        ushort v[16];
#pragma unroll
        for (int q = 0; q < 4; q++) {
            float4 f = src[q];
            v[q * 4 + 0] = f2bf(f.x); v[q * 4 + 1] = f2bf(f.y);
            v[q * 4 + 2] = f2bf(f.z); v[q * 4 + 3] = f2bf(f.w);
        }
        *(int4*)&sm.At[p][ch * 16]     = *(const int4*)&v[0];
        *(int4*)&sm.At[p][ch * 16 + 8] = *(const int4*)&v[8];
    }

    short8 bq[4][4];   // [nt4][kb]
#pragma unroll
    for (int nt4 = 0; nt4 < 4; nt4++)
#pragma unroll
        for (int kb = 0; kb < 4; kb++)
            bq[nt4][kb] = *(const short8*)(WfD + (size_t)(((w * 4 + nt4) * 4 + kb) * 64 + lane) * 8);

    __syncthreads();

    float4v acc[4][4];     // [mt][nt4]
#pragma unroll
    for (int mt = 0; mt < 4; mt++)
#pragma unroll
        for (int nt4 = 0; nt4 < 4; nt4++) {
            float4v z4 = {0.f, 0.f, 0.f, 0.f};
            acc[mt][nt4] = z4;
        }

#pragma unroll
    for (int kb = 0; kb < 4; kb++) {
        short8 af[4];
#pragma unroll
        for (int mt = 0; mt < 4; mt++)
            af[mt] = *(const short8*)&sm.At[mt * 16 + l][kb * 32 + quad * 8];
#pragma unroll
        for (int nt4 = 0; nt4 < 4; nt4++)
#pragma unroll
            for (int mt = 0; mt < 4; mt++)
                acc[mt][nt4] = __builtin_amdgcn_mfma_f32_16x16x32_bf16(
                    af[mt], bq[nt4][kb], acc[mt][nt4], 0, 0, 0);
    }

    float bv[4];
#pragma unroll
    for (int nt4 = 0; nt4 < 4; nt4++) {
        int col = (w * 4 + nt4) * 16 + l;
        bv[nt4] = bias[col] * gsc[col >> 7];
    }

    __syncthreads();   // all At reads done; union switches to Zt

#pragma unroll
    for (int mt = 0; mt < 4; mt++)
#pragma unroll
        for (int r = 0; r < 4; r++) {
            const int p = mt * 16 + quad * 4 + r;
#pragma unroll
            for (int nt4 = 0; nt4 < 4; nt4++)
                sm.Zt[p][(w * 4 + nt4) * 16 + l] = f2bf(acc[mt][nt4][r] + bv[nt4]);
        }
    __syncthreads();

#pragma unroll
    for (int i = 0; i < 16; i++) {
        int s = i * 512 + tid;          // 0..8191
        int pt = s >> 7;                // token row 0..63
        int u  = s & 127;
        int tok = tok0 + pt;
        if (tok < VNT) {
            ushort v[4];
#pragma unroll
            for (int g = 0; g < 4; g++)
                v[g] = sm.Zt[pt][g * 128 + u];
            *(uint2*)(Z + (size_t)tok * 512 + u * 4) = *(const uint2*)v;
        }
    }
}

// ---------------- MFMA LSTM (32 paths/block, zv pipelined) ------------------
// 32 paths, 512 threads (8 waves). Wave w owns hidden cols [w*16,w*16+16) of
// each gate; 2 M-tiles. Smaller per-thread state (acc 32, zv 16, c 8) ->
// minimal spill; 1250 blocks -> 2 co-resident blocks/CU overlap barrier
// stalls; finer tail granularity.

__global__ __launch_bounds__(512, 2) void lstm_kernel(
    const ushort* __restrict__ Zall,
    const ushort* __restrict__ Ufrag,
    const int* __restrict__ path_elements, const int* __restrict__ path_lengths,
    const int* __restrict__ order,
    ushort* __restrict__ h_out)   // bf16 [2][P][128]
{
    const int dir = blockIdx.y;
    const ushort* ZxD = Zall + (size_t)dir * VNT * 512;
    const ushort* UfD = Ufrag + (size_t)dir * 65536;

    __shared__ ushort hp[2][PB][HSTR]; // bf16 h planes (A-layout)
    __shared__ int s_tok[TT][PB];      // pre-shifted byte offsets (tok<<10)
    __shared__ int s_pid[PB];
    __shared__ int s_len[PB];

    const int tid  = threadIdx.x;
    const int w    = tid >> 6;         // wave 0..7
    const int lane = tid & 63;
    const int quad = lane >> 4;
    const int l    = lane & 15;

    if (tid < PB) {
        int idx = blockIdx.x * PB + tid;
        if (idx > PPP - 1) idx = PPP - 1;
        int pid = order[idx];
        s_pid[tid] = pid;
        s_len[tid] = path_lengths[pid];
    }
    for (int i = tid; i < PB * HSTR; i += 512) ((uint*)&hp[0][0][0])[i] = 0;
    __syncthreads();

    for (int i = tid; i < PB * TT; i += 512) {
        int p = i & (PB - 1), t = i >> 5;
        s_tok[t][p] = path_elements[(size_t)s_pid[p] * TT + t] << 10;  // *1024B
    }

    short8 bfrag[4][4];
#pragma unroll
    for (int g = 0; g < 4; g++)
#pragma unroll
        for (int kb = 0; kb < 4; kb++)
            bfrag[g][kb] = *(const short8*)(UfD + (size_t)(((w * 4 + g) * 4 + kb) * 64 + lane) * 8);

    __syncthreads();

    const int maxLen = s_len[0];       // descending sort
    const int myoff  = (w * 16 + l) * 8;
    const char* Zbase = (const char*)ZxD;

    // min length over my 8 rows (largest p I own -> shortest path)
    int lenMin = s_len[16 + quad * 4 + 3];

    float c_st[8];
#pragma unroll
    for (int i = 0; i < 8; i++) c_st[i] = 0.f;

    uint2 zvA[8], zvB[8];
    {
        const int t0 = dir ? (maxLen - 1) : 0;
#pragma unroll
        for (int mt = 0; mt < 2; mt++)
#pragma unroll
            for (int r = 0; r < 4; r++) {
                int off = s_tok[t0][mt * 16 + quad * 4 + r];
                zvA[mt * 4 + r] = *(const uint2*)(Zbase + off + myoff);
            }
    }

    auto stepBody = [&](int step, uint2 (&zvC)[8], uint2 (&zvN)[8]) {
        const int cu = step & 1, nx = cu ^ 1;
        const int t = dir ? (maxLen - 1 - step) : step;

        // acc preload: C = Zx contribution (bf16->f32), arrived last step
        float4v acc[2][4];             // [mt][g]
#pragma unroll
        for (int mt = 0; mt < 2; mt++)
#pragma unroll
            for (int r = 0; r < 4; r++) {
                const uint2 z2 = zvC[mt * 4 + r];
                acc[mt][0][r] = bf2f((ushort)(z2.x & 0xffff));
                acc[mt][1][r] = bf2f((ushort)(z2.x >> 16));
                acc[mt][2][r] = bf2f((ushort)(z2.y & 0xffff));
                acc[mt][3][r] = bf2f((ushort)(z2.y >> 16));
            }

        // prefetch next step's Zx (covered by MFMA + gating + barrier)
        {
            const int stepn = (step + 1 < maxLen) ? step + 1 : step;
            const int tn = dir ? (maxLen - 1 - stepn) : stepn;
#pragma unroll
            for (int mt = 0; mt < 2; mt++)
#pragma unroll
                for (int r = 0; r < 4; r++) {
                    int off = s_tok[tn][mt * 16 + quad * 4 + r];
                    zvN[mt * 4 + r] = *(const uint2*)(Zbase + off + myoff);
                }
        }

#pragma unroll
        for (int kb = 0; kb < 4; kb++) {
            short8 af[2];
#pragma unroll
            for (int mt = 0; mt < 2; mt++)
                af[mt] = *(const short8*)&hp[cu][mt * 16 + l][kb * 32 + quad * 8];
#pragma unroll
            for (int g = 0; g < 4; g++)
#pragma unroll
                for (int mt = 0; mt < 2; mt++)
                    acc[mt][g] = __builtin_amdgcn_mfma_f32_16x16x32_bf16(
                        af[mt], bfrag[g][kb], acc[mt][g], 0, 0, 0);
        }

        if (t < lenMin) {
            // fast path: all my 8 paths valid
#pragma unroll
            for (int mt = 0; mt < 2; mt++)
#pragma unroll
                for (int r = 0; r < 4; r++) {
                    const int p = mt * 16 + quad * 4 + r;
                    float ig = fsig_s(acc[mt][0][r]);
                    float fg = fsig_s(acc[mt][1][r]);
                    float gg = ftanh_s(acc[mt][2][r]);
                    float og = fsig_s(acc[mt][3][r]);
                    float cn = fg * c_st[mt * 4 + r] + ig * gg;
                    float hn = og * ftanh(cn);
                    c_st[mt * 4 + r] = cn;
                    hp[nx][p][w * 16 + l] = f2bf(hn);
                }
        } else {
#pragma unroll
            for (int mt = 0; mt < 2; mt++)
#pragma unroll
                for (int r = 0; r < 4; r++) {
                    const int p = mt * 16 + quad * 4 + r;
                    const bool valid = t < s_len[p];
                    const ushort hold = hp[cu][p][w * 16 + l];
                    float ig = fsig_s(acc[mt][0][r]);
                    float fg = fsig_s(acc[mt][1][r]);
                    float gg = ftanh_s(acc[mt][2][r]);
                    float og = fsig_s(acc[mt][3][r]);
                    float cn = fg * c_st[mt * 4 + r] + ig * gg;
                    float hn = og * ftanh(cn);
                    if (valid) c_st[mt * 4 + r] = cn;
                    hp[nx][p][w * 16 + l] = valid ? f2bf(hn) : hold;
                }
        }
        __syncthreads();
    };

    for (int step = 0; step < maxLen; step += 2) {
        stepBody(step, zvA, zvB);
        if (step + 1 < maxLen) stepBody(step + 1, zvB, zvA);
    }

    // epilogue: final plane -> bf16 h_out; thread -> path pg, cols ch*8..+7
    {
        const int fin = maxLen & 1;
        const int pg = tid >> 4;       // 0..31
        const int ch = tid & 15;       // 0..15 -> 8 cols
        ushort* dst = h_out + ((size_t)dir * PPP + s_pid[pg]) * 128 + ch * 8;
        *(int4*)dst = *(const int4*)&hp[fin][pg][ch * 8];
    }
}

// ---------------- MFMA projection + fused attention scores -----------------

__global__ __launch_bounds__(512) void proj_kernel(
    const float* __restrict__ leaf, const ushort* __restrict__ hbuf,
    const ushort* __restrict__ pfrag, const float* __restrict__ att,
    const int* __restrict__ leaf_idxs,
    float* __restrict__ full, float* __restrict__ scores)
{
    __shared__ ushort Vb[64][400];     // bf16, 16B-aligned rows
    __shared__ int s_lidx[64][2];

    const int tid  = threadIdx.x;
    const int w    = tid >> 6;
    const int lane = tid & 63;
    const int quad = lane >> 4;
    const int l    = lane & 15;
    const int p0   = blockIdx.x * 64;

    if (tid < 128) {
        int p = tid >> 1;
        int pg = p0 + p; if (pg > PPP - 1) pg = PPP - 1;
        s_lidx[p][tid & 1] = leaf_idxs[(size_t)pg * 2 + (tid & 1)];
    }
    __syncthreads();

    for (int s = tid; s < 64 * 192; s += 512) {
        int p = s / 192, cp = s % 192;
        int c = cp * 2;
        int pg = p0 + p; if (pg > PPP - 1) pg = PPP - 1;
        uint val;
        if (c < 128) {
            const float* src = leaf + (size_t)s_lidx[p][c >> 6] * 64 + (c & 63);
            float2 f = *(const float2*)src;
            val = (uint)f2bf(f.x) | ((uint)f2bf(f.y) << 16);
        } else {
            const ushort* src = hbuf + ((size_t)(c < 256 ? 0 : 1) * PPP + pg) * 128 + (c & 127);
            val = *(const uint*)src;
        }
        *(uint*)&Vb[p][c] = val;
    }

    short8 bq[12];
#pragma unroll
    for (int kb = 0; kb < 12; kb++)
        bq[kb] = *(const short8*)(pfrag + ((size_t)w * 768 + kb * 64 + lane) * 8);

    __syncthreads();

    float4v acc[4];
#pragma unroll
    for (int mt = 0; mt < 4; mt++) {
        float4v z4 = {0.f, 0.f, 0.f, 0.f};
        acc[mt] = z4;
    }

#pragma unroll
    for (int kb = 0; kb < 12; kb++) {
#pragma unroll
        for (int mt = 0; mt < 4; mt++) {
            short8 af = *(const short8*)&Vb[mt * 16 + l][kb * 32 + quad * 8];
            acc[mt] = __builtin_amdgcn_mfma_f32_16x16x32_bf16(af, bq[kb], acc[mt], 0, 0, 0);
        }
    }

    const int col = w * 16 + l;
    const float attc = att[col];
#pragma unroll
    for (int mt = 0; mt < 4; mt++)
#pragma unroll
        for (int r = 0; r < 4; r++) {
            int row = mt * 16 + quad * 4 + r;
            int pg = p0 + row;
            float v = acc[mt][r];
            if (pg < PPP) full[(size_t)pg * 128 + col] = v;
            float part = v * attc;
            part += __shfl_xor(part, 1);
            part += __shfl_xor(part, 2);
            part += __shfl_xor(part, 4);
            part += __shfl_xor(part, 8);
            if (l == 0 && pg < PPP) atomicAdd(&scores[pg], part);
        }
}

// ---------------- segment softmax + weighted sum (512 threads) --------------

__global__ __launch_bounds__(512) void seg_kernel(
    const float* __restrict__ scores, const float* __restrict__ full,
    const int* __restrict__ seg, float* __restrict__ out)
{
    const int s = blockIdx.x;
    const int tid = threadIdx.x;

    int lo = 0, hi = PPP;
    while (lo < hi) { int mid = (lo + hi) >> 1; if (seg[mid] < s) lo = mid + 1; else hi = mid; }
    const int start = lo;
    lo = start; hi = PPP;
    while (lo < hi) { int mid = (lo + hi) >> 1; if (seg[mid] < s + 1) lo = mid + 1; else hi = mid; }
    const int end = lo;

    if (start >= end) {
        if (tid < 128) out[(size_t)s * 128 + tid] = 0.f;
        return;
    }

    __shared__ float red[512];

    float mx = -1e30f;
    for (int i = start + tid; i < end; i += 512) mx = fmaxf(mx, scores[i]);
    red[tid] = mx; __syncthreads();
    for (int off = 256; off > 0; off >>= 1) {
        if (tid < off) red[tid] = fmaxf(red[tid], red[tid + off]);
        __syncthreads();
    }
    mx = red[0]; __syncthreads();

    float den = 0.f;
    for (int i = start + tid; i < end; i += 512) den += __expf(scores[i] - mx);
    red[tid] = den; __syncthreads();
    for (int off = 256; off > 0; off >>= 1) {
        if (tid < off) red[tid] += red[tid + off];
        __syncthreads();
    }
    den = red[0]; __syncthreads();

    const int col = tid & 127;
    const int pp  = tid >> 7;         // 0..3: 4 paths in flight
    float acc = 0.f;
    for (int i = start + pp; i < end; i += 4)
        acc = fmaf(__expf(scores[i] - mx), full[(size_t)i * 128 + col], acc);
    red[tid] = acc; __syncthreads();
    if (tid < 128)
        out[(size_t)s * 128 + tid] =
            (red[tid] + red[tid + 128] + red[tid + 256] + red[tid + 384]) / den;
}

// ---------------- launch ---------------------------------------------------

extern "C" void kernel_launch(void* const* d_in, const int* in_sizes, int n_in,
                              void* d_out, int out_size, void* d_ws, size_t ws_size,
                              hipStream_t stream) {
    (void)in_sizes; (void)n_in; (void)out_size; (void)ws_size;

    const float* leaf = (const float*)d_in[0];
    const float* emb  = (const float*)d_in[1];
    const float* Wf   = (const float*)d_in[2];
    const float* Uf   = (const float*)d_in[3];
    const float* bf   = (const float*)d_in[4];
    const float* Wb   = (const float*)d_in[5];
    const float* Ub   = (const float*)d_in[6];
    const float* bb   = (const float*)d_in[7];
    const float* proj = (const float*)d_in[8];
    const float* att  = (const float*)d_in[9];
    const int* path_elements = (const int*)d_in[10];
    const int* path_lengths  = (const int*)d_in[11];
    const int* leaf_idxs     = (const int*)d_in[12];
    const int* seg           = (const int*)d_in[13];
    float* out = (float*)d_out;

    char* ws = (char*)d_ws;
    int*    order  = (int*)ws;                         // 80,000 B
    int*    bins   = (int*)(ws + 80128);
    int*    cur    = (int*)(ws + 80384);
    ushort* Zall   = (ushort*)(ws + 81920);            // 20,480,000
    ushort* Ufrag  = (ushort*)(ws + 20561920);         // 262,144
    ushort* pfrag  = (ushort*)(ws + 20824064);         // 98,304
    ushort* Wfrag  = (ushort*)(ws + 20922368);         // 262,144
    ushort* hbuf   = (ushort*)(ws + 21184512);         // 10,240,000 (bf16)
    float*  full   = (float*)(ws + 31424512);          // 10,240,000
    float*  scores = (float*)(ws + 41664512);          // 80,000

    frag_kernel<<<152, 256, 0, stream>>>(Uf, Ub, Wf, Wb, proj,
                                         Ufrag, Wfrag, pfrag, bins);

    k_hist<<<(PPP + 255) / 256, 256, 0, stream>>>(path_lengths, bins, scores);
    k_scan<<<1, 64, 0, stream>>>(bins, cur);
    k_scatter<<<(PPP + 255) / 256, 256, 0, stream>>>(path_lengths, cur, order);

    dim3 gz((VNT + 63) / 64, 2);
    zx_kernel<<<gz, 512, 0, stream>>>(emb, Wfrag, bf, bb, Zall);

    dim3 g(PPP / PB, 2);
    lstm_kernel<<<g, 512, 0, stream>>>(Zall, Ufrag, path_elements, path_lengths,
                                       order, hbuf);

    proj_kernel<<<(PPP + 63) / 64, 512, 0, stream>>>(leaf, hbuf, pfrag, att,
                                                     leaf_idxs, full, scores);

    seg_kernel<<<SS, 512, 0, stream>>>(scores, full, seg, out);
}